// Round 11
// baseline (818.300 us; speedup 1.0000x reference)
//
#include <hip/hip_runtime.h>
#include <hip/hip_bf16.h>
#include <math.h>

#define BATCH 16
#define TLEN 3600
#define LEADS 12
#define PP 9
#define SS 400
#define DP 128
#define DM 256
#define NH 8
#define HD 32
#define NLAY 6
#define VV 512
#define RH 64

typedef __attribute__((ext_vector_type(8))) short short8b;
typedef __attribute__((ext_vector_type(4))) float f32x4;

__device__ __forceinline__ float gelu_f(float x) {
    return 0.5f * x * (1.0f + erff(x * 0.70710678118654752f));
}

__device__ __forceinline__ unsigned short f2bf(float f) {
    union { float f; unsigned u; } v; v.f = f;
    return (unsigned short)((v.u + 0x7FFFu + ((v.u >> 16) & 1u)) >> 16);
}

__device__ __forceinline__ float bf2f(unsigned short h) {
    union { unsigned u; float f; } v; v.u = ((unsigned)h) << 16; return v.f;
}

// ---------- block reduction helpers ----------
__device__ __forceinline__ float block_sum_256(float v, float* sm) {
    #pragma unroll
    for (int o = 32; o > 0; o >>= 1) v += __shfl_down(v, o);
    __syncthreads();
    if ((threadIdx.x & 63) == 0) sm[threadIdx.x >> 6] = v;
    __syncthreads();
    return sm[0] + sm[1] + sm[2] + sm[3];
}

__device__ __forceinline__ float block_sum_128(float v, float* sm) {
    #pragma unroll
    for (int o = 32; o > 0; o >>= 1) v += __shfl_down(v, o);
    __syncthreads();
    if ((threadIdx.x & 63) == 0) sm[threadIdx.x >> 6] = v;
    __syncthreads();
    return sm[0] + sm[1];
}

// ---------- fused pe1 + r1: both read x (B,T,12) ----------
__global__ __launch_bounds__(256, 4) void enc1_k(const float* __restrict__ x,
                                                 const float* __restrict__ w1,
                                                 const float* __restrict__ b1,
                                                 const float* __restrict__ w7,
                                                 const float* __restrict__ b7,
                                                 float* __restrict__ out1,
                                                 unsigned short* __restrict__ out7) {
    __shared__ __align__(16) float xs[12][80];
    __shared__ float w1s[12][3][64];
    __shared__ float w7s[12][7][64];
    const int b = blockIdx.y, t0 = blockIdx.x * 64, tid = threadIdx.x;
    const int tx = tid & 15, ty = tid >> 4;
    for (int idx = tid; idx < 70 * 12; idx += 256) {
        int j = idx / 12, ci = idx - j * 12;
        int t = t0 + j - 3;
        xs[ci][j] = (t >= 0 && t < TLEN) ? x[((size_t)b * TLEN + t) * 12 + ci] : 0.f;
    }
    for (int idx = tid; idx < 12 * 3 * 64; idx += 256) {
        int co = idx & 63; int rest = idx >> 6; int k = rest % 3; int ci = rest / 3;
        w1s[ci][k][co] = w1[(co * 12 + ci) * 3 + k];
    }
    for (int idx = tid; idx < 12 * 7 * 64; idx += 256) {
        int co = idx & 63; int rest = idx >> 6; int k = rest % 7; int ci = rest / 7;
        w7s[ci][k][co] = w7[(co * 12 + ci) * 7 + k];
    }
    __syncthreads();
    float a1[4][4] = {}, a7[4][4] = {};
    #pragma unroll 2
    for (int ci = 0; ci < 12; ++ci) {
        float tv[12];
        *(float4*)&tv[0] = *(const float4*)&xs[ci][tx * 4];
        *(float4*)&tv[4] = *(const float4*)&xs[ci][tx * 4 + 4];
        *(float4*)&tv[8] = *(const float4*)&xs[ci][tx * 4 + 8];
        #pragma unroll
        for (int k = 0; k < 7; ++k) {
            float4 wv = *(const float4*)&w7s[ci][k][ty * 4];
            #pragma unroll
            for (int j = 0; j < 4; ++j) {
                float iv = tv[j + k];
                a7[0][j] = fmaf(wv.x, iv, a7[0][j]);
                a7[1][j] = fmaf(wv.y, iv, a7[1][j]);
                a7[2][j] = fmaf(wv.z, iv, a7[2][j]);
                a7[3][j] = fmaf(wv.w, iv, a7[3][j]);
            }
        }
        #pragma unroll
        for (int k = 0; k < 3; ++k) {
            float4 wv = *(const float4*)&w1s[ci][k][ty * 4];
            #pragma unroll
            for (int j = 0; j < 4; ++j) {
                float iv = tv[j + k + 2];
                a1[0][j] = fmaf(wv.x, iv, a1[0][j]);
                a1[1][j] = fmaf(wv.y, iv, a1[1][j]);
                a1[2][j] = fmaf(wv.z, iv, a1[2][j]);
                a1[3][j] = fmaf(wv.w, iv, a1[3][j]);
            }
        }
    }
    float4 b1v4 = *(const float4*)&b1[ty * 4];
    #pragma unroll
    for (int j = 0; j < 4; ++j) {
        int t = t0 + tx * 4 + j;
        if (t < TLEN) {
            float4 o4;
            o4.x = gelu_f(a1[0][j] + b1v4.x);
            o4.y = gelu_f(a1[1][j] + b1v4.y);
            o4.z = gelu_f(a1[2][j] + b1v4.z);
            o4.w = gelu_f(a1[3][j] + b1v4.w);
            *(float4*)&out1[((size_t)(b * TLEN + t)) * 64 + ty * 4] = o4;
        }
    }
    float bv0 = b7[ty * 4], bv1 = b7[ty * 4 + 1], bv2 = b7[ty * 4 + 2], bv3 = b7[ty * 4 + 3];
    #pragma unroll
    for (int j = 0; j < 4; ++j) {
        int t = t0 + tx * 4 + j;
        if (t < TLEN) {
            unsigned long long pk =
                  (unsigned long long)f2bf(gelu_f(a7[0][j] + bv0))
                | ((unsigned long long)f2bf(gelu_f(a7[1][j] + bv1)) << 16)
                | ((unsigned long long)f2bf(gelu_f(a7[2][j] + bv2)) << 32)
                | ((unsigned long long)f2bf(gelu_f(a7[3][j] + bv3)) << 48);
            *(unsigned long long*)&out7[((size_t)(b * TLEN + t)) * 64 + ty * 4] = pk;
        }
    }
}

// ---------- pe_w2 pack ----------
__global__ void pwpack2_k(const float* __restrict__ w,
                          unsigned short* __restrict__ wh,
                          unsigned short* __restrict__ wl) {
    int idx = blockIdx.x * 256 + threadIdx.x;
    if (idx < 3 * 128 * 64) {
        int ci = idx & 63; int rest = idx >> 6; int co = rest & 127; int k = rest >> 7;
        float v = w[((size_t)co * 64 + ci) * 3 + k];
        unsigned short h = f2bf(v);
        wh[idx] = h;
        wl[idx] = f2bf(v - bf2f(h));
    }
}

// ---------- pe2 hi/lo MFMA conv ----------
__global__ __launch_bounds__(256) void pe2m_k(const float* __restrict__ in,
                                              const unsigned short* __restrict__ wh,
                                              const unsigned short* __restrict__ wl,
                                              const float* __restrict__ bias,
                                              float* __restrict__ out) {
    __shared__ __align__(16) unsigned short Ah[130][72];
    __shared__ __align__(16) unsigned short Al[130][72];
    __shared__ __align__(16) unsigned short Wh_s[128][72];
    __shared__ __align__(16) unsigned short Wl_s[128][72];
    const int b = blockIdx.y, t0 = blockIdx.x * 128, tid = threadIdx.x;
    const int w = tid >> 6, lane = tid & 63;
    const int fr = lane & 15, kg = (lane >> 4) * 8;
    for (int u = tid; u < 130 * 8; u += 256) {
        int row = u >> 3, q = u & 7;
        int t = t0 + row - 1;
        short8b h8 = (short8b){0, 0, 0, 0, 0, 0, 0, 0};
        short8b l8 = (short8b){0, 0, 0, 0, 0, 0, 0, 0};
        if (t >= 0 && t < TLEN) {
            const float* src = in + ((size_t)(b * TLEN + t)) * 64 + q * 8;
            float4 v0 = *(const float4*)src;
            float4 v1 = *(const float4*)(src + 4);
            float vv[8] = {v0.x, v0.y, v0.z, v0.w, v1.x, v1.y, v1.z, v1.w};
            #pragma unroll
            for (int e = 0; e < 8; ++e) {
                unsigned short h = f2bf(vv[e]);
                h8[e] = (short)h;
                l8[e] = (short)f2bf(vv[e] - bf2f(h));
            }
        }
        *(short8b*)&Ah[row][q * 8] = h8;
        *(short8b*)&Al[row][q * 8] = l8;
    }
    f32x4 acc[2][8];
    #pragma unroll
    for (int i = 0; i < 2; ++i)
        #pragma unroll
        for (int j = 0; j < 8; ++j) acc[i][j] = (f32x4){0.f, 0.f, 0.f, 0.f};
    for (int k = 0; k < 3; ++k) {
        __syncthreads();
        for (int u = tid; u < 128 * 8; u += 256) {
            int co = u >> 3, q = u & 7;
            *(short8b*)&Wh_s[co][q * 8] = *(const short8b*)&wh[((size_t)(k * 128 + co)) * 64 + q * 8];
            *(short8b*)&Wl_s[co][q * 8] = *(const short8b*)&wl[((size_t)(k * 128 + co)) * 64 + q * 8];
        }
        __syncthreads();
        #pragma unroll
        for (int c32 = 0; c32 < 2; ++c32) {
            short8b ah0 = *(const short8b*)&Ah[w * 32 + fr + k][c32 * 32 + kg];
            short8b ah1 = *(const short8b*)&Ah[w * 32 + 16 + fr + k][c32 * 32 + kg];
            short8b al0 = *(const short8b*)&Al[w * 32 + fr + k][c32 * 32 + kg];
            short8b al1 = *(const short8b*)&Al[w * 32 + 16 + fr + k][c32 * 32 + kg];
            #pragma unroll
            for (int j = 0; j < 8; ++j) {
                short8b bh = *(const short8b*)&Wh_s[j * 16 + fr][c32 * 32 + kg];
                short8b bl = *(const short8b*)&Wl_s[j * 16 + fr][c32 * 32 + kg];
                acc[0][j] = __builtin_amdgcn_mfma_f32_16x16x32_bf16(ah0, bh, acc[0][j], 0, 0, 0);
                acc[0][j] = __builtin_amdgcn_mfma_f32_16x16x32_bf16(ah0, bl, acc[0][j], 0, 0, 0);
                acc[0][j] = __builtin_amdgcn_mfma_f32_16x16x32_bf16(al0, bh, acc[0][j], 0, 0, 0);
                acc[1][j] = __builtin_amdgcn_mfma_f32_16x16x32_bf16(ah1, bh, acc[1][j], 0, 0, 0);
                acc[1][j] = __builtin_amdgcn_mfma_f32_16x16x32_bf16(ah1, bl, acc[1][j], 0, 0, 0);
                acc[1][j] = __builtin_amdgcn_mfma_f32_16x16x32_bf16(al1, bh, acc[1][j], 0, 0, 0);
            }
        }
    }
    const int orow = (lane >> 4) * 4, ocol = lane & 15;
    #pragma unroll
    for (int i = 0; i < 2; ++i)
        #pragma unroll
        for (int j = 0; j < 8; ++j) {
            const int co = j * 16 + ocol;
            const float bv = bias[co];
            #pragma unroll
            for (int r = 0; r < 4; ++r) {
                int t = t0 + w * 32 + i * 16 + orow + r;
                if (t < TLEN) {
                    int s = t / PP, kk = t - s * PP;
                    out[((size_t)(b * SS + s)) * 1152 + kk * 128 + co] = gelu_f(acc[i][j][r] + bv);
                }
            }
        }
}

// ---------- pe_pw pack ----------
__global__ void pwpack3_k(const float* __restrict__ pw,
                          unsigned short* __restrict__ wh,
                          unsigned short* __restrict__ wl) {
    int idx = blockIdx.x * 256 + threadIdx.x;
    if (idx < 128 * 1152) {
        int n = idx % 1152, d = idx / 1152;
        int co = n & 127, kk = n >> 7;
        float v = pw[(size_t)d * 1152 + co * 9 + kk];
        unsigned short h = f2bf(v);
        wh[idx] = h;
        wl[idx] = f2bf(v - bf2f(h));
    }
}

// ---------- patch projection: hi/lo 3-MFMA, 6-way split-K ----------
__global__ __launch_bounds__(256) void pproj3_k(const float* __restrict__ A,
                                                const unsigned short* __restrict__ Wh,
                                                const unsigned short* __restrict__ Wl,
                                                float* __restrict__ Cp,
                                                int M) {
    __shared__ __align__(16) unsigned short Ah[128][40];
    __shared__ __align__(16) unsigned short Al[128][40];
    __shared__ __align__(16) unsigned short Bh[128][40];
    __shared__ __align__(16) unsigned short Bl[128][40];
    const int tid = threadIdx.x;
    const int gm0 = blockIdx.y * 128;
    const int z = blockIdx.z;
    const int w = tid >> 6, lane = tid & 63;
    const int wr0 = (w >> 1) * 64, wc0 = (w & 1) * 64;
    const int srow = tid >> 1, sc = (tid & 1) * 16;
    const int K = 1152;
    const int kb = z * 192;
    f32x4 acc[4][4];
    #pragma unroll
    for (int i = 0; i < 4; ++i)
        #pragma unroll
        for (int j = 0; j < 4; ++j) acc[i][j] = (f32x4){0.f, 0.f, 0.f, 0.f};
    const int fr = lane & 15, kg = (lane >> 4) * 8;
    for (int s = 0; s < 6; ++s) {
        const int k0 = kb + s * 32;
        __syncthreads();
        {
            const float* ga = A + (size_t)(gm0 + srow) * K + k0 + sc;
            #pragma unroll
            for (int g = 0; g < 2; ++g) {
                float4 v0 = *(const float4*)(ga + g * 8);
                float4 v1 = *(const float4*)(ga + g * 8 + 4);
                short8b h8, l8;
                float vv[8] = {v0.x, v0.y, v0.z, v0.w, v1.x, v1.y, v1.z, v1.w};
                #pragma unroll
                for (int e = 0; e < 8; ++e) {
                    unsigned short h = f2bf(vv[e]);
                    h8[e] = (short)h;
                    l8[e] = (short)f2bf(vv[e] - bf2f(h));
                }
                *(short8b*)&Ah[srow][sc + g * 8] = h8;
                *(short8b*)&Al[srow][sc + g * 8] = l8;
            }
            const unsigned short* gh = Wh + (size_t)srow * K + k0 + sc;
            const unsigned short* gl = Wl + (size_t)srow * K + k0 + sc;
            *(short8b*)&Bh[srow][sc] = *(const short8b*)gh;
            *(short8b*)&Bh[srow][sc + 8] = *(const short8b*)(gh + 8);
            *(short8b*)&Bl[srow][sc] = *(const short8b*)gl;
            *(short8b*)&Bl[srow][sc + 8] = *(const short8b*)(gl + 8);
        }
        __syncthreads();
        short8b afh[4], afl[4], bfh[4], bfl[4];
        #pragma unroll
        for (int i = 0; i < 4; ++i) {
            afh[i] = *(const short8b*)&Ah[wr0 + i * 16 + fr][kg];
            afl[i] = *(const short8b*)&Al[wr0 + i * 16 + fr][kg];
            bfh[i] = *(const short8b*)&Bh[wc0 + i * 16 + fr][kg];
            bfl[i] = *(const short8b*)&Bl[wc0 + i * 16 + fr][kg];
        }
        #pragma unroll
        for (int i = 0; i < 4; ++i)
            #pragma unroll
            for (int j = 0; j < 4; ++j) {
                acc[i][j] = __builtin_amdgcn_mfma_f32_16x16x32_bf16(afh[i], bfh[j], acc[i][j], 0, 0, 0);
                acc[i][j] = __builtin_amdgcn_mfma_f32_16x16x32_bf16(afh[i], bfl[j], acc[i][j], 0, 0, 0);
                acc[i][j] = __builtin_amdgcn_mfma_f32_16x16x32_bf16(afl[i], bfh[j], acc[i][j], 0, 0, 0);
            }
    }
    const int orow = (lane >> 4) * 4, ocol = lane & 15;
    float* Cz = Cp + (size_t)z * M * 128;
    #pragma unroll
    for (int i = 0; i < 4; ++i)
        #pragma unroll
        for (int j = 0; j < 4; ++j) {
            const int colg = wc0 + j * 16 + ocol;
            #pragma unroll
            for (int r = 0; r < 4; ++r) {
                const int rowg = gm0 + wr0 + i * 16 + orow + r;
                Cz[(size_t)rowg * 128 + colg] = acc[i][j][r];
            }
        }
}

// ---------- codebook pack ----------
__global__ void cbpack_k(const float* __restrict__ cb,
                         unsigned short* __restrict__ ch,
                         unsigned short* __restrict__ cl) {
    int idx = blockIdx.x * 256 + threadIdx.x;
    if (idx < VV * DP) {
        float v = cb[idx];
        unsigned short h = f2bf(v);
        ch[idx] = h;
        cl[idx] = f2bf(v - bf2f(h));
    }
}

// ---------- VQ distances via hi/lo 3-MFMA + in-wave argmin ----------
__global__ __launch_bounds__(256) void vq3_k(const float* __restrict__ ze,
                                             const unsigned short* __restrict__ ch,
                                             const unsigned short* __restrict__ cl,
                                             const float* __restrict__ cbn,
                                             float* __restrict__ pval,
                                             int* __restrict__ pidx,
                                             int M) {
    __shared__ __align__(16) unsigned short Ah[128][40];
    __shared__ __align__(16) unsigned short Al[128][40];
    __shared__ __align__(16) unsigned short Bh[128][40];
    __shared__ __align__(16) unsigned short Bl[128][40];
    __shared__ float bwv[128][2];
    __shared__ int bwi[128][2];
    const int tid = threadIdx.x;
    const int c0 = blockIdx.x * 128;
    const int gm0 = blockIdx.y * 128;
    const int w = tid >> 6, lane = tid & 63;
    const int wr0 = (w >> 1) * 64, wc0 = (w & 1) * 64;
    const int srow = tid >> 1, sc = (tid & 1) * 16;
    const int fr = lane & 15, kg = (lane >> 4) * 8;
    f32x4 acc[4][4];
    #pragma unroll
    for (int i = 0; i < 4; ++i)
        #pragma unroll
        for (int j = 0; j < 4; ++j) acc[i][j] = (f32x4){0.f, 0.f, 0.f, 0.f};
    for (int s = 0; s < 4; ++s) {
        const int k0 = s * 32;
        __syncthreads();
        {
            const float* ga = ze + (size_t)(gm0 + srow) * DP + k0 + sc;
            #pragma unroll
            for (int g = 0; g < 2; ++g) {
                float4 v0 = *(const float4*)(ga + g * 8);
                float4 v1 = *(const float4*)(ga + g * 8 + 4);
                short8b h8, l8;
                float vv[8] = {v0.x, v0.y, v0.z, v0.w, v1.x, v1.y, v1.z, v1.w};
                #pragma unroll
                for (int e = 0; e < 8; ++e) {
                    unsigned short h = f2bf(vv[e]);
                    h8[e] = (short)h;
                    l8[e] = (short)f2bf(vv[e] - bf2f(h));
                }
                *(short8b*)&Ah[srow][sc + g * 8] = h8;
                *(short8b*)&Al[srow][sc + g * 8] = l8;
            }
            const unsigned short* gh = ch + (size_t)(c0 + srow) * DP + k0 + sc;
            const unsigned short* gl = cl + (size_t)(c0 + srow) * DP + k0 + sc;
            *(short8b*)&Bh[srow][sc] = *(const short8b*)gh;
            *(short8b*)&Bh[srow][sc + 8] = *(const short8b*)(gh + 8);
            *(short8b*)&Bl[srow][sc] = *(const short8b*)gl;
            *(short8b*)&Bl[srow][sc + 8] = *(const short8b*)(gl + 8);
        }
        __syncthreads();
        short8b afh[4], afl[4], bfh[4], bfl[4];
        #pragma unroll
        for (int i = 0; i < 4; ++i) {
            afh[i] = *(const short8b*)&Ah[wr0 + i * 16 + fr][kg];
            afl[i] = *(const short8b*)&Al[wr0 + i * 16 + fr][kg];
            bfh[i] = *(const short8b*)&Bh[wc0 + i * 16 + fr][kg];
            bfl[i] = *(const short8b*)&Bl[wc0 + i * 16 + fr][kg];
        }
        #pragma unroll
        for (int i = 0; i < 4; ++i)
            #pragma unroll
            for (int j = 0; j < 4; ++j) {
                acc[i][j] = __builtin_amdgcn_mfma_f32_16x16x32_bf16(afh[i], bfh[j], acc[i][j], 0, 0, 0);
                acc[i][j] = __builtin_amdgcn_mfma_f32_16x16x32_bf16(afh[i], bfl[j], acc[i][j], 0, 0, 0);
                acc[i][j] = __builtin_amdgcn_mfma_f32_16x16x32_bf16(afl[i], bfh[j], acc[i][j], 0, 0, 0);
            }
    }
    const int orow = (lane >> 4) * 4, ocol = lane & 15;
    #pragma unroll
    for (int i = 0; i < 4; ++i)
        #pragma unroll
        for (int r = 0; r < 4; ++r) {
            int row = wr0 + i * 16 + orow + r;
            float bv = 1e30f; int bi = 0;
            #pragma unroll
            for (int j = 0; j < 4; ++j) {
                int col = c0 + wc0 + j * 16 + ocol;
                float d = cbn[col] - 2.0f * acc[i][j][r];
                if (d < bv || (d == bv && col < bi)) { bv = d; bi = col; }
            }
            #pragma unroll
            for (int o = 1; o < 16; o <<= 1) {
                float ov = __shfl_xor(bv, o);
                int oi = __shfl_xor(bi, o);
                if (ov < bv || (ov == bv && oi < bi)) { bv = ov; bi = oi; }
            }
            if (ocol == 0) { bwv[row][w & 1] = bv; bwi[row][w & 1] = bi; }
        }
    __syncthreads();
    if (tid < 128) {
        float v0 = bwv[tid][0], v1 = bwv[tid][1];
        int i0 = bwi[tid][0], i1 = bwi[tid][1];
        bool sel = (v1 < v0) || (v1 == v0 && i1 < i0);
        pval[(size_t)blockIdx.x * M + gm0 + tid] = sel ? v1 : v0;
        pidx[(size_t)blockIdx.x * M + gm0 + tid] = sel ? i1 : i0;
    }
}

// ---------- VQ finish ----------
__global__ __launch_bounds__(128) void vqfin_k(const float* __restrict__ ze,
                                               const float* __restrict__ cb,
                                               const float* __restrict__ pval,
                                               const int* __restrict__ pidx,
                                               unsigned short* __restrict__ zqb,
                                               float* __restrict__ vqs,
                                               int M) {
    const int row = blockIdx.x, tid = threadIdx.x;
    __shared__ float sm[2];
    __shared__ int tok_s;
    if (tid == 0) {
        float bv = pval[row]; int bi = pidx[row];
        #pragma unroll
        for (int z = 1; z < 4; ++z) {
            float v = pval[(size_t)z * M + row]; int ix = pidx[(size_t)z * M + row];
            if (v < bv || (v == bv && ix < bi)) { bv = v; bi = ix; }
        }
        tok_s = bi;
    }
    __syncthreads();
    int tok = tok_s;
    float qv = cb[(size_t)tok * DP + tid];
    float zv = ze[(size_t)row * DP + tid];
    zqb[(size_t)row * DP + tid] = f2bf(qv);
    float d = qv - zv;
    float tot = block_sum_128(d * d, sm);
    if (tid == 0) vqs[row] = tot;
}

// ---------- bf16 MFMA implicit-GEMM conv ----------
template <int CI, int K, int PAD>
__global__ __launch_bounds__(256) void mfconv_k(const unsigned short* __restrict__ in,
                                                const unsigned short* __restrict__ wpk,
                                                const float* __restrict__ bias,
                                                unsigned short* __restrict__ out) {
    constexpr int CIC = (CI > 64) ? 64 : CI;
    constexpr int NCH = CI / CIC;
    constexpr int TROWS = 128 + K - 1;
    constexpr int CQ = CIC / 8;
    __shared__ __align__(16) unsigned short in_s[TROWS][CIC + 8];
    __shared__ __align__(16) unsigned short w_s[K][64][CIC + 8];
    const int b = blockIdx.z;
    const int t0 = blockIdx.x * 128;
    const int tid = threadIdx.x;
    const int w = tid >> 6, lane = tid & 63;
    const int fr = lane & 15, kg = (lane >> 4) * 8;
    f32x4 acc[2][4];
    #pragma unroll
    for (int i = 0; i < 2; ++i)
        #pragma unroll
        for (int j = 0; j < 4; ++j) acc[i][j] = (f32x4){0.f, 0.f, 0.f, 0.f};
    for (int ch = 0; ch < NCH; ++ch) {
        const int c0 = ch * CIC;
        if (ch) __syncthreads();
        for (int u = tid; u < TROWS * CQ; u += 256) {
            int row = u / CQ, q = u - row * CQ;
            int t = t0 + row - PAD;
            short8b v = (short8b){0, 0, 0, 0, 0, 0, 0, 0};
            if (t >= 0 && t < TLEN)
                v = *(const short8b*)&in[((size_t)(b * TLEN + t)) * CI + c0 + q * 8];
            *(short8b*)&in_s[row][q * 8] = v;
        }
        for (int u = tid; u < K * 64 * CQ; u += 256) {
            int q = u % CQ; int rest = u / CQ; int co = rest & 63; int k = rest >> 6;
            *(short8b*)&w_s[k][co][q * 8] =
                *(const short8b*)&wpk[((size_t)(k * 64 + co)) * CI + c0 + q * 8];
        }
        __syncthreads();
        #pragma unroll
        for (int k = 0; k < K; ++k) {
            #pragma unroll
            for (int c32 = 0; c32 < CIC / 32; ++c32) {
                short8b a0 = *(const short8b*)&in_s[w * 32 + fr + k][c32 * 32 + kg];
                short8b a1 = *(const short8b*)&in_s[w * 32 + 16 + fr + k][c32 * 32 + kg];
                short8b b0 = *(const short8b*)&w_s[k][fr][c32 * 32 + kg];
                short8b b1 = *(const short8b*)&w_s[k][16 + fr][c32 * 32 + kg];
                short8b b2 = *(const short8b*)&w_s[k][32 + fr][c32 * 32 + kg];
                short8b b3 = *(const short8b*)&w_s[k][48 + fr][c32 * 32 + kg];
                acc[0][0] = __builtin_amdgcn_mfma_f32_16x16x32_bf16(a0, b0, acc[0][0], 0, 0, 0);
                acc[0][1] = __builtin_amdgcn_mfma_f32_16x16x32_bf16(a0, b1, acc[0][1], 0, 0, 0);
                acc[0][2] = __builtin_amdgcn_mfma_f32_16x16x32_bf16(a0, b2, acc[0][2], 0, 0, 0);
                acc[0][3] = __builtin_amdgcn_mfma_f32_16x16x32_bf16(a0, b3, acc[0][3], 0, 0, 0);
                acc[1][0] = __builtin_amdgcn_mfma_f32_16x16x32_bf16(a1, b0, acc[1][0], 0, 0, 0);
                acc[1][1] = __builtin_amdgcn_mfma_f32_16x16x32_bf16(a1, b1, acc[1][1], 0, 0, 0);
                acc[1][2] = __builtin_amdgcn_mfma_f32_16x16x32_bf16(a1, b2, acc[1][2], 0, 0, 0);
                acc[1][3] = __builtin_amdgcn_mfma_f32_16x16x32_bf16(a1, b3, acc[1][3], 0, 0, 0);
            }
        }
    }
    const int orow = (lane >> 4) * 4, ocol = lane & 15;
    #pragma unroll
    for (int i = 0; i < 2; ++i)
        #pragma unroll
        for (int j = 0; j < 4; ++j) {
            const int co = j * 16 + ocol;
            const float bv = bias[co];
            #pragma unroll
            for (int r = 0; r < 4; ++r) {
                int t = t0 + w * 32 + i * 16 + orow + r;
                if (t < TLEN)
                    out[((size_t)(b * TLEN + t)) * 64 + co] = f2bf(gelu_f(acc[i][j][r] + bv));
            }
        }
}

// ---------- bf16 MFMA GEMM, 128x128 tile ----------
template <int ACT, int RES, int OUTBF>
__global__ __launch_bounds__(256) void bgemm_k(const unsigned short* __restrict__ A,
                                               const unsigned short* __restrict__ W,
                                               const float* __restrict__ bias,
                                               const float* __restrict__ res,
                                               void* __restrict__ Cv,
                                               int M, int N, int K) {
    __shared__ __align__(16) unsigned short As[128][40];
    __shared__ __align__(16) unsigned short Bs[128][40];
    const int tid = threadIdx.x;
    const int gm0 = blockIdx.y * 128, gn0 = blockIdx.x * 128;
    const int w = tid >> 6, lane = tid & 63;
    const int wr0 = (w >> 1) * 64, wc0 = (w & 1) * 64;
    const int srow = tid >> 1, sc = (tid & 1) * 16;
    const unsigned short* ga = A + (size_t)(gm0 + srow) * K + sc;
    const unsigned short* gb = W + (size_t)(gn0 + srow) * K + sc;
    short8b ra0 = *(const short8b*)(ga), ra1 = *(const short8b*)(ga + 8);
    short8b rb0 = *(const short8b*)(gb), rb1 = *(const short8b*)(gb + 8);
    f32x4 acc[4][4];
    #pragma unroll
    for (int i = 0; i < 4; ++i)
        #pragma unroll
        for (int j = 0; j < 4; ++j) acc[i][j] = (f32x4){0.f, 0.f, 0.f, 0.f};
    const int fr = lane & 15, kg = (lane >> 4) * 8;
    const int nstep = K >> 5;
    for (int s = 0; s < nstep; ++s) {
        __syncthreads();
        *(short8b*)&As[srow][sc] = ra0; *(short8b*)&As[srow][sc + 8] = ra1;
        *(short8b*)&Bs[srow][sc] = rb0; *(short8b*)&Bs[srow][sc + 8] = rb1;
        __syncthreads();
        if (s + 1 < nstep) {
            ga += 32; gb += 32;
            ra0 = *(const short8b*)(ga); ra1 = *(const short8b*)(ga + 8);
            rb0 = *(const short8b*)(gb); rb1 = *(const short8b*)(gb + 8);
        }
        short8b af[4], bf[4];
        #pragma unroll
        for (int i = 0; i < 4; ++i) {
            af[i] = *(const short8b*)&As[wr0 + i * 16 + fr][kg];
            bf[i] = *(const short8b*)&Bs[wc0 + i * 16 + fr][kg];
        }
        #pragma unroll
        for (int i = 0; i < 4; ++i)
            #pragma unroll
            for (int j = 0; j < 4; ++j)
                acc[i][j] = __builtin_amdgcn_mfma_f32_16x16x32_bf16(af[i], bf[j], acc[i][j], 0, 0, 0);
    }
    const int orow = (lane >> 4) * 4, ocol = lane & 15;
    #pragma unroll
    for (int i = 0; i < 4; ++i) {
        #pragma unroll
        for (int j = 0; j < 4; ++j) {
            const int colg = gn0 + wc0 + j * 16 + ocol;
            const float bsv = bias[colg];
            #pragma unroll
            for (int r = 0; r < 4; ++r) {
                const int rowg = gm0 + wr0 + i * 16 + orow + r;
                float v = acc[i][j][r] + bsv;
                if (ACT) v = gelu_f(v);
                if (RES) v += res[(size_t)rowg * N + colg];
                if (OUTBF) ((unsigned short*)Cv)[(size_t)rowg * N + colg] = f2bf(v);
                else ((float*)Cv)[(size_t)rowg * N + colg] = v;
            }
        }
    }
}

// ---------- bf16 MFMA GEMM, 64x128 tile (token projection) ----------
template <int ACT, int RES, int OUTBF>
__global__ __launch_bounds__(256) void bgemm64_k(const unsigned short* __restrict__ A,
                                                 const unsigned short* __restrict__ W,
                                                 const float* __restrict__ bias,
                                                 const float* __restrict__ res,
                                                 void* __restrict__ Cv,
                                                 int M, int N, int K) {
    __shared__ __align__(16) unsigned short As[64][40];
    __shared__ __align__(16) unsigned short Bs[128][40];
    const int tid = threadIdx.x;
    const int gm0 = blockIdx.y * 64, gn0 = blockIdx.x * 128;
    const int w = tid >> 6, lane = tid & 63;
    const int wc0 = w * 32;
    const int arow = tid >> 2, ac = (tid & 3) * 8;
    const int brow = tid >> 1, bc = (tid & 1) * 16;
    const unsigned short* ga = A + (size_t)(gm0 + arow) * K + ac;
    const unsigned short* gb = W + (size_t)(gn0 + brow) * K + bc;
    short8b ra0 = *(const short8b*)(ga);
    short8b rb0 = *(const short8b*)(gb), rb1 = *(const short8b*)(gb + 8);
    f32x4 acc[4][2];
    #pragma unroll
    for (int i = 0; i < 4; ++i)
        #pragma unroll
        for (int j = 0; j < 2; ++j) acc[i][j] = (f32x4){0.f, 0.f, 0.f, 0.f};
    const int fr = lane & 15, kg = (lane >> 4) * 8;
    const int nstep = K >> 5;
    for (int s = 0; s < nstep; ++s) {
        __syncthreads();
        *(short8b*)&As[arow][ac] = ra0;
        *(short8b*)&Bs[brow][bc] = rb0; *(short8b*)&Bs[brow][bc + 8] = rb1;
        __syncthreads();
        if (s + 1 < nstep) {
            ga += 32; gb += 32;
            ra0 = *(const short8b*)(ga);
            rb0 = *(const short8b*)(gb); rb1 = *(const short8b*)(gb + 8);
        }
        short8b af[4], bf[2];
        #pragma unroll
        for (int i = 0; i < 4; ++i) af[i] = *(const short8b*)&As[i * 16 + fr][kg];
        #pragma unroll
        for (int j = 0; j < 2; ++j) bf[j] = *(const short8b*)&Bs[wc0 + j * 16 + fr][kg];
        #pragma unroll
        for (int i = 0; i < 4; ++i)
            #pragma unroll
            for (int j = 0; j < 2; ++j)
                acc[i][j] = __builtin_amdgcn_mfma_f32_16x16x32_bf16(af[i], bf[j], acc[i][j], 0, 0, 0);
    }
    const int orow = (lane >> 4) * 4, ocol = lane & 15;
    #pragma unroll
    for (int i = 0; i < 4; ++i) {
        #pragma unroll
        for (int j = 0; j < 2; ++j) {
            const int colg = gn0 + wc0 + j * 16 + ocol;
            const float bsv = bias[colg];
            #pragma unroll
            for (int r = 0; r < 4; ++r) {
                const int rowg = gm0 + i * 16 + orow + r;
                float v = acc[i][j][r] + bsv;
                if (ACT) v = gelu_f(v);
                if (RES) v += res[(size_t)rowg * N + colg];
                if (OUTBF) ((unsigned short*)Cv)[(size_t)rowg * N + colg] = f2bf(v);
                else ((float*)Cv)[(size_t)rowg * N + colg] = v;
            }
        }
    }
}

// ---------- fused GEMM(N=256) + residual + LayerNorm: 32x256 tile ----------
// hbout = acc + bias + res (fp32); xout = LN(hbout) bf16 with (g,bb).
__global__ __launch_bounds__(256) void bgemmln_k(const unsigned short* __restrict__ A,
                                                 const unsigned short* __restrict__ W,
                                                 const float* __restrict__ bias,
                                                 const float* __restrict__ res,
                                                 float* __restrict__ hbout,
                                                 const float* __restrict__ g,
                                                 const float* __restrict__ bb,
                                                 unsigned short* __restrict__ xout,
                                                 int M, int K) {
    __shared__ __align__(16) char smem[33792];
    unsigned short (*As)[40] = (unsigned short(*)[40])smem;           // 32x40x2 = 2560
    unsigned short (*Bs)[40] = (unsigned short(*)[40])(smem + 2560);  // 256x40x2 = 20480
    float (*Ct)[264] = (float(*)[264])smem;                           // 32x264x4 = 33792
    const int tid = threadIdx.x;
    const int gm0 = blockIdx.x * 32;
    const int w = tid >> 6, lane = tid & 63;
    const int wc0 = w * 64;
    const int fr = lane & 15, kg = (lane >> 4) * 8;
    const unsigned short* ga = A + (size_t)(gm0 + (tid >> 2)) * K + (tid & 3) * 8;
    const unsigned short* gb = W + (size_t)tid * K;
    short8b ra;
    if (tid < 128) ra = *(const short8b*)ga;
    short8b rb0 = *(const short8b*)(gb), rb1 = *(const short8b*)(gb + 8);
    short8b rb2 = *(const short8b*)(gb + 16), rb3 = *(const short8b*)(gb + 24);
    f32x4 acc[2][4];
    #pragma unroll
    for (int i = 0; i < 2; ++i)
        #pragma unroll
        for (int j = 0; j < 4; ++j) acc[i][j] = (f32x4){0.f, 0.f, 0.f, 0.f};
    const int nstep = K >> 5;
    for (int s = 0; s < nstep; ++s) {
        __syncthreads();
        if (tid < 128) *(short8b*)&As[tid >> 2][(tid & 3) * 8] = ra;
        *(short8b*)&Bs[tid][0] = rb0;  *(short8b*)&Bs[tid][8] = rb1;
        *(short8b*)&Bs[tid][16] = rb2; *(short8b*)&Bs[tid][24] = rb3;
        __syncthreads();
        if (s + 1 < nstep) {
            ga += 32; gb += 32;
            if (tid < 128) ra = *(const short8b*)ga;
            rb0 = *(const short8b*)(gb);      rb1 = *(const short8b*)(gb + 8);
            rb2 = *(const short8b*)(gb + 16); rb3 = *(const short8b*)(gb + 24);
        }
        short8b af[2], bf[4];
        af[0] = *(const short8b*)&As[fr][kg];
        af[1] = *(const short8b*)&As[16 + fr][kg];
        #pragma unroll
        for (int j = 0; j < 4; ++j) bf[j] = *(const short8b*)&Bs[wc0 + j * 16 + fr][kg];
        #pragma unroll
        for (int i = 0; i < 2; ++i)
            #pragma unroll
            for (int j = 0; j < 4; ++j)
                acc[i][j] = __builtin_amdgcn_mfma_f32_16x16x32_bf16(af[i], bf[j], acc[i][j], 0, 0, 0);
    }
    __syncthreads();   // staging reads done; reuse smem as Ct
    const int orow = (lane >> 4) * 4, ocol = lane & 15;
    #pragma unroll
    for (int i = 0; i < 2; ++i)
        #pragma unroll
        for (int j = 0; j < 4; ++j) {
            const int col = wc0 + j * 16 + ocol;
            const float bsv = bias[col];
            #pragma unroll
            for (int r = 0; r < 4; ++r) {
                const int row = i * 16 + orow + r;
                float v = acc[i][j][r] + bsv + res[(size_t)(gm0 + row) * DM + col];
                hbout[(size_t)(gm0 + row) * DM + col] = v;
                Ct[row][col] = v;
            }
        }
    __syncthreads();
    #pragma unroll
    for (int rr = 0; rr < 8; ++rr) {
        const int row = w * 8 + rr;
        float4 v = *(const float4*)&Ct[row][lane * 4];
        float s = v.x + v.y + v.z + v.w;
        #pragma unroll
        for (int o = 1; o < 64; o <<= 1) s += __shfl_xor(s, o);
        float mean = s * (1.0f / DM);
        float dx = v.x - mean, dy = v.y - mean, dz = v.z - mean, dw = v.w - mean;
        float vv = dx * dx + dy * dy + dz * dz + dw * dw;
        #pragma unroll
        for (int o = 1; o < 64; o <<= 1) vv += __shfl_xor(vv, o);
        float rstd = rsqrtf(vv * (1.0f / DM) + 1e-5f);
        float4 gv = *(const float4*)&g[lane * 4];
        float4 bv = *(const float4*)&bb[lane * 4];
        unsigned long long pk = (unsigned long long)f2bf(dx * rstd * gv.x + bv.x)
                              | ((unsigned long long)f2bf(dy * rstd * gv.y + bv.y) << 16)
                              | ((unsigned long long)f2bf(dz * rstd * gv.z + bv.z) << 32)
                              | ((unsigned long long)f2bf(dw * rstd * gv.w + bv.w) << 48);
        *(unsigned long long*)&xout[(size_t)(gm0 + row) * DM + lane * 4] = pk;
    }
}

// ---------- weight fp32 -> bf16 ----------
__global__ void tobf_k(const float* __restrict__ in, unsigned short* __restrict__ out, int n) {
    int i = blockIdx.x * 256 + threadIdx.x;
    if (i < n) out[i] = f2bf(in[i]);
}

__global__ void cpack_k(const float* __restrict__ w, unsigned short* __restrict__ out,
                        int Co, int CI, int K) {
    int idx = blockIdx.x * 256 + threadIdx.x;
    if (idx < Co * CI * K) {
        int ci = idx % CI; int rest = idx / CI; int co = rest % Co; int k = rest / Co;
        out[idx] = f2bf(w[((size_t)co * CI + ci) * K + k]);
    }
}

__global__ void upwt2_k(const float* __restrict__ w, const float* __restrict__ bsrc,
                        unsigned short* __restrict__ out, float* __restrict__ b2) {
    int idx = blockIdx.x * 256 + threadIdx.x;
    if (idx < 1152 * 256) {
        int d = idx & 255, n = idx >> 8;
        int o = n & 127, k = n >> 7;
        out[(size_t)n * 256 + d] = f2bf(w[(size_t)d * 1152 + o * 9 + k]);
    }
    if (idx < 1152) b2[idx] = bsrc[idx & 127];
}

// ---------- LayerNorm over 128 with 6-way split-K partial sum + bias ----------
__global__ __launch_bounds__(128) void ln128s_k(const float* __restrict__ part,
                                                const float* __restrict__ bias,
                                                const float* __restrict__ g,
                                                const float* __restrict__ bb,
                                                float* __restrict__ out,
                                                int M) {
    int row = blockIdx.x, tid = threadIdx.x;
    __shared__ float sm[2];
    size_t stride = (size_t)M * DP;
    size_t base = (size_t)row * DP + tid;
    float v = bias[tid];
    #pragma unroll
    for (int s2 = 0; s2 < 6; ++s2) v += part[base + (size_t)s2 * stride];
    float mean = block_sum_128(v, sm) * (1.0f / DP);
    float d = v - mean;
    float var = block_sum_128(d * d, sm) * (1.0f / DP);
    out[(size_t)row * DP + tid] = d * rsqrtf(var + 1e-5f) * g[tid] + bb[tid];
}

// ---------- codebook norms ----------
__global__ void cbnorm_k(const float* __restrict__ cb, float* __restrict__ cbn) {
    int c = blockIdx.x * 256 + threadIdx.x;
    if (c < VV) {
        const float* cr = cb + (size_t)c * DP;
        float s = 0;
        for (int i = 0; i < DP; ++i) s += cr[i] * cr[i];
        cbn[c] = s;
    }
}

__global__ void vqreduce_k(const float* __restrict__ vqs, float* __restrict__ out) {
    float s = 0;
    for (int i = threadIdx.x; i < BATCH * SS; i += 256) s += vqs[i];
    __shared__ float sm[4];
    s = block_sum_256(s, sm);
    if (threadIdx.x == 0) out[0] = s * (1.25f / (float)(BATCH * SS * DP));
}

// ---------- wave-per-row LayerNorm over 256 (shfl-only) ----------
template <int OUTBF>
__global__ __launch_bounds__(256) void lnw_k(const float* __restrict__ in,
                                             const float* __restrict__ g,
                                             const float* __restrict__ bb,
                                             void* __restrict__ out) {
    const int row = blockIdx.x * 4 + (threadIdx.x >> 6);
    const int lane = threadIdx.x & 63;
    float4 v = *(const float4*)&in[(size_t)row * DM + lane * 4];
    float s = v.x + v.y + v.z + v.w;
    #pragma unroll
    for (int o = 1; o < 64; o <<= 1) s += __shfl_xor(s, o);
    float mean = s * (1.0f / DM);
    float dx = v.x - mean, dy = v.y - mean, dz = v.z - mean, dw = v.w - mean;
    float vv = dx * dx + dy * dy + dz * dz + dw * dw;
    #pragma unroll
    for (int o = 1; o < 64; o <<= 1) vv += __shfl_xor(vv, o);
    float rstd = rsqrtf(vv * (1.0f / DM) + 1e-5f);
    float4 gv = *(const float4*)&g[lane * 4];
    float4 bv = *(const float4*)&bb[lane * 4];
    float o0 = dx * rstd * gv.x + bv.x;
    float o1 = dy * rstd * gv.y + bv.y;
    float o2 = dz * rstd * gv.z + bv.z;
    float o3 = dw * rstd * gv.w + bv.w;
    if (OUTBF) {
        unsigned long long pk = (unsigned long long)f2bf(o0)
                              | ((unsigned long long)f2bf(o1) << 16)
                              | ((unsigned long long)f2bf(o2) << 32)
                              | ((unsigned long long)f2bf(o3) << 48);
        *(unsigned long long*)((unsigned short*)out + (size_t)row * DM + lane * 4) = pk;
    } else {
        float4 o4; o4.x = o0; o4.y = o1; o4.z = o2; o4.w = o3;
        *(float4*)((float*)out + (size_t)row * DM + lane * 4) = o4;
    }
}

// ---------- fused flash MFMA attention, 64-q blocks (proven variant) ----------
__global__ __launch_bounds__(256) void fattn_k(const unsigned short* __restrict__ qkv,
                                               const float* __restrict__ slopes,
                                               unsigned short* __restrict__ out) {
    __shared__ __align__(16) unsigned short Qs[64][40];
    __shared__ __align__(16) unsigned short Ks[64][40];
    __shared__ __align__(16) unsigned short Vt[32][72];
    __shared__ __align__(16) unsigned short Ps[4][16][72];
    const int qb = blockIdx.x, hh = blockIdx.y, b = blockIdx.z;
    const int tid = threadIdx.x;
    const int w = tid >> 6, lane = tid & 63;
    const int lr = lane & 15, lg = lane >> 4;
    const float slope = fabsf(slopes[hh]);
    const unsigned short* base = qkv + (size_t)b * SS * (3 * DM);
    {
        int row = tid >> 2, c = (tid & 3) * 8;
        int q = qb * 64 + row; q = q < SS ? q : SS - 1;
        *(short8b*)&Qs[row][c] = *(const short8b*)(base + (size_t)q * (3 * DM) + hh * HD + c);
    }
    __syncthreads();
    const short8b qa = *(const short8b*)&Qs[w * 16 + lr][lg * 8];
    float m_run[4] = {-1e30f, -1e30f, -1e30f, -1e30f};
    float l_run[4] = {0.f, 0.f, 0.f, 0.f};
    f32x4 of0 = (f32x4){0.f, 0.f, 0.f, 0.f}, of1 = (f32x4){0.f, 0.f, 0.f, 0.f};
    const int qg0 = qb * 64 + w * 16 + lg * 4;
    for (int kt = 0; kt < SS; kt += 64) {
        const int tl = (SS - kt) < 64 ? (SS - kt) : 64;
        const int nks = tl >> 4;
        __syncthreads();
        {
            int row = tid >> 2, c = (tid & 3) * 8;
            if (row < tl) {
                *(short8b*)&Ks[row][c] =
                    *(const short8b*)(base + (size_t)(kt + row) * (3 * DM) + DM + hh * HD + c);
                short8b v8 = *(const short8b*)(base + (size_t)(kt + row) * (3 * DM) + 2 * DM + hh * HD + c);
                #pragma unroll
                for (int j = 0; j < 8; ++j) Vt[c + j][row] = ((unsigned short*)&v8)[j];
            }
        }
        __syncthreads();
        f32x4 sf[4];
        #pragma unroll
        for (int ks = 0; ks < 4; ++ks) {
            if (ks < nks) {
                short8b kb = *(const short8b*)&Ks[ks * 16 + lr][lg * 8];
                sf[ks] = __builtin_amdgcn_mfma_f32_16x16x32_bf16(qa, kb, (f32x4){0.f, 0.f, 0.f, 0.f}, 0, 0, 0);
            }
        }
        float pv[4][4];
        #pragma unroll
        for (int r = 0; r < 4; ++r) {
            float tmax = -1e30f;
            #pragma unroll
            for (int ks = 0; ks < 4; ++ks) {
                if (ks < nks) {
                    float sv = sf[ks][r] * 0.17677669529663687f
                             - slope * fabsf((float)(qg0 + r - (kt + ks * 16 + lr)));
                    pv[ks][r] = sv;
                    tmax = fmaxf(tmax, sv);
                }
            }
            #pragma unroll
            for (int o = 1; o < 16; o <<= 1) tmax = fmaxf(tmax, __shfl_xor(tmax, o));
            float mnew = fmaxf(m_run[r], tmax);
            float sc = __expf(m_run[r] - mnew);
            m_run[r] = mnew;
            float tsum = 0.f;
            #pragma unroll
            for (int ks = 0; ks < 4; ++ks) {
                if (ks < nks) {
                    float e = __expf(pv[ks][r] - mnew);
                    pv[ks][r] = e;
                    tsum += e;
                }
            }
            #pragma unroll
            for (int o = 1; o < 16; o <<= 1) tsum += __shfl_xor(tsum, o);
            l_run[r] = l_run[r] * sc + tsum;
            of0[r] *= sc; of1[r] *= sc;
        }
        #pragma unroll
        for (int ks = 0; ks < 4; ++ks)
            #pragma unroll
            for (int r = 0; r < 4; ++r)
                Ps[w][lg * 4 + r][ks * 16 + lr] = (ks < nks) ? f2bf(pv[ks][r]) : (unsigned short)0;
        #pragma unroll
        for (int kc = 0; kc < 64; kc += 32) {
            if (kc < nks * 16) {
                short8b pa = *(const short8b*)&Ps[w][lr][kc + lg * 8];
                short8b vb0 = *(const short8b*)&Vt[lr][kc + lg * 8];
                short8b vb1 = *(const short8b*)&Vt[16 + lr][kc + lg * 8];
                of0 = __builtin_amdgcn_mfma_f32_16x16x32_bf16(pa, vb0, of0, 0, 0, 0);
                of1 = __builtin_amdgcn_mfma_f32_16x16x32_bf16(pa, vb1, of1, 0, 0, 0);
            }
        }
    }
    #pragma unroll
    for (int r = 0; r < 4; ++r) {
        int q = qg0 + r;
        if (q < SS) {
            float inv = 1.0f / l_run[r];
            out[((size_t)(b * SS + q)) * DM + hh * HD + lr] = f2bf(of0[r] * inv);
            out[((size_t)(b * SS + q)) * DM + hh * HD + 16 + lr] = f2bf(of1[r] * inv);
        }
    }
}

// ---------- final: d2 conv + r4 1x1 conv + alpha blend; inputs bf16 TM ----------
__global__ __launch_bounds__(256) void final2_k(const unsigned short* __restrict__ ud1,
                                                const unsigned short* __restrict__ r3i,
                                                const float* __restrict__ d2w,
                                                const float* __restrict__ d2b,
                                                const float* __restrict__ r4w,
                                                const float* __restrict__ r4b,
                                                const float* __restrict__ alpha,
                                                float* __restrict__ out) {
    __shared__ float u_s[64][66];
    __shared__ float r_s[64][64];
    __shared__ float wd_s[64][3][12];
    __shared__ float wr_s[64][12];
    __shared__ float o_s[64][12];
    const int b = blockIdx.z, t0 = blockIdx.x * 64, tid = threadIdx.x;
    for (int u2 = tid; u2 < 66 * 8; u2 += 256) {
        int j = u2 >> 3, q = u2 & 7;
        int t = t0 + j - 1;
        short8b v = (short8b){0, 0, 0, 0, 0, 0, 0, 0};
        if (t >= 0 && t < TLEN) v = *(const short8b*)&ud1[((size_t)(b * TLEN + t)) * 64 + q * 8];
        #pragma unroll
        for (int i = 0; i < 8; ++i) u_s[q * 8 + i][j] = bf2f((unsigned short)v[i]);
    }
    for (int u2 = tid; u2 < 64 * 8; u2 += 256) {
        int j = u2 >> 3, q = u2 & 7;
        int t = t0 + j;
        short8b v = (short8b){0, 0, 0, 0, 0, 0, 0, 0};
        if (t < TLEN) v = *(const short8b*)&r3i[((size_t)(b * TLEN + t)) * 64 + q * 8];
        #pragma unroll
        for (int i = 0; i < 8; ++i) r_s[q * 8 + i][j] = bf2f((unsigned short)v[i]);
    }
    for (int idx = tid; idx < 64 * 3 * 12; idx += 256) {
        int l = idx % 12, k = (idx / 12) % 3, ci = idx / 36;
        wd_s[ci][k][l] = d2w[(l * 64 + ci) * 3 + k];
    }
    for (int idx = tid; idx < 64 * 12; idx += 256) {
        int l = idx % 12, ci = idx / 12;
        wr_s[ci][l] = r4w[l * 64 + ci];
    }
    __syncthreads();
    const int tl = tid & 63, lg = tid >> 6;
    float accD[3] = {}, accR[3] = {};
    for (int ci = 0; ci < 64; ++ci) {
        float a0 = u_s[ci][tl], a1 = u_s[ci][tl + 1], a2 = u_s[ci][tl + 2];
        float rv = r_s[ci][tl];
        #pragma unroll
        for (int c = 0; c < 3; ++c) {
            int l = lg * 3 + c;
            accD[c] += a0 * wd_s[ci][0][l] + a1 * wd_s[ci][1][l] + a2 * wd_s[ci][2][l];
            accR[c] = fmaf(rv, wr_s[ci][l], accR[c]);
        }
    }
    float al = alpha[0];
    #pragma unroll
    for (int c = 0; c < 3; ++c) {
        int l = lg * 3 + c;
        o_s[tl][l] = accD[c] + d2b[l] + al * (accR[c] + r4b[l]);
    }
    __syncthreads();
    for (int idx = tid; idx < 64 * 12; idx += 256) {
        int t = t0 + idx / 12;
        if (t < TLEN) out[((size_t)b * TLEN + t) * 12 + idx % 12] = o_s[idx / 12][idx % 12];
    }
}

extern "C" void kernel_launch(void* const* d_in, const int* in_sizes, int n_in,
                              void* d_out, int out_size, void* d_ws, size_t ws_size,
                              hipStream_t stream) {
    const float* x     = (const float*)d_in[0];
    const float* pe_w1 = (const float*)d_in[1];
    const float* pe_b1 = (const float*)d_in[2];
    const float* pe_w2 = (const float*)d_in[3];
    const float* pe_b2 = (const float*)d_in[4];
    const float* pe_pw = (const float*)d_in[5];
    const float* pe_pb = (const float*)d_in[6];
    const float* pe_g  = (const float*)d_in[7];
    const float* pe_bb = (const float*)d_in[8];
    const float* cb    = (const float*)d_in[9];
    const float* tp_w  = (const float*)d_in[10];
    const float* tp_b  = (const float*)d_in[11];
    const float* tp_g  = (const float*)d_in[12];
    const float* tp_bb = (const float*)d_in[13];
    const float* ln1_g = (const float*)d_in[14];
    const float* ln1_b = (const float*)d_in[15];
    const float* inw   = (const float*)d_in[16];
    const float* inb   = (const float*)d_in[17];
    const float* ow    = (const float*)d_in[18];
    const float* ob    = (const float*)d_in[19];
    const float* ln2_g = (const float*)d_in[20];
    const float* ln2_b = (const float*)d_in[21];
    const float* f1w   = (const float*)d_in[22];
    const float* f1b   = (const float*)d_in[23];
    const float* f2w   = (const float*)d_in[24];
    const float* f2b   = (const float*)d_in[25];
    const float* slopes= (const float*)d_in[26];
    const float* fn_g  = (const float*)d_in[27];
    const float* fn_b  = (const float*)d_in[28];
    const float* up_w  = (const float*)d_in[29];
    const float* up_b  = (const float*)d_in[30];
    const float* d1w   = (const float*)d_in[31];
    const float* d1b   = (const float*)d_in[32];
    const float* d2w   = (const float*)d_in[33];
    const float* d2b   = (const float*)d_in[34];
    const float* r1w   = (const float*)d_in[35];
    const float* r1b   = (const float*)d_in[36];
    const float* r2w   = (const float*)d_in[37];
    const float* r2b   = (const float*)d_in[38];
    const float* r3w   = (const float*)d_in[39];
    const float* r3b   = (const float*)d_in[40];
    const float* r4w   = (const float*)d_in[41];
    const float* r4b   = (const float*)d_in[42];
    const float* alpha = (const float*)d_in[43];

    float* W = (float*)d_ws;
    size_t off = 0;
    auto alloc = [&](size_t n) { float* p = W + off; off += (n + 3) & ~(size_t)3; return p; };
    const size_t M = (size_t)BATCH * SS;  // 6400
    float* A    = alloc((size_t)BATCH * DP * TLEN);
    float* Bb   = alloc((size_t)BATCH * 64 * TLEN);
    float* ze   = alloc(M * DP);
    float* tx   = alloc(M * DM);
    float* hb   = alloc(M * DM);
    float* qf   = alloc(M * 3 * DM);
    float* cbn  = alloc(VV);
    float* vqs  = alloc(M);
    float* upb2 = alloc(1152);
    float* pval = alloc(4 * M);
    int*   pidx = (int*)alloc(4 * M);
    unsigned short* zqb  = (unsigned short*)alloc(M * DP / 2);
    unsigned short* xnb  = (unsigned short*)alloc(M * DM / 2);
    unsigned short* aob  = (unsigned short*)alloc(M * DM / 2);
    float* pgpart        = qf;
    unsigned short* qkvb = (unsigned short*)qf;
    unsigned short* ffb  = (unsigned short*)qf;
    unsigned short* utm  = (unsigned short*)qf;
    unsigned short* inwb = (unsigned short*)alloc((size_t)NLAY * 3 * DM * DM / 2);
    unsigned short* owb  = (unsigned short*)alloc((size_t)NLAY * DM * DM / 2);
    unsigned short* f1wb = (unsigned short*)alloc((size_t)NLAY * 4 * DM * DM / 2);
    unsigned short* f2wb = (unsigned short*)alloc((size_t)NLAY * 4 * DM * DM / 2);
    unsigned short* tpwb = (unsigned short*)alloc((size_t)DM * DP / 2);
    unsigned short* upwb = (unsigned short*)alloc((size_t)1152 * DM / 2);
    unsigned short* pwh  = (unsigned short*)alloc((size_t)128 * 1152 / 2);
    unsigned short* pwl  = (unsigned short*)alloc((size_t)128 * 1152 / 2);
    unsigned short* w2h  = (unsigned short*)alloc((size_t)3 * 128 * 64 / 2);
    unsigned short* w2l  = (unsigned short*)alloc((size_t)3 * 128 * 64 / 2);
    unsigned short* cbh  = (unsigned short*)alloc((size_t)VV * DP / 2);
    unsigned short* cbl  = (unsigned short*)alloc((size_t)VV * DP / 2);
    unsigned short* r2pk = (unsigned short*)alloc((size_t)64 * 64 * 5 / 2);
    unsigned short* r3pk = (unsigned short*)alloc((size_t)64 * 64 * 3 / 2 + 2);
    unsigned short* d1pk = (unsigned short*)alloc((size_t)64 * 128 * 5 / 2);
    unsigned short* r1tm = (unsigned short*)alloc((size_t)BATCH * TLEN * 64 / 2);
    unsigned short* r2tm = (unsigned short*)alloc((size_t)BATCH * TLEN * 64 / 2);
    unsigned short* r3tm = (unsigned short*)alloc((size_t)BATCH * TLEN * 64 / 2);
    unsigned short* d1tm = (unsigned short*)alloc((size_t)BATCH * TLEN * 64 / 2);
    if (off * sizeof(float) > ws_size) return;

    float* outp = (float*)d_out;
    const dim3 cgrid(57, 1, BATCH);
    const dim3 mgrid(29, 1, BATCH);

    // --- weight conversions / packs ---
    tobf_k<<<(NLAY * 3 * DM * DM + 255) / 256, 256, 0, stream>>>(inw, inwb, NLAY * 3 * DM * DM);
    tobf_k<<<(NLAY * DM * DM + 255) / 256, 256, 0, stream>>>(ow, owb, NLAY * DM * DM);
    tobf_k<<<(NLAY * 4 * DM * DM + 255) / 256, 256, 0, stream>>>(f1w, f1wb, NLAY * 4 * DM * DM);
    tobf_k<<<(NLAY * 4 * DM * DM + 255) / 256, 256, 0, stream>>>(f2w, f2wb, NLAY * 4 * DM * DM);
    tobf_k<<<(DM * DP + 255) / 256, 256, 0, stream>>>(tp_w, tpwb, DM * DP);
    upwt2_k<<<(1152 * 256 + 255) / 256, 256, 0, stream>>>(up_w, up_b, upwb, upb2);
    pwpack3_k<<<(128 * 1152 + 255) / 256, 256, 0, stream>>>(pe_pw, pwh, pwl);
    pwpack2_k<<<(3 * 128 * 64 + 255) / 256, 256, 0, stream>>>(pe_w2, w2h, w2l);
    cbpack_k<<<(VV * DP + 255) / 256, 256, 0, stream>>>(cb, cbh, cbl);
    cpack_k<<<(64 * 64 * 5 + 255) / 256, 256, 0, stream>>>(r2w, r2pk, 64, 64, 5);
    cpack_k<<<(64 * 64 * 3 + 255) / 256, 256, 0, stream>>>(r3w, r3pk, 64, 64, 3);
    cpack_k<<<(64 * 128 * 5 + 255) / 256, 256, 0, stream>>>(d1w, d1pk, 64, 128, 5);

    // --- fused pe1 + r1 ---
    enc1_k<<<dim3(57, BATCH), 256, 0, stream>>>(x, pe_w1, pe_b1, r1w, r1b, Bb, r1tm);

    // --- encoder tail ---
    pe2m_k<<<dim3(29, BATCH), 256, 0, stream>>>(Bb, w2h, w2l, pe_b2, A);
    cbnorm_k<<<2, 256, 0, stream>>>(cb, cbn);
    pproj3_k<<<dim3(1, M / 128, 6), 256, 0, stream>>>(A, pwh, pwl, pgpart, M);
    ln128s_k<<<M, 128, 0, stream>>>(pgpart, pe_pb, pe_g, pe_bb, ze, M);
    vq3_k<<<dim3(4, M / 128), 256, 0, stream>>>(ze, cbh, cbl, cbn, pval, pidx, M);
    vqfin_k<<<M, 128, 0, stream>>>(ze, cb, pval, pidx, zqb, vqs, M);
    vqreduce_k<<<1, 256, 0, stream>>>(vqs, outp + (size_t)BATCH * TLEN * LEADS);

    // --- residual CNN ---
    mfconv_k<64, 5, 2><<<mgrid, 256, 0, stream>>>(r1tm, r2pk, r2b, r2tm);
    mfconv_k<64, 3, 1><<<mgrid, 256, 0, stream>>>(r2tm, r3pk, r3b, r3tm);

    // --- token projection + LN + ln1(layer0) ---
    bgemm64_k<0, 0, 0><<<dim3(DM / 128, M / 64), 256, 0, stream>>>(zqb, tpwb, tp_b, nullptr, tx, M, DM, DP);
    lnw_k<0><<<M / 4, 256, 0, stream>>>(tx, tp_g, tp_bb, hb);
    lnw_k<1><<<M / 4, 256, 0, stream>>>(hb, ln1_g, ln1_b, xnb);

    // --- transformer (LN fused into o-proj and FFN2 epilogues) ---
    for (int l = 0; l < NLAY; ++l) {
        bgemm_k<0, 0, 1><<<dim3(3 * DM / 128, M / 128), 256, 0, stream>>>(
            xnb, inwb + (size_t)l * 3 * DM * DM, inb + l * 3 * DM, nullptr, qkvb, M, 3 * DM, DM);
        fattn_k<<<dim3((SS + 63) / 64, NH, BATCH), 256, 0, stream>>>(qkvb, slopes + l * NH, aob);
        bgemmln_k<<<M / 32, 256, 0, stream>>>(
            aob, owb + (size_t)l * DM * DM, ob + l * DM, hb, hb,
            ln2_g + l * DM, ln2_b + l * DM, xnb, M, DM);
        bgemm_k<1, 0, 1><<<dim3(4 * DM / 128, M / 128), 256, 0, stream>>>(
            xnb, f1wb + (size_t)l * 4 * DM * DM, f1b + l * 4 * DM, nullptr, ffb, M, 4 * DM, DM);
        const float* gN = (l < NLAY - 1) ? ln1_g + (l + 1) * DM : fn_g;
        const float* bN = (l < NLAY - 1) ? ln1_b + (l + 1) * DM : fn_b;
        bgemmln_k<<<M / 32, 256, 0, stream>>>(
            ffb, f2wb + (size_t)l * 4 * DM * DM, f2b + l * DM, hb, hb,
            gN, bN, xnb, M, 4 * DM);
    }

    // --- decoder (xnb = final-norm output) ---
    bgemm_k<1, 0, 1><<<dim3(1152 / 128, M / 128), 256, 0, stream>>>(xnb, upwb, upb2, nullptr, utm, M, 1152, DM);
    mfconv_k<128, 5, 2><<<mgrid, 256, 0, stream>>>(utm, d1pk, d1b, d1tm);

    // --- fused d2 conv + r4 conv + alpha blend ---
    final2_k<<<cgrid, 256, 0, stream>>>(d1tm, r3tm, d2w, d2b, r4w, r4b, alpha, outp);
}

// Round 12
// 742.634 us; speedup vs baseline: 1.1019x; 1.1019x over previous
//
#include <hip/hip_runtime.h>
#include <hip/hip_bf16.h>
#include <math.h>

#define BATCH 16
#define TLEN 3600
#define LEADS 12
#define PP 9
#define SS 400
#define DP 128
#define DM 256
#define NH 8
#define HD 32
#define NLAY 6
#define VV 512
#define RH 64

typedef __attribute__((ext_vector_type(8))) short short8b;
typedef __attribute__((ext_vector_type(4))) float f32x4;

__device__ __forceinline__ float gelu_f(float x) {
    return 0.5f * x * (1.0f + erff(x * 0.70710678118654752f));
}

__device__ __forceinline__ unsigned short f2bf(float f) {
    union { float f; unsigned u; } v; v.f = f;
    return (unsigned short)((v.u + 0x7FFFu + ((v.u >> 16) & 1u)) >> 16);
}

__device__ __forceinline__ float bf2f(unsigned short h) {
    union { unsigned u; float f; } v; v.u = ((unsigned)h) << 16; return v.f;
}

// ---------- block reduction helpers ----------
__device__ __forceinline__ float block_sum_256(float v, float* sm) {
    #pragma unroll
    for (int o = 32; o > 0; o >>= 1) v += __shfl_down(v, o);
    __syncthreads();
    if ((threadIdx.x & 63) == 0) sm[threadIdx.x >> 6] = v;
    __syncthreads();
    return sm[0] + sm[1] + sm[2] + sm[3];
}

__device__ __forceinline__ float block_sum_128(float v, float* sm) {
    #pragma unroll
    for (int o = 32; o > 0; o >>= 1) v += __shfl_down(v, o);
    __syncthreads();
    if ((threadIdx.x & 63) == 0) sm[threadIdx.x >> 6] = v;
    __syncthreads();
    return sm[0] + sm[1];
}

// ---------- fused pe1 + r1: both read x (B,T,12) ----------
__global__ __launch_bounds__(256, 4) void enc1_k(const float* __restrict__ x,
                                                 const float* __restrict__ w1,
                                                 const float* __restrict__ b1,
                                                 const float* __restrict__ w7,
                                                 const float* __restrict__ b7,
                                                 float* __restrict__ out1,
                                                 unsigned short* __restrict__ out7) {
    __shared__ __align__(16) float xs[12][80];
    __shared__ float w1s[12][3][64];
    __shared__ float w7s[12][7][64];
    const int b = blockIdx.y, t0 = blockIdx.x * 64, tid = threadIdx.x;
    const int tx = tid & 15, ty = tid >> 4;
    for (int idx = tid; idx < 70 * 12; idx += 256) {
        int j = idx / 12, ci = idx - j * 12;
        int t = t0 + j - 3;
        xs[ci][j] = (t >= 0 && t < TLEN) ? x[((size_t)b * TLEN + t) * 12 + ci] : 0.f;
    }
    for (int idx = tid; idx < 12 * 3 * 64; idx += 256) {
        int co = idx & 63; int rest = idx >> 6; int k = rest % 3; int ci = rest / 3;
        w1s[ci][k][co] = w1[(co * 12 + ci) * 3 + k];
    }
    for (int idx = tid; idx < 12 * 7 * 64; idx += 256) {
        int co = idx & 63; int rest = idx >> 6; int k = rest % 7; int ci = rest / 7;
        w7s[ci][k][co] = w7[(co * 12 + ci) * 7 + k];
    }
    __syncthreads();
    float a1[4][4] = {}, a7[4][4] = {};
    #pragma unroll 2
    for (int ci = 0; ci < 12; ++ci) {
        float tv[12];
        *(float4*)&tv[0] = *(const float4*)&xs[ci][tx * 4];
        *(float4*)&tv[4] = *(const float4*)&xs[ci][tx * 4 + 4];
        *(float4*)&tv[8] = *(const float4*)&xs[ci][tx * 4 + 8];
        #pragma unroll
        for (int k = 0; k < 7; ++k) {
            float4 wv = *(const float4*)&w7s[ci][k][ty * 4];
            #pragma unroll
            for (int j = 0; j < 4; ++j) {
                float iv = tv[j + k];
                a7[0][j] = fmaf(wv.x, iv, a7[0][j]);
                a7[1][j] = fmaf(wv.y, iv, a7[1][j]);
                a7[2][j] = fmaf(wv.z, iv, a7[2][j]);
                a7[3][j] = fmaf(wv.w, iv, a7[3][j]);
            }
        }
        #pragma unroll
        for (int k = 0; k < 3; ++k) {
            float4 wv = *(const float4*)&w1s[ci][k][ty * 4];
            #pragma unroll
            for (int j = 0; j < 4; ++j) {
                float iv = tv[j + k + 2];
                a1[0][j] = fmaf(wv.x, iv, a1[0][j]);
                a1[1][j] = fmaf(wv.y, iv, a1[1][j]);
                a1[2][j] = fmaf(wv.z, iv, a1[2][j]);
                a1[3][j] = fmaf(wv.w, iv, a1[3][j]);
            }
        }
    }
    float4 b1v4 = *(const float4*)&b1[ty * 4];
    #pragma unroll
    for (int j = 0; j < 4; ++j) {
        int t = t0 + tx * 4 + j;
        if (t < TLEN) {
            float4 o4;
            o4.x = gelu_f(a1[0][j] + b1v4.x);
            o4.y = gelu_f(a1[1][j] + b1v4.y);
            o4.z = gelu_f(a1[2][j] + b1v4.z);
            o4.w = gelu_f(a1[3][j] + b1v4.w);
            *(float4*)&out1[((size_t)(b * TLEN + t)) * 64 + ty * 4] = o4;
        }
    }
    float bv0 = b7[ty * 4], bv1 = b7[ty * 4 + 1], bv2 = b7[ty * 4 + 2], bv3 = b7[ty * 4 + 3];
    #pragma unroll
    for (int j = 0; j < 4; ++j) {
        int t = t0 + tx * 4 + j;
        if (t < TLEN) {
            unsigned long long pk =
                  (unsigned long long)f2bf(gelu_f(a7[0][j] + bv0))
                | ((unsigned long long)f2bf(gelu_f(a7[1][j] + bv1)) << 16)
                | ((unsigned long long)f2bf(gelu_f(a7[2][j] + bv2)) << 32)
                | ((unsigned long long)f2bf(gelu_f(a7[3][j] + bv3)) << 48);
            *(unsigned long long*)&out7[((size_t)(b * TLEN + t)) * 64 + ty * 4] = pk;
        }
    }
}

// ---------- pe_w2 pack ----------
__global__ void pwpack2_k(const float* __restrict__ w,
                          unsigned short* __restrict__ wh,
                          unsigned short* __restrict__ wl) {
    int idx = blockIdx.x * 256 + threadIdx.x;
    if (idx < 3 * 128 * 64) {
        int ci = idx & 63; int rest = idx >> 6; int co = rest & 127; int k = rest >> 7;
        float v = w[((size_t)co * 64 + ci) * 3 + k];
        unsigned short h = f2bf(v);
        wh[idx] = h;
        wl[idx] = f2bf(v - bf2f(h));
    }
}

// ---------- pe2 hi/lo MFMA conv ----------
__global__ __launch_bounds__(256) void pe2m_k(const float* __restrict__ in,
                                              const unsigned short* __restrict__ wh,
                                              const unsigned short* __restrict__ wl,
                                              const float* __restrict__ bias,
                                              float* __restrict__ out) {
    __shared__ __align__(16) unsigned short Ah[130][72];
    __shared__ __align__(16) unsigned short Al[130][72];
    __shared__ __align__(16) unsigned short Wh_s[128][72];
    __shared__ __align__(16) unsigned short Wl_s[128][72];
    const int b = blockIdx.y, t0 = blockIdx.x * 128, tid = threadIdx.x;
    const int w = tid >> 6, lane = tid & 63;
    const int fr = lane & 15, kg = (lane >> 4) * 8;
    for (int u = tid; u < 130 * 8; u += 256) {
        int row = u >> 3, q = u & 7;
        int t = t0 + row - 1;
        short8b h8 = (short8b){0, 0, 0, 0, 0, 0, 0, 0};
        short8b l8 = (short8b){0, 0, 0, 0, 0, 0, 0, 0};
        if (t >= 0 && t < TLEN) {
            const float* src = in + ((size_t)(b * TLEN + t)) * 64 + q * 8;
            float4 v0 = *(const float4*)src;
            float4 v1 = *(const float4*)(src + 4);
            float vv[8] = {v0.x, v0.y, v0.z, v0.w, v1.x, v1.y, v1.z, v1.w};
            #pragma unroll
            for (int e = 0; e < 8; ++e) {
                unsigned short h = f2bf(vv[e]);
                h8[e] = (short)h;
                l8[e] = (short)f2bf(vv[e] - bf2f(h));
            }
        }
        *(short8b*)&Ah[row][q * 8] = h8;
        *(short8b*)&Al[row][q * 8] = l8;
    }
    f32x4 acc[2][8];
    #pragma unroll
    for (int i = 0; i < 2; ++i)
        #pragma unroll
        for (int j = 0; j < 8; ++j) acc[i][j] = (f32x4){0.f, 0.f, 0.f, 0.f};
    for (int k = 0; k < 3; ++k) {
        __syncthreads();
        for (int u = tid; u < 128 * 8; u += 256) {
            int co = u >> 3, q = u & 7;
            *(short8b*)&Wh_s[co][q * 8] = *(const short8b*)&wh[((size_t)(k * 128 + co)) * 64 + q * 8];
            *(short8b*)&Wl_s[co][q * 8] = *(const short8b*)&wl[((size_t)(k * 128 + co)) * 64 + q * 8];
        }
        __syncthreads();
        #pragma unroll
        for (int c32 = 0; c32 < 2; ++c32) {
            short8b ah0 = *(const short8b*)&Ah[w * 32 + fr + k][c32 * 32 + kg];
            short8b ah1 = *(const short8b*)&Ah[w * 32 + 16 + fr + k][c32 * 32 + kg];
            short8b al0 = *(const short8b*)&Al[w * 32 + fr + k][c32 * 32 + kg];
            short8b al1 = *(const short8b*)&Al[w * 32 + 16 + fr + k][c32 * 32 + kg];
            #pragma unroll
            for (int j = 0; j < 8; ++j) {
                short8b bh = *(const short8b*)&Wh_s[j * 16 + fr][c32 * 32 + kg];
                short8b bl = *(const short8b*)&Wl_s[j * 16 + fr][c32 * 32 + kg];
                acc[0][j] = __builtin_amdgcn_mfma_f32_16x16x32_bf16(ah0, bh, acc[0][j], 0, 0, 0);
                acc[0][j] = __builtin_amdgcn_mfma_f32_16x16x32_bf16(ah0, bl, acc[0][j], 0, 0, 0);
                acc[0][j] = __builtin_amdgcn_mfma_f32_16x16x32_bf16(al0, bh, acc[0][j], 0, 0, 0);
                acc[1][j] = __builtin_amdgcn_mfma_f32_16x16x32_bf16(ah1, bh, acc[1][j], 0, 0, 0);
                acc[1][j] = __builtin_amdgcn_mfma_f32_16x16x32_bf16(ah1, bl, acc[1][j], 0, 0, 0);
                acc[1][j] = __builtin_amdgcn_mfma_f32_16x16x32_bf16(al1, bh, acc[1][j], 0, 0, 0);
            }
        }
    }
    const int orow = (lane >> 4) * 4, ocol = lane & 15;
    #pragma unroll
    for (int i = 0; i < 2; ++i)
        #pragma unroll
        for (int j = 0; j < 8; ++j) {
            const int co = j * 16 + ocol;
            const float bv = bias[co];
            #pragma unroll
            for (int r = 0; r < 4; ++r) {
                int t = t0 + w * 32 + i * 16 + orow + r;
                if (t < TLEN) {
                    int s = t / PP, kk = t - s * PP;
                    out[((size_t)(b * SS + s)) * 1152 + kk * 128 + co] = gelu_f(acc[i][j][r] + bv);
                }
            }
        }
}

// ---------- pe_pw pack ----------
__global__ void pwpack3_k(const float* __restrict__ pw,
                          unsigned short* __restrict__ wh,
                          unsigned short* __restrict__ wl) {
    int idx = blockIdx.x * 256 + threadIdx.x;
    if (idx < 128 * 1152) {
        int n = idx % 1152, d = idx / 1152;
        int co = n & 127, kk = n >> 7;
        float v = pw[(size_t)d * 1152 + co * 9 + kk];
        unsigned short h = f2bf(v);
        wh[idx] = h;
        wl[idx] = f2bf(v - bf2f(h));
    }
}

// ---------- patch projection: hi/lo 3-MFMA, 6-way split-K ----------
__global__ __launch_bounds__(256) void pproj3_k(const float* __restrict__ A,
                                                const unsigned short* __restrict__ Wh,
                                                const unsigned short* __restrict__ Wl,
                                                float* __restrict__ Cp,
                                                int M) {
    __shared__ __align__(16) unsigned short Ah[128][40];
    __shared__ __align__(16) unsigned short Al[128][40];
    __shared__ __align__(16) unsigned short Bh[128][40];
    __shared__ __align__(16) unsigned short Bl[128][40];
    const int tid = threadIdx.x;
    const int gm0 = blockIdx.y * 128;
    const int z = blockIdx.z;
    const int w = tid >> 6, lane = tid & 63;
    const int wr0 = (w >> 1) * 64, wc0 = (w & 1) * 64;
    const int srow = tid >> 1, sc = (tid & 1) * 16;
    const int K = 1152;
    const int kb = z * 192;
    f32x4 acc[4][4];
    #pragma unroll
    for (int i = 0; i < 4; ++i)
        #pragma unroll
        for (int j = 0; j < 4; ++j) acc[i][j] = (f32x4){0.f, 0.f, 0.f, 0.f};
    const int fr = lane & 15, kg = (lane >> 4) * 8;
    for (int s = 0; s < 6; ++s) {
        const int k0 = kb + s * 32;
        __syncthreads();
        {
            const float* ga = A + (size_t)(gm0 + srow) * K + k0 + sc;
            #pragma unroll
            for (int g = 0; g < 2; ++g) {
                float4 v0 = *(const float4*)(ga + g * 8);
                float4 v1 = *(const float4*)(ga + g * 8 + 4);
                short8b h8, l8;
                float vv[8] = {v0.x, v0.y, v0.z, v0.w, v1.x, v1.y, v1.z, v1.w};
                #pragma unroll
                for (int e = 0; e < 8; ++e) {
                    unsigned short h = f2bf(vv[e]);
                    h8[e] = (short)h;
                    l8[e] = (short)f2bf(vv[e] - bf2f(h));
                }
                *(short8b*)&Ah[srow][sc + g * 8] = h8;
                *(short8b*)&Al[srow][sc + g * 8] = l8;
            }
            const unsigned short* gh = Wh + (size_t)srow * K + k0 + sc;
            const unsigned short* gl = Wl + (size_t)srow * K + k0 + sc;
            *(short8b*)&Bh[srow][sc] = *(const short8b*)gh;
            *(short8b*)&Bh[srow][sc + 8] = *(const short8b*)(gh + 8);
            *(short8b*)&Bl[srow][sc] = *(const short8b*)gl;
            *(short8b*)&Bl[srow][sc + 8] = *(const short8b*)(gl + 8);
        }
        __syncthreads();
        short8b afh[4], afl[4], bfh[4], bfl[4];
        #pragma unroll
        for (int i = 0; i < 4; ++i) {
            afh[i] = *(const short8b*)&Ah[wr0 + i * 16 + fr][kg];
            afl[i] = *(const short8b*)&Al[wr0 + i * 16 + fr][kg];
            bfh[i] = *(const short8b*)&Bh[wc0 + i * 16 + fr][kg];
            bfl[i] = *(const short8b*)&Bl[wc0 + i * 16 + fr][kg];
        }
        #pragma unroll
        for (int i = 0; i < 4; ++i)
            #pragma unroll
            for (int j = 0; j < 4; ++j) {
                acc[i][j] = __builtin_amdgcn_mfma_f32_16x16x32_bf16(afh[i], bfh[j], acc[i][j], 0, 0, 0);
                acc[i][j] = __builtin_amdgcn_mfma_f32_16x16x32_bf16(afh[i], bfl[j], acc[i][j], 0, 0, 0);
                acc[i][j] = __builtin_amdgcn_mfma_f32_16x16x32_bf16(afl[i], bfh[j], acc[i][j], 0, 0, 0);
            }
    }
    const int orow = (lane >> 4) * 4, ocol = lane & 15;
    float* Cz = Cp + (size_t)z * M * 128;
    #pragma unroll
    for (int i = 0; i < 4; ++i)
        #pragma unroll
        for (int j = 0; j < 4; ++j) {
            const int colg = wc0 + j * 16 + ocol;
            #pragma unroll
            for (int r = 0; r < 4; ++r) {
                const int rowg = gm0 + wr0 + i * 16 + orow + r;
                Cz[(size_t)rowg * 128 + colg] = acc[i][j][r];
            }
        }
}

// ---------- codebook pack ----------
__global__ void cbpack_k(const float* __restrict__ cb,
                         unsigned short* __restrict__ ch,
                         unsigned short* __restrict__ cl) {
    int idx = blockIdx.x * 256 + threadIdx.x;
    if (idx < VV * DP) {
        float v = cb[idx];
        unsigned short h = f2bf(v);
        ch[idx] = h;
        cl[idx] = f2bf(v - bf2f(h));
    }
}

// ---------- VQ distances via hi/lo 3-MFMA + in-wave argmin ----------
__global__ __launch_bounds__(256) void vq3_k(const float* __restrict__ ze,
                                             const unsigned short* __restrict__ ch,
                                             const unsigned short* __restrict__ cl,
                                             const float* __restrict__ cbn,
                                             float* __restrict__ pval,
                                             int* __restrict__ pidx,
                                             int M) {
    __shared__ __align__(16) unsigned short Ah[128][40];
    __shared__ __align__(16) unsigned short Al[128][40];
    __shared__ __align__(16) unsigned short Bh[128][40];
    __shared__ __align__(16) unsigned short Bl[128][40];
    __shared__ float bwv[128][2];
    __shared__ int bwi[128][2];
    const int tid = threadIdx.x;
    const int c0 = blockIdx.x * 128;
    const int gm0 = blockIdx.y * 128;
    const int w = tid >> 6, lane = tid & 63;
    const int wr0 = (w >> 1) * 64, wc0 = (w & 1) * 64;
    const int srow = tid >> 1, sc = (tid & 1) * 16;
    const int fr = lane & 15, kg = (lane >> 4) * 8;
    f32x4 acc[4][4];
    #pragma unroll
    for (int i = 0; i < 4; ++i)
        #pragma unroll
        for (int j = 0; j < 4; ++j) acc[i][j] = (f32x4){0.f, 0.f, 0.f, 0.f};
    for (int s = 0; s < 4; ++s) {
        const int k0 = s * 32;
        __syncthreads();
        {
            const float* ga = ze + (size_t)(gm0 + srow) * DP + k0 + sc;
            #pragma unroll
            for (int g = 0; g < 2; ++g) {
                float4 v0 = *(const float4*)(ga + g * 8);
                float4 v1 = *(const float4*)(ga + g * 8 + 4);
                short8b h8, l8;
                float vv[8] = {v0.x, v0.y, v0.z, v0.w, v1.x, v1.y, v1.z, v1.w};
                #pragma unroll
                for (int e = 0; e < 8; ++e) {
                    unsigned short h = f2bf(vv[e]);
                    h8[e] = (short)h;
                    l8[e] = (short)f2bf(vv[e] - bf2f(h));
                }
                *(short8b*)&Ah[srow][sc + g * 8] = h8;
                *(short8b*)&Al[srow][sc + g * 8] = l8;
            }
            const unsigned short* gh = ch + (size_t)(c0 + srow) * DP + k0 + sc;
            const unsigned short* gl = cl + (size_t)(c0 + srow) * DP + k0 + sc;
            *(short8b*)&Bh[srow][sc] = *(const short8b*)gh;
            *(short8b*)&Bh[srow][sc + 8] = *(const short8b*)(gh + 8);
            *(short8b*)&Bl[srow][sc] = *(const short8b*)gl;
            *(short8b*)&Bl[srow][sc + 8] = *(const short8b*)(gl + 8);
        }
        __syncthreads();
        short8b afh[4], afl[4], bfh[4], bfl[4];
        #pragma unroll
        for (int i = 0; i < 4; ++i) {
            afh[i] = *(const short8b*)&Ah[wr0 + i * 16 + fr][kg];
            afl[i] = *(const short8b*)&Al[wr0 + i * 16 + fr][kg];
            bfh[i] = *(const short8b*)&Bh[wc0 + i * 16 + fr][kg];
            bfl[i] = *(const short8b*)&Bl[wc0 + i * 16 + fr][kg];
        }
        #pragma unroll
        for (int i = 0; i < 4; ++i)
            #pragma unroll
            for (int j = 0; j < 4; ++j) {
                acc[i][j] = __builtin_amdgcn_mfma_f32_16x16x32_bf16(afh[i], bfh[j], acc[i][j], 0, 0, 0);
                acc[i][j] = __builtin_amdgcn_mfma_f32_16x16x32_bf16(afh[i], bfl[j], acc[i][j], 0, 0, 0);
                acc[i][j] = __builtin_amdgcn_mfma_f32_16x16x32_bf16(afl[i], bfh[j], acc[i][j], 0, 0, 0);
            }
    }
    const int orow = (lane >> 4) * 4, ocol = lane & 15;
    #pragma unroll
    for (int i = 0; i < 4; ++i)
        #pragma unroll
        for (int r = 0; r < 4; ++r) {
            int row = wr0 + i * 16 + orow + r;
            float bv = 1e30f; int bi = 0;
            #pragma unroll
            for (int j = 0; j < 4; ++j) {
                int col = c0 + wc0 + j * 16 + ocol;
                float d = cbn[col] - 2.0f * acc[i][j][r];
                if (d < bv || (d == bv && col < bi)) { bv = d; bi = col; }
            }
            #pragma unroll
            for (int o = 1; o < 16; o <<= 1) {
                float ov = __shfl_xor(bv, o);
                int oi = __shfl_xor(bi, o);
                if (ov < bv || (ov == bv && oi < bi)) { bv = ov; bi = oi; }
            }
            if (ocol == 0) { bwv[row][w & 1] = bv; bwi[row][w & 1] = bi; }
        }
    __syncthreads();
    if (tid < 128) {
        float v0 = bwv[tid][0], v1 = bwv[tid][1];
        int i0 = bwi[tid][0], i1 = bwi[tid][1];
        bool sel = (v1 < v0) || (v1 == v0 && i1 < i0);
        pval[(size_t)blockIdx.x * M + gm0 + tid] = sel ? v1 : v0;
        pidx[(size_t)blockIdx.x * M + gm0 + tid] = sel ? i1 : i0;
    }
}

// ---------- VQ finish ----------
__global__ __launch_bounds__(128) void vqfin_k(const float* __restrict__ ze,
                                               const float* __restrict__ cb,
                                               const float* __restrict__ pval,
                                               const int* __restrict__ pidx,
                                               unsigned short* __restrict__ zqb,
                                               float* __restrict__ vqs,
                                               int M) {
    const int row = blockIdx.x, tid = threadIdx.x;
    __shared__ float sm[2];
    __shared__ int tok_s;
    if (tid == 0) {
        float bv = pval[row]; int bi = pidx[row];
        #pragma unroll
        for (int z = 1; z < 4; ++z) {
            float v = pval[(size_t)z * M + row]; int ix = pidx[(size_t)z * M + row];
            if (v < bv || (v == bv && ix < bi)) { bv = v; bi = ix; }
        }
        tok_s = bi;
    }
    __syncthreads();
    int tok = tok_s;
    float qv = cb[(size_t)tok * DP + tid];
    float zv = ze[(size_t)row * DP + tid];
    zqb[(size_t)row * DP + tid] = f2bf(qv);
    float d = qv - zv;
    float tot = block_sum_128(d * d, sm);
    if (tid == 0) vqs[row] = tot;
}

// ---------- bf16 MFMA implicit-GEMM conv ----------
template <int CI, int K, int PAD>
__global__ __launch_bounds__(256) void mfconv_k(const unsigned short* __restrict__ in,
                                                const unsigned short* __restrict__ wpk,
                                                const float* __restrict__ bias,
                                                unsigned short* __restrict__ out) {
    constexpr int CIC = (CI > 64) ? 64 : CI;
    constexpr int NCH = CI / CIC;
    constexpr int TROWS = 128 + K - 1;
    constexpr int CQ = CIC / 8;
    __shared__ __align__(16) unsigned short in_s[TROWS][CIC + 8];
    __shared__ __align__(16) unsigned short w_s[K][64][CIC + 8];
    const int b = blockIdx.z;
    const int t0 = blockIdx.x * 128;
    const int tid = threadIdx.x;
    const int w = tid >> 6, lane = tid & 63;
    const int fr = lane & 15, kg = (lane >> 4) * 8;
    f32x4 acc[2][4];
    #pragma unroll
    for (int i = 0; i < 2; ++i)
        #pragma unroll
        for (int j = 0; j < 4; ++j) acc[i][j] = (f32x4){0.f, 0.f, 0.f, 0.f};
    for (int ch = 0; ch < NCH; ++ch) {
        const int c0 = ch * CIC;
        if (ch) __syncthreads();
        for (int u = tid; u < TROWS * CQ; u += 256) {
            int row = u / CQ, q = u - row * CQ;
            int t = t0 + row - PAD;
            short8b v = (short8b){0, 0, 0, 0, 0, 0, 0, 0};
            if (t >= 0 && t < TLEN)
                v = *(const short8b*)&in[((size_t)(b * TLEN + t)) * CI + c0 + q * 8];
            *(short8b*)&in_s[row][q * 8] = v;
        }
        for (int u = tid; u < K * 64 * CQ; u += 256) {
            int q = u % CQ; int rest = u / CQ; int co = rest & 63; int k = rest >> 6;
            *(short8b*)&w_s[k][co][q * 8] =
                *(const short8b*)&wpk[((size_t)(k * 64 + co)) * CI + c0 + q * 8];
        }
        __syncthreads();
        #pragma unroll
        for (int k = 0; k < K; ++k) {
            #pragma unroll
            for (int c32 = 0; c32 < CIC / 32; ++c32) {
                short8b a0 = *(const short8b*)&in_s[w * 32 + fr + k][c32 * 32 + kg];
                short8b a1 = *(const short8b*)&in_s[w * 32 + 16 + fr + k][c32 * 32 + kg];
                short8b b0 = *(const short8b*)&w_s[k][fr][c32 * 32 + kg];
                short8b b1 = *(const short8b*)&w_s[k][16 + fr][c32 * 32 + kg];
                short8b b2 = *(const short8b*)&w_s[k][32 + fr][c32 * 32 + kg];
                short8b b3 = *(const short8b*)&w_s[k][48 + fr][c32 * 32 + kg];
                acc[0][0] = __builtin_amdgcn_mfma_f32_16x16x32_bf16(a0, b0, acc[0][0], 0, 0, 0);
                acc[0][1] = __builtin_amdgcn_mfma_f32_16x16x32_bf16(a0, b1, acc[0][1], 0, 0, 0);
                acc[0][2] = __builtin_amdgcn_mfma_f32_16x16x32_bf16(a0, b2, acc[0][2], 0, 0, 0);
                acc[0][3] = __builtin_amdgcn_mfma_f32_16x16x32_bf16(a0, b3, acc[0][3], 0, 0, 0);
                acc[1][0] = __builtin_amdgcn_mfma_f32_16x16x32_bf16(a1, b0, acc[1][0], 0, 0, 0);
                acc[1][1] = __builtin_amdgcn_mfma_f32_16x16x32_bf16(a1, b1, acc[1][1], 0, 0, 0);
                acc[1][2] = __builtin_amdgcn_mfma_f32_16x16x32_bf16(a1, b2, acc[1][2], 0, 0, 0);
                acc[1][3] = __builtin_amdgcn_mfma_f32_16x16x32_bf16(a1, b3, acc[1][3], 0, 0, 0);
            }
        }
    }
    const int orow = (lane >> 4) * 4, ocol = lane & 15;
    #pragma unroll
    for (int i = 0; i < 2; ++i)
        #pragma unroll
        for (int j = 0; j < 4; ++j) {
            const int co = j * 16 + ocol;
            const float bv = bias[co];
            #pragma unroll
            for (int r = 0; r < 4; ++r) {
                int t = t0 + w * 32 + i * 16 + orow + r;
                if (t < TLEN)
                    out[((size_t)(b * TLEN + t)) * 64 + co] = f2bf(gelu_f(acc[i][j][r] + bv));
            }
        }
}

// ---------- bf16 MFMA GEMM, 128x128 tile ----------
template <int ACT, int RES, int OUTBF>
__global__ __launch_bounds__(256) void bgemm_k(const unsigned short* __restrict__ A,
                                               const unsigned short* __restrict__ W,
                                               const float* __restrict__ bias,
                                               const float* __restrict__ res,
                                               void* __restrict__ Cv,
                                               int M, int N, int K) {
    __shared__ __align__(16) unsigned short As[128][40];
    __shared__ __align__(16) unsigned short Bs[128][40];
    const int tid = threadIdx.x;
    const int gm0 = blockIdx.y * 128, gn0 = blockIdx.x * 128;
    const int w = tid >> 6, lane = tid & 63;
    const int wr0 = (w >> 1) * 64, wc0 = (w & 1) * 64;
    const int srow = tid >> 1, sc = (tid & 1) * 16;
    const unsigned short* ga = A + (size_t)(gm0 + srow) * K + sc;
    const unsigned short* gb = W + (size_t)(gn0 + srow) * K + sc;
    short8b ra0 = *(const short8b*)(ga), ra1 = *(const short8b*)(ga + 8);
    short8b rb0 = *(const short8b*)(gb), rb1 = *(const short8b*)(gb + 8);
    f32x4 acc[4][4];
    #pragma unroll
    for (int i = 0; i < 4; ++i)
        #pragma unroll
        for (int j = 0; j < 4; ++j) acc[i][j] = (f32x4){0.f, 0.f, 0.f, 0.f};
    const int fr = lane & 15, kg = (lane >> 4) * 8;
    const int nstep = K >> 5;
    for (int s = 0; s < nstep; ++s) {
        __syncthreads();
        *(short8b*)&As[srow][sc] = ra0; *(short8b*)&As[srow][sc + 8] = ra1;
        *(short8b*)&Bs[srow][sc] = rb0; *(short8b*)&Bs[srow][sc + 8] = rb1;
        __syncthreads();
        if (s + 1 < nstep) {
            ga += 32; gb += 32;
            ra0 = *(const short8b*)(ga); ra1 = *(const short8b*)(ga + 8);
            rb0 = *(const short8b*)(gb); rb1 = *(const short8b*)(gb + 8);
        }
        short8b af[4], bf[4];
        #pragma unroll
        for (int i = 0; i < 4; ++i) {
            af[i] = *(const short8b*)&As[wr0 + i * 16 + fr][kg];
            bf[i] = *(const short8b*)&Bs[wc0 + i * 16 + fr][kg];
        }
        #pragma unroll
        for (int i = 0; i < 4; ++i)
            #pragma unroll
            for (int j = 0; j < 4; ++j)
                acc[i][j] = __builtin_amdgcn_mfma_f32_16x16x32_bf16(af[i], bf[j], acc[i][j], 0, 0, 0);
    }
    const int orow = (lane >> 4) * 4, ocol = lane & 15;
    #pragma unroll
    for (int i = 0; i < 4; ++i) {
        #pragma unroll
        for (int j = 0; j < 4; ++j) {
            const int colg = gn0 + wc0 + j * 16 + ocol;
            const float bsv = bias[colg];
            #pragma unroll
            for (int r = 0; r < 4; ++r) {
                const int rowg = gm0 + wr0 + i * 16 + orow + r;
                float v = acc[i][j][r] + bsv;
                if (ACT) v = gelu_f(v);
                if (RES) v += res[(size_t)rowg * N + colg];
                if (OUTBF) ((unsigned short*)Cv)[(size_t)rowg * N + colg] = f2bf(v);
                else ((float*)Cv)[(size_t)rowg * N + colg] = v;
            }
        }
    }
}

// ---------- bf16 MFMA GEMM, 64x128 tile (for N=256 parallelism-starved GEMMs) ----------
template <int ACT, int RES, int OUTBF>
__global__ __launch_bounds__(256) void bgemm64_k(const unsigned short* __restrict__ A,
                                                 const unsigned short* __restrict__ W,
                                                 const float* __restrict__ bias,
                                                 const float* __restrict__ res,
                                                 void* __restrict__ Cv,
                                                 int M, int N, int K) {
    __shared__ __align__(16) unsigned short As[64][40];
    __shared__ __align__(16) unsigned short Bs[128][40];
    const int tid = threadIdx.x;
    const int gm0 = blockIdx.y * 64, gn0 = blockIdx.x * 128;
    const int w = tid >> 6, lane = tid & 63;
    const int wc0 = w * 32;
    const int arow = tid >> 2, ac = (tid & 3) * 8;
    const int brow = tid >> 1, bc = (tid & 1) * 16;
    const unsigned short* ga = A + (size_t)(gm0 + arow) * K + ac;
    const unsigned short* gb = W + (size_t)(gn0 + brow) * K + bc;
    short8b ra0 = *(const short8b*)(ga);
    short8b rb0 = *(const short8b*)(gb), rb1 = *(const short8b*)(gb + 8);
    f32x4 acc[4][2];
    #pragma unroll
    for (int i = 0; i < 4; ++i)
        #pragma unroll
        for (int j = 0; j < 2; ++j) acc[i][j] = (f32x4){0.f, 0.f, 0.f, 0.f};
    const int fr = lane & 15, kg = (lane >> 4) * 8;
    const int nstep = K >> 5;
    for (int s = 0; s < nstep; ++s) {
        __syncthreads();
        *(short8b*)&As[arow][ac] = ra0;
        *(short8b*)&Bs[brow][bc] = rb0; *(short8b*)&Bs[brow][bc + 8] = rb1;
        __syncthreads();
        if (s + 1 < nstep) {
            ga += 32; gb += 32;
            ra0 = *(const short8b*)(ga);
            rb0 = *(const short8b*)(gb); rb1 = *(const short8b*)(gb + 8);
        }
        short8b af[4], bf[2];
        #pragma unroll
        for (int i = 0; i < 4; ++i) af[i] = *(const short8b*)&As[i * 16 + fr][kg];
        #pragma unroll
        for (int j = 0; j < 2; ++j) bf[j] = *(const short8b*)&Bs[wc0 + j * 16 + fr][kg];
        #pragma unroll
        for (int i = 0; i < 4; ++i)
            #pragma unroll
            for (int j = 0; j < 2; ++j)
                acc[i][j] = __builtin_amdgcn_mfma_f32_16x16x32_bf16(af[i], bf[j], acc[i][j], 0, 0, 0);
    }
    const int orow = (lane >> 4) * 4, ocol = lane & 15;
    #pragma unroll
    for (int i = 0; i < 4; ++i) {
        #pragma unroll
        for (int j = 0; j < 2; ++j) {
            const int colg = gn0 + wc0 + j * 16 + ocol;
            const float bsv = bias[colg];
            #pragma unroll
            for (int r = 0; r < 4; ++r) {
                const int rowg = gm0 + i * 16 + orow + r;
                float v = acc[i][j][r] + bsv;
                if (ACT) v = gelu_f(v);
                if (RES) v += res[(size_t)rowg * N + colg];
                if (OUTBF) ((unsigned short*)Cv)[(size_t)rowg * N + colg] = f2bf(v);
                else ((float*)Cv)[(size_t)rowg * N + colg] = v;
            }
        }
    }
}

// ---------- weight fp32 -> bf16 ----------
__global__ void tobf_k(const float* __restrict__ in, unsigned short* __restrict__ out, int n) {
    int i = blockIdx.x * 256 + threadIdx.x;
    if (i < n) out[i] = f2bf(in[i]);
}

__global__ void cpack_k(const float* __restrict__ w, unsigned short* __restrict__ out,
                        int Co, int CI, int K) {
    int idx = blockIdx.x * 256 + threadIdx.x;
    if (idx < Co * CI * K) {
        int ci = idx % CI; int rest = idx / CI; int co = rest % Co; int k = rest / Co;
        out[idx] = f2bf(w[((size_t)co * CI + ci) * K + k]);
    }
}

__global__ void upwt2_k(const float* __restrict__ w, const float* __restrict__ bsrc,
                        unsigned short* __restrict__ out, float* __restrict__ b2) {
    int idx = blockIdx.x * 256 + threadIdx.x;
    if (idx < 1152 * 256) {
        int d = idx & 255, n = idx >> 8;
        int o = n & 127, k = n >> 7;
        out[(size_t)n * 256 + d] = f2bf(w[(size_t)d * 1152 + o * 9 + k]);
    }
    if (idx < 1152) b2[idx] = bsrc[idx & 127];
}

// ---------- LayerNorm over 128 with 6-way split-K partial sum + bias ----------
__global__ __launch_bounds__(128) void ln128s_k(const float* __restrict__ part,
                                                const float* __restrict__ bias,
                                                const float* __restrict__ g,
                                                const float* __restrict__ bb,
                                                float* __restrict__ out,
                                                int M) {
    int row = blockIdx.x, tid = threadIdx.x;
    __shared__ float sm[2];
    size_t stride = (size_t)M * DP;
    size_t base = (size_t)row * DP + tid;
    float v = bias[tid];
    #pragma unroll
    for (int s2 = 0; s2 < 6; ++s2) v += part[base + (size_t)s2 * stride];
    float mean = block_sum_128(v, sm) * (1.0f / DP);
    float d = v - mean;
    float var = block_sum_128(d * d, sm) * (1.0f / DP);
    out[(size_t)row * DP + tid] = d * rsqrtf(var + 1e-5f) * g[tid] + bb[tid];
}

// ---------- codebook norms ----------
__global__ void cbnorm_k(const float* __restrict__ cb, float* __restrict__ cbn) {
    int c = blockIdx.x * 256 + threadIdx.x;
    if (c < VV) {
        const float* cr = cb + (size_t)c * DP;
        float s = 0;
        for (int i = 0; i < DP; ++i) s += cr[i] * cr[i];
        cbn[c] = s;
    }
}

__global__ void vqreduce_k(const float* __restrict__ vqs, float* __restrict__ out) {
    float s = 0;
    for (int i = threadIdx.x; i < BATCH * SS; i += 256) s += vqs[i];
    __shared__ float sm[4];
    s = block_sum_256(s, sm);
    if (threadIdx.x == 0) out[0] = s * (1.25f / (float)(BATCH * SS * DP));
}

// ---------- wave-per-row LayerNorm over 256 (shfl-only) ----------
template <int OUTBF>
__global__ __launch_bounds__(256) void lnw_k(const float* __restrict__ in,
                                             const float* __restrict__ g,
                                             const float* __restrict__ bb,
                                             void* __restrict__ out) {
    const int row = blockIdx.x * 4 + (threadIdx.x >> 6);
    const int lane = threadIdx.x & 63;
    float4 v = *(const float4*)&in[(size_t)row * DM + lane * 4];
    float s = v.x + v.y + v.z + v.w;
    #pragma unroll
    for (int o = 1; o < 64; o <<= 1) s += __shfl_xor(s, o);
    float mean = s * (1.0f / DM);
    float dx = v.x - mean, dy = v.y - mean, dz = v.z - mean, dw = v.w - mean;
    float vv = dx * dx + dy * dy + dz * dz + dw * dw;
    #pragma unroll
    for (int o = 1; o < 64; o <<= 1) vv += __shfl_xor(vv, o);
    float rstd = rsqrtf(vv * (1.0f / DM) + 1e-5f);
    float4 gv = *(const float4*)&g[lane * 4];
    float4 bv = *(const float4*)&bb[lane * 4];
    float o0 = dx * rstd * gv.x + bv.x;
    float o1 = dy * rstd * gv.y + bv.y;
    float o2 = dz * rstd * gv.z + bv.z;
    float o3 = dw * rstd * gv.w + bv.w;
    if (OUTBF) {
        unsigned long long pk = (unsigned long long)f2bf(o0)
                              | ((unsigned long long)f2bf(o1) << 16)
                              | ((unsigned long long)f2bf(o2) << 32)
                              | ((unsigned long long)f2bf(o3) << 48);
        *(unsigned long long*)((unsigned short*)out + (size_t)row * DM + lane * 4) = pk;
    } else {
        float4 o4; o4.x = o0; o4.y = o1; o4.z = o2; o4.w = o3;
        *(float4*)((float*)out + (size_t)row * DM + lane * 4) = o4;
    }
}

// ---------- fused flash MFMA attention, 64-q blocks (proven variant) ----------
__global__ __launch_bounds__(256) void fattn_k(const unsigned short* __restrict__ qkv,
                                               const float* __restrict__ slopes,
                                               unsigned short* __restrict__ out) {
    __shared__ __align__(16) unsigned short Qs[64][40];
    __shared__ __align__(16) unsigned short Ks[64][40];
    __shared__ __align__(16) unsigned short Vt[32][72];
    __shared__ __align__(16) unsigned short Ps[4][16][72];
    const int qb = blockIdx.x, hh = blockIdx.y, b = blockIdx.z;
    const int tid = threadIdx.x;
    const int w = tid >> 6, lane = tid & 63;
    const int lr = lane & 15, lg = lane >> 4;
    const float slope = fabsf(slopes[hh]);
    const unsigned short* base = qkv + (size_t)b * SS * (3 * DM);
    {
        int row = tid >> 2, c = (tid & 3) * 8;
        int q = qb * 64 + row; q = q < SS ? q : SS - 1;
        *(short8b*)&Qs[row][c] = *(const short8b*)(base + (size_t)q * (3 * DM) + hh * HD + c);
    }
    __syncthreads();
    const short8b qa = *(const short8b*)&Qs[w * 16 + lr][lg * 8];
    float m_run[4] = {-1e30f, -1e30f, -1e30f, -1e30f};
    float l_run[4] = {0.f, 0.f, 0.f, 0.f};
    f32x4 of0 = (f32x4){0.f, 0.f, 0.f, 0.f}, of1 = (f32x4){0.f, 0.f, 0.f, 0.f};
    const int qg0 = qb * 64 + w * 16 + lg * 4;
    for (int kt = 0; kt < SS; kt += 64) {
        const int tl = (SS - kt) < 64 ? (SS - kt) : 64;
        const int nks = tl >> 4;
        __syncthreads();
        {
            int row = tid >> 2, c = (tid & 3) * 8;
            if (row < tl) {
                *(short8b*)&Ks[row][c] =
                    *(const short8b*)(base + (size_t)(kt + row) * (3 * DM) + DM + hh * HD + c);
                short8b v8 = *(const short8b*)(base + (size_t)(kt + row) * (3 * DM) + 2 * DM + hh * HD + c);
                #pragma unroll
                for (int j = 0; j < 8; ++j) Vt[c + j][row] = ((unsigned short*)&v8)[j];
            }
        }
        __syncthreads();
        f32x4 sf[4];
        #pragma unroll
        for (int ks = 0; ks < 4; ++ks) {
            if (ks < nks) {
                short8b kb = *(const short8b*)&Ks[ks * 16 + lr][lg * 8];
                sf[ks] = __builtin_amdgcn_mfma_f32_16x16x32_bf16(qa, kb, (f32x4){0.f, 0.f, 0.f, 0.f}, 0, 0, 0);
            }
        }
        float pv[4][4];
        #pragma unroll
        for (int r = 0; r < 4; ++r) {
            float tmax = -1e30f;
            #pragma unroll
            for (int ks = 0; ks < 4; ++ks) {
                if (ks < nks) {
                    float sv = sf[ks][r] * 0.17677669529663687f
                             - slope * fabsf((float)(qg0 + r - (kt + ks * 16 + lr)));
                    pv[ks][r] = sv;
                    tmax = fmaxf(tmax, sv);
                }
            }
            #pragma unroll
            for (int o = 1; o < 16; o <<= 1) tmax = fmaxf(tmax, __shfl_xor(tmax, o));
            float mnew = fmaxf(m_run[r], tmax);
            float sc = __expf(m_run[r] - mnew);
            m_run[r] = mnew;
            float tsum = 0.f;
            #pragma unroll
            for (int ks = 0; ks < 4; ++ks) {
                if (ks < nks) {
                    float e = __expf(pv[ks][r] - mnew);
                    pv[ks][r] = e;
                    tsum += e;
                }
            }
            #pragma unroll
            for (int o = 1; o < 16; o <<= 1) tsum += __shfl_xor(tsum, o);
            l_run[r] = l_run[r] * sc + tsum;
            of0[r] *= sc; of1[r] *= sc;
        }
        #pragma unroll
        for (int ks = 0; ks < 4; ++ks)
            #pragma unroll
            for (int r = 0; r < 4; ++r)
                Ps[w][lg * 4 + r][ks * 16 + lr] = (ks < nks) ? f2bf(pv[ks][r]) : (unsigned short)0;
        #pragma unroll
        for (int kc = 0; kc < 64; kc += 32) {
            if (kc < nks * 16) {
                short8b pa = *(const short8b*)&Ps[w][lr][kc + lg * 8];
                short8b vb0 = *(const short8b*)&Vt[lr][kc + lg * 8];
                short8b vb1 = *(const short8b*)&Vt[16 + lr][kc + lg * 8];
                of0 = __builtin_amdgcn_mfma_f32_16x16x32_bf16(pa, vb0, of0, 0, 0, 0);
                of1 = __builtin_amdgcn_mfma_f32_16x16x32_bf16(pa, vb1, of1, 0, 0, 0);
            }
        }
    }
    #pragma unroll
    for (int r = 0; r < 4; ++r) {
        int q = qg0 + r;
        if (q < SS) {
            float inv = 1.0f / l_run[r];
            out[((size_t)(b * SS + q)) * DM + hh * HD + lr] = f2bf(of0[r] * inv);
            out[((size_t)(b * SS + q)) * DM + hh * HD + 16 + lr] = f2bf(of1[r] * inv);
        }
    }
}

// ---------- final: d2 conv + r4 1x1 conv + alpha blend; inputs bf16 TM ----------
__global__ __launch_bounds__(256) void final2_k(const unsigned short* __restrict__ ud1,
                                                const unsigned short* __restrict__ r3i,
                                                const float* __restrict__ d2w,
                                                const float* __restrict__ d2b,
                                                const float* __restrict__ r4w,
                                                const float* __restrict__ r4b,
                                                const float* __restrict__ alpha,
                                                float* __restrict__ out) {
    __shared__ float u_s[64][66];
    __shared__ float r_s[64][64];
    __shared__ float wd_s[64][3][12];
    __shared__ float wr_s[64][12];
    __shared__ float o_s[64][12];
    const int b = blockIdx.z, t0 = blockIdx.x * 64, tid = threadIdx.x;
    for (int u2 = tid; u2 < 66 * 8; u2 += 256) {
        int j = u2 >> 3, q = u2 & 7;
        int t = t0 + j - 1;
        short8b v = (short8b){0, 0, 0, 0, 0, 0, 0, 0};
        if (t >= 0 && t < TLEN) v = *(const short8b*)&ud1[((size_t)(b * TLEN + t)) * 64 + q * 8];
        #pragma unroll
        for (int i = 0; i < 8; ++i) u_s[q * 8 + i][j] = bf2f((unsigned short)v[i]);
    }
    for (int u2 = tid; u2 < 64 * 8; u2 += 256) {
        int j = u2 >> 3, q = u2 & 7;
        int t = t0 + j;
        short8b v = (short8b){0, 0, 0, 0, 0, 0, 0, 0};
        if (t < TLEN) v = *(const short8b*)&r3i[((size_t)(b * TLEN + t)) * 64 + q * 8];
        #pragma unroll
        for (int i = 0; i < 8; ++i) r_s[q * 8 + i][j] = bf2f((unsigned short)v[i]);
    }
    for (int idx = tid; idx < 64 * 3 * 12; idx += 256) {
        int l = idx % 12, k = (idx / 12) % 3, ci = idx / 36;
        wd_s[ci][k][l] = d2w[(l * 64 + ci) * 3 + k];
    }
    for (int idx = tid; idx < 64 * 12; idx += 256) {
        int l = idx % 12, ci = idx / 12;
        wr_s[ci][l] = r4w[l * 64 + ci];
    }
    __syncthreads();
    const int tl = tid & 63, lg = tid >> 6;
    float accD[3] = {}, accR[3] = {};
    for (int ci = 0; ci < 64; ++ci) {
        float a0 = u_s[ci][tl], a1 = u_s[ci][tl + 1], a2 = u_s[ci][tl + 2];
        float rv = r_s[ci][tl];
        #pragma unroll
        for (int c = 0; c < 3; ++c) {
            int l = lg * 3 + c;
            accD[c] += a0 * wd_s[ci][0][l] + a1 * wd_s[ci][1][l] + a2 * wd_s[ci][2][l];
            accR[c] = fmaf(rv, wr_s[ci][l], accR[c]);
        }
    }
    float al = alpha[0];
    #pragma unroll
    for (int c = 0; c < 3; ++c) {
        int l = lg * 3 + c;
        o_s[tl][l] = accD[c] + d2b[l] + al * (accR[c] + r4b[l]);
    }
    __syncthreads();
    for (int idx = tid; idx < 64 * 12; idx += 256) {
        int t = t0 + idx / 12;
        if (t < TLEN) out[((size_t)b * TLEN + t) * 12 + idx % 12] = o_s[idx / 12][idx % 12];
    }
}

extern "C" void kernel_launch(void* const* d_in, const int* in_sizes, int n_in,
                              void* d_out, int out_size, void* d_ws, size_t ws_size,
                              hipStream_t stream) {
    const float* x     = (const float*)d_in[0];
    const float* pe_w1 = (const float*)d_in[1];
    const float* pe_b1 = (const float*)d_in[2];
    const float* pe_w2 = (const float*)d_in[3];
    const float* pe_b2 = (const float*)d_in[4];
    const float* pe_pw = (const float*)d_in[5];
    const float* pe_pb = (const float*)d_in[6];
    const float* pe_g  = (const float*)d_in[7];
    const float* pe_bb = (const float*)d_in[8];
    const float* cb    = (const float*)d_in[9];
    const float* tp_w  = (const float*)d_in[10];
    const float* tp_b  = (const float*)d_in[11];
    const float* tp_g  = (const float*)d_in[12];
    const float* tp_bb = (const float*)d_in[13];
    const float* ln1_g = (const float*)d_in[14];
    const float* ln1_b = (const float*)d_in[15];
    const float* inw   = (const float*)d_in[16];
    const float* inb   = (const float*)d_in[17];
    const float* ow    = (const float*)d_in[18];
    const float* ob    = (const float*)d_in[19];
    const float* ln2_g = (const float*)d_in[20];
    const float* ln2_b = (const float*)d_in[21];
    const float* f1w   = (const float*)d_in[22];
    const float* f1b   = (const float*)d_in[23];
    const float* f2w   = (const float*)d_in[24];
    const float* f2b   = (const float*)d_in[25];
    const float* slopes= (const float*)d_in[26];
    const float* fn_g  = (const float*)d_in[27];
    const float* fn_b  = (const float*)d_in[28];
    const float* up_w  = (const float*)d_in[29];
    const float* up_b  = (const float*)d_in[30];
    const float* d1w   = (const float*)d_in[31];
    const float* d1b   = (const float*)d_in[32];
    const float* d2w   = (const float*)d_in[33];
    const float* d2b   = (const float*)d_in[34];
    const float* r1w   = (const float*)d_in[35];
    const float* r1b   = (const float*)d_in[36];
    const float* r2w   = (const float*)d_in[37];
    const float* r2b   = (const float*)d_in[38];
    const float* r3w   = (const float*)d_in[39];
    const float* r3b   = (const float*)d_in[40];
    const float* r4w   = (const float*)d_in[41];
    const float* r4b   = (const float*)d_in[42];
    const float* alpha = (const float*)d_in[43];

    float* W = (float*)d_ws;
    size_t off = 0;
    auto alloc = [&](size_t n) { float* p = W + off; off += (n + 3) & ~(size_t)3; return p; };
    const size_t M = (size_t)BATCH * SS;  // 6400
    float* A    = alloc((size_t)BATCH * DP * TLEN);
    float* Bb   = alloc((size_t)BATCH * 64 * TLEN);
    float* ze   = alloc(M * DP);
    float* tx   = alloc(M * DM);
    float* hb   = alloc(M * DM);
    float* qf   = alloc(M * 3 * DM);
    float* cbn  = alloc(VV);
    float* vqs  = alloc(M);
    float* upb2 = alloc(1152);
    float* pval = alloc(4 * M);
    int*   pidx = (int*)alloc(4 * M);
    unsigned short* zqb  = (unsigned short*)alloc(M * DP / 2);
    unsigned short* xnb  = (unsigned short*)alloc(M * DM / 2);
    unsigned short* aob  = (unsigned short*)alloc(M * DM / 2);
    float* pgpart        = qf;
    unsigned short* qkvb = (unsigned short*)qf;
    unsigned short* ffb  = (unsigned short*)qf;
    unsigned short* utm  = (unsigned short*)qf;
    unsigned short* inwb = (unsigned short*)alloc((size_t)NLAY * 3 * DM * DM / 2);
    unsigned short* owb  = (unsigned short*)alloc((size_t)NLAY * DM * DM / 2);
    unsigned short* f1wb = (unsigned short*)alloc((size_t)NLAY * 4 * DM * DM / 2);
    unsigned short* f2wb = (unsigned short*)alloc((size_t)NLAY * 4 * DM * DM / 2);
    unsigned short* tpwb = (unsigned short*)alloc((size_t)DM * DP / 2);
    unsigned short* upwb = (unsigned short*)alloc((size_t)1152 * DM / 2);
    unsigned short* pwh  = (unsigned short*)alloc((size_t)128 * 1152 / 2);
    unsigned short* pwl  = (unsigned short*)alloc((size_t)128 * 1152 / 2);
    unsigned short* w2h  = (unsigned short*)alloc((size_t)3 * 128 * 64 / 2);
    unsigned short* w2l  = (unsigned short*)alloc((size_t)3 * 128 * 64 / 2);
    unsigned short* cbh  = (unsigned short*)alloc((size_t)VV * DP / 2);
    unsigned short* cbl  = (unsigned short*)alloc((size_t)VV * DP / 2);
    unsigned short* r2pk = (unsigned short*)alloc((size_t)64 * 64 * 5 / 2);
    unsigned short* r3pk = (unsigned short*)alloc((size_t)64 * 64 * 3 / 2 + 2);
    unsigned short* d1pk = (unsigned short*)alloc((size_t)64 * 128 * 5 / 2);
    unsigned short* r1tm = (unsigned short*)alloc((size_t)BATCH * TLEN * 64 / 2);
    unsigned short* r2tm = (unsigned short*)alloc((size_t)BATCH * TLEN * 64 / 2);
    unsigned short* r3tm = (unsigned short*)alloc((size_t)BATCH * TLEN * 64 / 2);
    unsigned short* d1tm = (unsigned short*)alloc((size_t)BATCH * TLEN * 64 / 2);
    if (off * sizeof(float) > ws_size) return;

    float* outp = (float*)d_out;
    const dim3 cgrid(57, 1, BATCH);
    const dim3 mgrid(29, 1, BATCH);

    // --- weight conversions / packs ---
    tobf_k<<<(NLAY * 3 * DM * DM + 255) / 256, 256, 0, stream>>>(inw, inwb, NLAY * 3 * DM * DM);
    tobf_k<<<(NLAY * DM * DM + 255) / 256, 256, 0, stream>>>(ow, owb, NLAY * DM * DM);
    tobf_k<<<(NLAY * 4 * DM * DM + 255) / 256, 256, 0, stream>>>(f1w, f1wb, NLAY * 4 * DM * DM);
    tobf_k<<<(NLAY * 4 * DM * DM + 255) / 256, 256, 0, stream>>>(f2w, f2wb, NLAY * 4 * DM * DM);
    tobf_k<<<(DM * DP + 255) / 256, 256, 0, stream>>>(tp_w, tpwb, DM * DP);
    upwt2_k<<<(1152 * 256 + 255) / 256, 256, 0, stream>>>(up_w, up_b, upwb, upb2);
    pwpack3_k<<<(128 * 1152 + 255) / 256, 256, 0, stream>>>(pe_pw, pwh, pwl);
    pwpack2_k<<<(3 * 128 * 64 + 255) / 256, 256, 0, stream>>>(pe_w2, w2h, w2l);
    cbpack_k<<<(VV * DP + 255) / 256, 256, 0, stream>>>(cb, cbh, cbl);
    cpack_k<<<(64 * 64 * 5 + 255) / 256, 256, 0, stream>>>(r2w, r2pk, 64, 64, 5);
    cpack_k<<<(64 * 64 * 3 + 255) / 256, 256, 0, stream>>>(r3w, r3pk, 64, 64, 3);
    cpack_k<<<(64 * 128 * 5 + 255) / 256, 256, 0, stream>>>(d1w, d1pk, 64, 128, 5);

    // --- fused pe1 + r1 ---
    enc1_k<<<dim3(57, BATCH), 256, 0, stream>>>(x, pe_w1, pe_b1, r1w, r1b, Bb, r1tm);

    // --- encoder tail ---
    pe2m_k<<<dim3(29, BATCH), 256, 0, stream>>>(Bb, w2h, w2l, pe_b2, A);
    cbnorm_k<<<2, 256, 0, stream>>>(cb, cbn);
    pproj3_k<<<dim3(1, M / 128, 6), 256, 0, stream>>>(A, pwh, pwl, pgpart, M);
    ln128s_k<<<M, 128, 0, stream>>>(pgpart, pe_pb, pe_g, pe_bb, ze, M);
    vq3_k<<<dim3(4, M / 128), 256, 0, stream>>>(ze, cbh, cbl, cbn, pval, pidx, M);
    vqfin_k<<<M, 128, 0, stream>>>(ze, cb, pval, pidx, zqb, vqs, M);
    vqreduce_k<<<1, 256, 0, stream>>>(vqs, outp + (size_t)BATCH * TLEN * LEADS);

    // --- residual CNN ---
    mfconv_k<64, 5, 2><<<mgrid, 256, 0, stream>>>(r1tm, r2pk, r2b, r2tm);
    mfconv_k<64, 3, 1><<<mgrid, 256, 0, stream>>>(r2tm, r3pk, r3b, r3tm);

    // --- token projection + LN ---
    bgemm64_k<0, 0, 0><<<dim3(DM / 128, M / 64), 256, 0, stream>>>(zqb, tpwb, tp_b, nullptr, tx, M, DM, DP);
    lnw_k<0><<<M / 4, 256, 0, stream>>>(tx, tp_g, tp_bb, hb);

    // --- transformer ---
    for (int l = 0; l < NLAY; ++l) {
        lnw_k<1><<<M / 4, 256, 0, stream>>>(hb, ln1_g + l * DM, ln1_b + l * DM, xnb);
        bgemm_k<0, 0, 1><<<dim3(3 * DM / 128, M / 128), 256, 0, stream>>>(
            xnb, inwb + (size_t)l * 3 * DM * DM, inb + l * 3 * DM, nullptr, qkvb, M, 3 * DM, DM);
        fattn_k<<<dim3((SS + 63) / 64, NH, BATCH), 256, 0, stream>>>(qkvb, slopes + l * NH, aob);
        bgemm64_k<0, 1, 0><<<dim3(DM / 128, M / 64), 256, 0, stream>>>(
            aob, owb + (size_t)l * DM * DM, ob + l * DM, hb, hb, M, DM, DM);
        lnw_k<1><<<M / 4, 256, 0, stream>>>(hb, ln2_g + l * DM, ln2_b + l * DM, xnb);
        bgemm_k<1, 0, 1><<<dim3(4 * DM / 128, M / 128), 256, 0, stream>>>(
            xnb, f1wb + (size_t)l * 4 * DM * DM, f1b + l * 4 * DM, nullptr, ffb, M, 4 * DM, DM);
        bgemm64_k<0, 1, 0><<<dim3(DM / 128, M / 64), 256, 0, stream>>>(
            ffb, f2wb + (size_t)l * 4 * DM * DM, f2b + l * DM, hb, hb, M, DM, 4 * DM);
    }
    lnw_k<1><<<M / 4, 256, 0, stream>>>(hb, fn_g, fn_b, xnb);

    // --- decoder ---
    bgemm_k<1, 0, 1><<<dim3(1152 / 128, M / 128), 256, 0, stream>>>(xnb, upwb, upb2, nullptr, utm, M, 1152, DM);
    mfconv_k<128, 5, 2><<<mgrid, 256, 0, stream>>>(utm, d1pk, d1b, d1tm);

    // --- fused d2 conv + r4 conv + alpha blend ---
    final2_k<<<cgrid, 256, 0, stream>>>(d1tm, r3tm, d2w, d2b, r4w, r4b, alpha, outp);
}

// Round 13
// 719.371 us; speedup vs baseline: 1.1375x; 1.0323x over previous
//
#include <hip/hip_runtime.h>
#include <hip/hip_bf16.h>
#include <math.h>

#define BATCH 16
#define TLEN 3600
#define LEADS 12
#define PP 9
#define SS 400
#define DP 128
#define DM 256
#define NH 8
#define HD 32
#define NLAY 6
#define VV 512
#define RH 64

typedef __attribute__((ext_vector_type(8))) short short8b;
typedef __attribute__((ext_vector_type(4))) float f32x4;

__device__ __forceinline__ float gelu_f(float x) {
    return 0.5f * x * (1.0f + erff(x * 0.70710678118654752f));
}

__device__ __forceinline__ unsigned short f2bf(float f) {
    union { float f; unsigned u; } v; v.f = f;
    return (unsigned short)((v.u + 0x7FFFu + ((v.u >> 16) & 1u)) >> 16);
}

__device__ __forceinline__ float bf2f(unsigned short h) {
    union { unsigned u; float f; } v; v.u = ((unsigned)h) << 16; return v.f;
}

// ---------- block reduction helpers ----------
__device__ __forceinline__ float block_sum_256(float v, float* sm) {
    #pragma unroll
    for (int o = 32; o > 0; o >>= 1) v += __shfl_down(v, o);
    __syncthreads();
    if ((threadIdx.x & 63) == 0) sm[threadIdx.x >> 6] = v;
    __syncthreads();
    return sm[0] + sm[1] + sm[2] + sm[3];
}

__device__ __forceinline__ float block_sum_128(float v, float* sm) {
    #pragma unroll
    for (int o = 32; o > 0; o >>= 1) v += __shfl_down(v, o);
    __syncthreads();
    if ((threadIdx.x & 63) == 0) sm[threadIdx.x >> 6] = v;
    __syncthreads();
    return sm[0] + sm[1];
}

// ---------- ALL weight packs + codebook prep in ONE kernel ----------
__global__ void packall_k(const float* __restrict__ inw, unsigned short* __restrict__ inwb,
                          const float* __restrict__ ow,  unsigned short* __restrict__ owb,
                          const float* __restrict__ f1w, unsigned short* __restrict__ f1wb,
                          const float* __restrict__ f2w, unsigned short* __restrict__ f2wb,
                          const float* __restrict__ tpw, unsigned short* __restrict__ tpwb,
                          const float* __restrict__ upw, const float* __restrict__ upb,
                          unsigned short* __restrict__ upwb, float* __restrict__ upb2,
                          const float* __restrict__ ppw, unsigned short* __restrict__ pwh,
                          unsigned short* __restrict__ pwl,
                          const float* __restrict__ w2, unsigned short* __restrict__ w2h,
                          unsigned short* __restrict__ w2l,
                          const float* __restrict__ cb, unsigned short* __restrict__ cbh,
                          unsigned short* __restrict__ cbl, float* __restrict__ cbn,
                          const float* __restrict__ r2w, unsigned short* __restrict__ r2pk,
                          const float* __restrict__ r3w, unsigned short* __restrict__ r3pk,
                          const float* __restrict__ d1w, unsigned short* __restrict__ d1pk) {
    long idx = (long)blockIdx.x * 256 + threadIdx.x;
    const long S0 = 1179648, S1 = 393216, S2 = 1572864, S3 = 1572864, S4 = 32768,
               S5 = 294912, S6 = 147456, S7 = 24576, S8 = 65536, S8b = 512,
               S9 = 20480, S10 = 12288, S11 = 40960;
    if (idx < S0) { inwb[idx] = f2bf(inw[idx]); return; } idx -= S0;
    if (idx < S1) { owb[idx] = f2bf(ow[idx]); return; } idx -= S1;
    if (idx < S2) { f1wb[idx] = f2bf(f1w[idx]); return; } idx -= S2;
    if (idx < S3) { f2wb[idx] = f2bf(f2w[idx]); return; } idx -= S3;
    if (idx < S4) { tpwb[idx] = f2bf(tpw[idx]); return; } idx -= S4;
    if (idx < S5) {                               // upwt2: W'[n][d], n=k*128+o
        int d = (int)(idx & 255), n = (int)(idx >> 8);
        int o = n & 127, k = n >> 7;
        upwb[(size_t)n * 256 + d] = f2bf(upw[(size_t)d * 1152 + o * 9 + k]);
        if (idx < 1152) upb2[idx] = upb[idx & 127];
        return;
    } idx -= S5;
    if (idx < S6) {                               // pwpack3: hi/lo, kidx=kk*128+co
        int n = (int)(idx % 1152), d = (int)(idx / 1152);
        int co = n & 127, kk = n >> 7;
        float v = ppw[(size_t)d * 1152 + co * 9 + kk];
        unsigned short h = f2bf(v);
        pwh[idx] = h; pwl[idx] = f2bf(v - bf2f(h));
        return;
    } idx -= S6;
    if (idx < S7) {                               // pwpack2
        int ci = (int)(idx & 63); long rest = idx >> 6; int co = (int)(rest & 127); int k = (int)(rest >> 7);
        float v = w2[((size_t)co * 64 + ci) * 3 + k];
        unsigned short h = f2bf(v);
        w2h[idx] = h; w2l[idx] = f2bf(v - bf2f(h));
        return;
    } idx -= S7;
    if (idx < S8) {                               // cbpack
        float v = cb[idx];
        unsigned short h = f2bf(v);
        cbh[idx] = h; cbl[idx] = f2bf(v - bf2f(h));
        return;
    } idx -= S8;
    if (idx < S8b) {                              // cbnorm
        const float* cr = cb + (size_t)idx * DP;
        float s = 0;
        for (int i = 0; i < DP; ++i) s += cr[i] * cr[i];
        cbn[idx] = s;
        return;
    } idx -= S8b;
    if (idx < S9) {                               // r2 cpack (Co=64,CI=64,K=5)
        int ci = (int)(idx % 64); long rest = idx / 64; int co = (int)(rest % 64); int k = (int)(rest / 64);
        r2pk[idx] = f2bf(r2w[((size_t)co * 64 + ci) * 5 + k]);
        return;
    } idx -= S9;
    if (idx < S10) {                              // r3 cpack (Co=64,CI=64,K=3)
        int ci = (int)(idx % 64); long rest = idx / 64; int co = (int)(rest % 64); int k = (int)(rest / 64);
        r3pk[idx] = f2bf(r3w[((size_t)co * 64 + ci) * 3 + k]);
        return;
    } idx -= S10;
    if (idx < S11) {                              // d1 cpack (Co=64,CI=128,K=5)
        int ci = (int)(idx % 128); long rest = idx / 128; int co = (int)(rest % 64); int k = (int)(rest / 64);
        d1pk[idx] = f2bf(d1w[((size_t)co * 128 + ci) * 5 + k]);
        return;
    }
}

// ---------- fused pe1 + r1: both read x (B,T,12) ----------
__global__ __launch_bounds__(256, 4) void enc1_k(const float* __restrict__ x,
                                                 const float* __restrict__ w1,
                                                 const float* __restrict__ b1,
                                                 const float* __restrict__ w7,
                                                 const float* __restrict__ b7,
                                                 float* __restrict__ out1,
                                                 unsigned short* __restrict__ out7) {
    __shared__ __align__(16) float xs[12][80];
    __shared__ float w1s[12][3][64];
    __shared__ float w7s[12][7][64];
    const int b = blockIdx.y, t0 = blockIdx.x * 64, tid = threadIdx.x;
    const int tx = tid & 15, ty = tid >> 4;
    for (int idx = tid; idx < 70 * 12; idx += 256) {
        int j = idx / 12, ci = idx - j * 12;
        int t = t0 + j - 3;
        xs[ci][j] = (t >= 0 && t < TLEN) ? x[((size_t)b * TLEN + t) * 12 + ci] : 0.f;
    }
    for (int idx = tid; idx < 12 * 3 * 64; idx += 256) {
        int co = idx & 63; int rest = idx >> 6; int k = rest % 3; int ci = rest / 3;
        w1s[ci][k][co] = w1[(co * 12 + ci) * 3 + k];
    }
    for (int idx = tid; idx < 12 * 7 * 64; idx += 256) {
        int co = idx & 63; int rest = idx >> 6; int k = rest % 7; int ci = rest / 7;
        w7s[ci][k][co] = w7[(co * 12 + ci) * 7 + k];
    }
    __syncthreads();
    float a1[4][4] = {}, a7[4][4] = {};
    #pragma unroll 2
    for (int ci = 0; ci < 12; ++ci) {
        float tv[12];
        *(float4*)&tv[0] = *(const float4*)&xs[ci][tx * 4];
        *(float4*)&tv[4] = *(const float4*)&xs[ci][tx * 4 + 4];
        *(float4*)&tv[8] = *(const float4*)&xs[ci][tx * 4 + 8];
        #pragma unroll
        for (int k = 0; k < 7; ++k) {
            float4 wv = *(const float4*)&w7s[ci][k][ty * 4];
            #pragma unroll
            for (int j = 0; j < 4; ++j) {
                float iv = tv[j + k];
                a7[0][j] = fmaf(wv.x, iv, a7[0][j]);
                a7[1][j] = fmaf(wv.y, iv, a7[1][j]);
                a7[2][j] = fmaf(wv.z, iv, a7[2][j]);
                a7[3][j] = fmaf(wv.w, iv, a7[3][j]);
            }
        }
        #pragma unroll
        for (int k = 0; k < 3; ++k) {
            float4 wv = *(const float4*)&w1s[ci][k][ty * 4];
            #pragma unroll
            for (int j = 0; j < 4; ++j) {
                float iv = tv[j + k + 2];
                a1[0][j] = fmaf(wv.x, iv, a1[0][j]);
                a1[1][j] = fmaf(wv.y, iv, a1[1][j]);
                a1[2][j] = fmaf(wv.z, iv, a1[2][j]);
                a1[3][j] = fmaf(wv.w, iv, a1[3][j]);
            }
        }
    }
    float4 b1v4 = *(const float4*)&b1[ty * 4];
    #pragma unroll
    for (int j = 0; j < 4; ++j) {
        int t = t0 + tx * 4 + j;
        if (t < TLEN) {
            float4 o4;
            o4.x = gelu_f(a1[0][j] + b1v4.x);
            o4.y = gelu_f(a1[1][j] + b1v4.y);
            o4.z = gelu_f(a1[2][j] + b1v4.z);
            o4.w = gelu_f(a1[3][j] + b1v4.w);
            *(float4*)&out1[((size_t)(b * TLEN + t)) * 64 + ty * 4] = o4;
        }
    }
    float bv0 = b7[ty * 4], bv1 = b7[ty * 4 + 1], bv2 = b7[ty * 4 + 2], bv3 = b7[ty * 4 + 3];
    #pragma unroll
    for (int j = 0; j < 4; ++j) {
        int t = t0 + tx * 4 + j;
        if (t < TLEN) {
            unsigned long long pk =
                  (unsigned long long)f2bf(gelu_f(a7[0][j] + bv0))
                | ((unsigned long long)f2bf(gelu_f(a7[1][j] + bv1)) << 16)
                | ((unsigned long long)f2bf(gelu_f(a7[2][j] + bv2)) << 32)
                | ((unsigned long long)f2bf(gelu_f(a7[3][j] + bv3)) << 48);
            *(unsigned long long*)&out7[((size_t)(b * TLEN + t)) * 64 + ty * 4] = pk;
        }
    }
}

// ---------- pe2 hi/lo MFMA conv ----------
__global__ __launch_bounds__(256) void pe2m_k(const float* __restrict__ in,
                                              const unsigned short* __restrict__ wh,
                                              const unsigned short* __restrict__ wl,
                                              const float* __restrict__ bias,
                                              float* __restrict__ out) {
    __shared__ __align__(16) unsigned short Ah[130][72];
    __shared__ __align__(16) unsigned short Al[130][72];
    __shared__ __align__(16) unsigned short Wh_s[128][72];
    __shared__ __align__(16) unsigned short Wl_s[128][72];
    const int b = blockIdx.y, t0 = blockIdx.x * 128, tid = threadIdx.x;
    const int w = tid >> 6, lane = tid & 63;
    const int fr = lane & 15, kg = (lane >> 4) * 8;
    for (int u = tid; u < 130 * 8; u += 256) {
        int row = u >> 3, q = u & 7;
        int t = t0 + row - 1;
        short8b h8 = (short8b){0, 0, 0, 0, 0, 0, 0, 0};
        short8b l8 = (short8b){0, 0, 0, 0, 0, 0, 0, 0};
        if (t >= 0 && t < TLEN) {
            const float* src = in + ((size_t)(b * TLEN + t)) * 64 + q * 8;
            float4 v0 = *(const float4*)src;
            float4 v1 = *(const float4*)(src + 4);
            float vv[8] = {v0.x, v0.y, v0.z, v0.w, v1.x, v1.y, v1.z, v1.w};
            #pragma unroll
            for (int e = 0; e < 8; ++e) {
                unsigned short h = f2bf(vv[e]);
                h8[e] = (short)h;
                l8[e] = (short)f2bf(vv[e] - bf2f(h));
            }
        }
        *(short8b*)&Ah[row][q * 8] = h8;
        *(short8b*)&Al[row][q * 8] = l8;
    }
    f32x4 acc[2][8];
    #pragma unroll
    for (int i = 0; i < 2; ++i)
        #pragma unroll
        for (int j = 0; j < 8; ++j) acc[i][j] = (f32x4){0.f, 0.f, 0.f, 0.f};
    for (int k = 0; k < 3; ++k) {
        __syncthreads();
        for (int u = tid; u < 128 * 8; u += 256) {
            int co = u >> 3, q = u & 7;
            *(short8b*)&Wh_s[co][q * 8] = *(const short8b*)&wh[((size_t)(k * 128 + co)) * 64 + q * 8];
            *(short8b*)&Wl_s[co][q * 8] = *(const short8b*)&wl[((size_t)(k * 128 + co)) * 64 + q * 8];
        }
        __syncthreads();
        #pragma unroll
        for (int c32 = 0; c32 < 2; ++c32) {
            short8b ah0 = *(const short8b*)&Ah[w * 32 + fr + k][c32 * 32 + kg];
            short8b ah1 = *(const short8b*)&Ah[w * 32 + 16 + fr + k][c32 * 32 + kg];
            short8b al0 = *(const short8b*)&Al[w * 32 + fr + k][c32 * 32 + kg];
            short8b al1 = *(const short8b*)&Al[w * 32 + 16 + fr + k][c32 * 32 + kg];
            #pragma unroll
            for (int j = 0; j < 8; ++j) {
                short8b bh = *(const short8b*)&Wh_s[j * 16 + fr][c32 * 32 + kg];
                short8b bl = *(const short8b*)&Wl_s[j * 16 + fr][c32 * 32 + kg];
                acc[0][j] = __builtin_amdgcn_mfma_f32_16x16x32_bf16(ah0, bh, acc[0][j], 0, 0, 0);
                acc[0][j] = __builtin_amdgcn_mfma_f32_16x16x32_bf16(ah0, bl, acc[0][j], 0, 0, 0);
                acc[0][j] = __builtin_amdgcn_mfma_f32_16x16x32_bf16(al0, bh, acc[0][j], 0, 0, 0);
                acc[1][j] = __builtin_amdgcn_mfma_f32_16x16x32_bf16(ah1, bh, acc[1][j], 0, 0, 0);
                acc[1][j] = __builtin_amdgcn_mfma_f32_16x16x32_bf16(ah1, bl, acc[1][j], 0, 0, 0);
                acc[1][j] = __builtin_amdgcn_mfma_f32_16x16x32_bf16(al1, bh, acc[1][j], 0, 0, 0);
            }
        }
    }
    const int orow = (lane >> 4) * 4, ocol = lane & 15;
    #pragma unroll
    for (int i = 0; i < 2; ++i)
        #pragma unroll
        for (int j = 0; j < 8; ++j) {
            const int co = j * 16 + ocol;
            const float bv = bias[co];
            #pragma unroll
            for (int r = 0; r < 4; ++r) {
                int t = t0 + w * 32 + i * 16 + orow + r;
                if (t < TLEN) {
                    int s = t / PP, kk = t - s * PP;
                    out[((size_t)(b * SS + s)) * 1152 + kk * 128 + co] = gelu_f(acc[i][j][r] + bv);
                }
            }
        }
}

// ---------- patch projection: hi/lo 3-MFMA, 6-way split-K ----------
__global__ __launch_bounds__(256) void pproj3_k(const float* __restrict__ A,
                                                const unsigned short* __restrict__ Wh,
                                                const unsigned short* __restrict__ Wl,
                                                float* __restrict__ Cp,
                                                int M) {
    __shared__ __align__(16) unsigned short Ah[128][40];
    __shared__ __align__(16) unsigned short Al[128][40];
    __shared__ __align__(16) unsigned short Bh[128][40];
    __shared__ __align__(16) unsigned short Bl[128][40];
    const int tid = threadIdx.x;
    const int gm0 = blockIdx.y * 128;
    const int z = blockIdx.z;
    const int w = tid >> 6, lane = tid & 63;
    const int wr0 = (w >> 1) * 64, wc0 = (w & 1) * 64;
    const int srow = tid >> 1, sc = (tid & 1) * 16;
    const int K = 1152;
    const int kb = z * 192;
    f32x4 acc[4][4];
    #pragma unroll
    for (int i = 0; i < 4; ++i)
        #pragma unroll
        for (int j = 0; j < 4; ++j) acc[i][j] = (f32x4){0.f, 0.f, 0.f, 0.f};
    const int fr = lane & 15, kg = (lane >> 4) * 8;
    for (int s = 0; s < 6; ++s) {
        const int k0 = kb + s * 32;
        __syncthreads();
        {
            const float* ga = A + (size_t)(gm0 + srow) * K + k0 + sc;
            #pragma unroll
            for (int g = 0; g < 2; ++g) {
                float4 v0 = *(const float4*)(ga + g * 8);
                float4 v1 = *(const float4*)(ga + g * 8 + 4);
                short8b h8, l8;
                float vv[8] = {v0.x, v0.y, v0.z, v0.w, v1.x, v1.y, v1.z, v1.w};
                #pragma unroll
                for (int e = 0; e < 8; ++e) {
                    unsigned short h = f2bf(vv[e]);
                    h8[e] = (short)h;
                    l8[e] = (short)f2bf(vv[e] - bf2f(h));
                }
                *(short8b*)&Ah[srow][sc + g * 8] = h8;
                *(short8b*)&Al[srow][sc + g * 8] = l8;
            }
            const unsigned short* gh = Wh + (size_t)srow * K + k0 + sc;
            const unsigned short* gl = Wl + (size_t)srow * K + k0 + sc;
            *(short8b*)&Bh[srow][sc] = *(const short8b*)gh;
            *(short8b*)&Bh[srow][sc + 8] = *(const short8b*)(gh + 8);
            *(short8b*)&Bl[srow][sc] = *(const short8b*)gl;
            *(short8b*)&Bl[srow][sc + 8] = *(const short8b*)(gl + 8);
        }
        __syncthreads();
        short8b afh[4], afl[4], bfh[4], bfl[4];
        #pragma unroll
        for (int i = 0; i < 4; ++i) {
            afh[i] = *(const short8b*)&Ah[wr0 + i * 16 + fr][kg];
            afl[i] = *(const short8b*)&Al[wr0 + i * 16 + fr][kg];
            bfh[i] = *(const short8b*)&Bh[wc0 + i * 16 + fr][kg];
            bfl[i] = *(const short8b*)&Bl[wc0 + i * 16 + fr][kg];
        }
        #pragma unroll
        for (int i = 0; i < 4; ++i)
            #pragma unroll
            for (int j = 0; j < 4; ++j) {
                acc[i][j] = __builtin_amdgcn_mfma_f32_16x16x32_bf16(afh[i], bfh[j], acc[i][j], 0, 0, 0);
                acc[i][j] = __builtin_amdgcn_mfma_f32_16x16x32_bf16(afh[i], bfl[j], acc[i][j], 0, 0, 0);
                acc[i][j] = __builtin_amdgcn_mfma_f32_16x16x32_bf16(afl[i], bfh[j], acc[i][j], 0, 0, 0);
            }
    }
    const int orow = (lane >> 4) * 4, ocol = lane & 15;
    float* Cz = Cp + (size_t)z * M * 128;
    #pragma unroll
    for (int i = 0; i < 4; ++i)
        #pragma unroll
        for (int j = 0; j < 4; ++j) {
            const int colg = wc0 + j * 16 + ocol;
            #pragma unroll
            for (int r = 0; r < 4; ++r) {
                const int rowg = gm0 + wr0 + i * 16 + orow + r;
                Cz[(size_t)rowg * 128 + colg] = acc[i][j][r];
            }
        }
}

// ---------- VQ distances via hi/lo 3-MFMA + in-wave argmin ----------
__global__ __launch_bounds__(256) void vq3_k(const float* __restrict__ ze,
                                             const unsigned short* __restrict__ ch,
                                             const unsigned short* __restrict__ cl,
                                             const float* __restrict__ cbn,
                                             float* __restrict__ pval,
                                             int* __restrict__ pidx,
                                             int M) {
    __shared__ __align__(16) unsigned short Ah[128][40];
    __shared__ __align__(16) unsigned short Al[128][40];
    __shared__ __align__(16) unsigned short Bh[128][40];
    __shared__ __align__(16) unsigned short Bl[128][40];
    __shared__ float bwv[128][2];
    __shared__ int bwi[128][2];
    const int tid = threadIdx.x;
    const int c0 = blockIdx.x * 128;
    const int gm0 = blockIdx.y * 128;
    const int w = tid >> 6, lane = tid & 63;
    const int wr0 = (w >> 1) * 64, wc0 = (w & 1) * 64;
    const int srow = tid >> 1, sc = (tid & 1) * 16;
    const int fr = lane & 15, kg = (lane >> 4) * 8;
    f32x4 acc[4][4];
    #pragma unroll
    for (int i = 0; i < 4; ++i)
        #pragma unroll
        for (int j = 0; j < 4; ++j) acc[i][j] = (f32x4){0.f, 0.f, 0.f, 0.f};
    for (int s = 0; s < 4; ++s) {
        const int k0 = s * 32;
        __syncthreads();
        {
            const float* ga = ze + (size_t)(gm0 + srow) * DP + k0 + sc;
            #pragma unroll
            for (int g = 0; g < 2; ++g) {
                float4 v0 = *(const float4*)(ga + g * 8);
                float4 v1 = *(const float4*)(ga + g * 8 + 4);
                short8b h8, l8;
                float vv[8] = {v0.x, v0.y, v0.z, v0.w, v1.x, v1.y, v1.z, v1.w};
                #pragma unroll
                for (int e = 0; e < 8; ++e) {
                    unsigned short h = f2bf(vv[e]);
                    h8[e] = (short)h;
                    l8[e] = (short)f2bf(vv[e] - bf2f(h));
                }
                *(short8b*)&Ah[srow][sc + g * 8] = h8;
                *(short8b*)&Al[srow][sc + g * 8] = l8;
            }
            const unsigned short* gh = ch + (size_t)(c0 + srow) * DP + k0 + sc;
            const unsigned short* gl = cl + (size_t)(c0 + srow) * DP + k0 + sc;
            *(short8b*)&Bh[srow][sc] = *(const short8b*)gh;
            *(short8b*)&Bh[srow][sc + 8] = *(const short8b*)(gh + 8);
            *(short8b*)&Bl[srow][sc] = *(const short8b*)gl;
            *(short8b*)&Bl[srow][sc + 8] = *(const short8b*)(gl + 8);
        }
        __syncthreads();
        short8b afh[4], afl[4], bfh[4], bfl[4];
        #pragma unroll
        for (int i = 0; i < 4; ++i) {
            afh[i] = *(const short8b*)&Ah[wr0 + i * 16 + fr][kg];
            afl[i] = *(const short8b*)&Al[wr0 + i * 16 + fr][kg];
            bfh[i] = *(const short8b*)&Bh[wc0 + i * 16 + fr][kg];
            bfl[i] = *(const short8b*)&Bl[wc0 + i * 16 + fr][kg];
        }
        #pragma unroll
        for (int i = 0; i < 4; ++i)
            #pragma unroll
            for (int j = 0; j < 4; ++j) {
                acc[i][j] = __builtin_amdgcn_mfma_f32_16x16x32_bf16(afh[i], bfh[j], acc[i][j], 0, 0, 0);
                acc[i][j] = __builtin_amdgcn_mfma_f32_16x16x32_bf16(afh[i], bfl[j], acc[i][j], 0, 0, 0);
                acc[i][j] = __builtin_amdgcn_mfma_f32_16x16x32_bf16(afl[i], bfh[j], acc[i][j], 0, 0, 0);
            }
    }
    const int orow = (lane >> 4) * 4, ocol = lane & 15;
    #pragma unroll
    for (int i = 0; i < 4; ++i)
        #pragma unroll
        for (int r = 0; r < 4; ++r) {
            int row = wr0 + i * 16 + orow + r;
            float bv = 1e30f; int bi = 0;
            #pragma unroll
            for (int j = 0; j < 4; ++j) {
                int col = c0 + wc0 + j * 16 + ocol;
                float d = cbn[col] - 2.0f * acc[i][j][r];
                if (d < bv || (d == bv && col < bi)) { bv = d; bi = col; }
            }
            #pragma unroll
            for (int o = 1; o < 16; o <<= 1) {
                float ov = __shfl_xor(bv, o);
                int oi = __shfl_xor(bi, o);
                if (ov < bv || (ov == bv && oi < bi)) { bv = ov; bi = oi; }
            }
            if (ocol == 0) { bwv[row][w & 1] = bv; bwi[row][w & 1] = bi; }
        }
    __syncthreads();
    if (tid < 128) {
        float v0 = bwv[tid][0], v1 = bwv[tid][1];
        int i0 = bwi[tid][0], i1 = bwi[tid][1];
        bool sel = (v1 < v0) || (v1 == v0 && i1 < i0);
        pval[(size_t)blockIdx.x * M + gm0 + tid] = sel ? v1 : v0;
        pidx[(size_t)blockIdx.x * M + gm0 + tid] = sel ? i1 : i0;
    }
}

// ---------- VQ finish ----------
__global__ __launch_bounds__(128) void vqfin_k(const float* __restrict__ ze,
                                               const float* __restrict__ cb,
                                               const float* __restrict__ pval,
                                               const int* __restrict__ pidx,
                                               unsigned short* __restrict__ zqb,
                                               float* __restrict__ vqs,
                                               int M) {
    const int row = blockIdx.x, tid = threadIdx.x;
    __shared__ float sm[2];
    __shared__ int tok_s;
    if (tid == 0) {
        float bv = pval[row]; int bi = pidx[row];
        #pragma unroll
        for (int z = 1; z < 4; ++z) {
            float v = pval[(size_t)z * M + row]; int ix = pidx[(size_t)z * M + row];
            if (v < bv || (v == bv && ix < bi)) { bv = v; bi = ix; }
        }
        tok_s = bi;
    }
    __syncthreads();
    int tok = tok_s;
    float qv = cb[(size_t)tok * DP + tid];
    float zv = ze[(size_t)row * DP + tid];
    zqb[(size_t)row * DP + tid] = f2bf(qv);
    float d = qv - zv;
    float tot = block_sum_128(d * d, sm);
    if (tid == 0) vqs[row] = tot;
}

// ---------- bf16 MFMA implicit-GEMM conv ----------
template <int CI, int K, int PAD>
__global__ __launch_bounds__(256) void mfconv_k(const unsigned short* __restrict__ in,
                                                const unsigned short* __restrict__ wpk,
                                                const float* __restrict__ bias,
                                                unsigned short* __restrict__ out) {
    constexpr int CIC = (CI > 64) ? 64 : CI;
    constexpr int NCH = CI / CIC;
    constexpr int TROWS = 128 + K - 1;
    constexpr int CQ = CIC / 8;
    __shared__ __align__(16) unsigned short in_s[TROWS][CIC + 8];
    __shared__ __align__(16) unsigned short w_s[K][64][CIC + 8];
    const int b = blockIdx.z;
    const int t0 = blockIdx.x * 128;
    const int tid = threadIdx.x;
    const int w = tid >> 6, lane = tid & 63;
    const int fr = lane & 15, kg = (lane >> 4) * 8;
    f32x4 acc[2][4];
    #pragma unroll
    for (int i = 0; i < 2; ++i)
        #pragma unroll
        for (int j = 0; j < 4; ++j) acc[i][j] = (f32x4){0.f, 0.f, 0.f, 0.f};
    for (int ch = 0; ch < NCH; ++ch) {
        const int c0 = ch * CIC;
        if (ch) __syncthreads();
        for (int u = tid; u < TROWS * CQ; u += 256) {
            int row = u / CQ, q = u - row * CQ;
            int t = t0 + row - PAD;
            short8b v = (short8b){0, 0, 0, 0, 0, 0, 0, 0};
            if (t >= 0 && t < TLEN)
                v = *(const short8b*)&in[((size_t)(b * TLEN + t)) * CI + c0 + q * 8];
            *(short8b*)&in_s[row][q * 8] = v;
        }
        for (int u = tid; u < K * 64 * CQ; u += 256) {
            int q = u % CQ; int rest = u / CQ; int co = rest & 63; int k = rest >> 6;
            *(short8b*)&w_s[k][co][q * 8] =
                *(const short8b*)&wpk[((size_t)(k * 64 + co)) * CI + c0 + q * 8];
        }
        __syncthreads();
        #pragma unroll
        for (int k = 0; k < K; ++k) {
            #pragma unroll
            for (int c32 = 0; c32 < CIC / 32; ++c32) {
                short8b a0 = *(const short8b*)&in_s[w * 32 + fr + k][c32 * 32 + kg];
                short8b a1 = *(const short8b*)&in_s[w * 32 + 16 + fr + k][c32 * 32 + kg];
                short8b b0 = *(const short8b*)&w_s[k][fr][c32 * 32 + kg];
                short8b b1 = *(const short8b*)&w_s[k][16 + fr][c32 * 32 + kg];
                short8b b2 = *(const short8b*)&w_s[k][32 + fr][c32 * 32 + kg];
                short8b b3 = *(const short8b*)&w_s[k][48 + fr][c32 * 32 + kg];
                acc[0][0] = __builtin_amdgcn_mfma_f32_16x16x32_bf16(a0, b0, acc[0][0], 0, 0, 0);
                acc[0][1] = __builtin_amdgcn_mfma_f32_16x16x32_bf16(a0, b1, acc[0][1], 0, 0, 0);
                acc[0][2] = __builtin_amdgcn_mfma_f32_16x16x32_bf16(a0, b2, acc[0][2], 0, 0, 0);
                acc[0][3] = __builtin_amdgcn_mfma_f32_16x16x32_bf16(a0, b3, acc[0][3], 0, 0, 0);
                acc[1][0] = __builtin_amdgcn_mfma_f32_16x16x32_bf16(a1, b0, acc[1][0], 0, 0, 0);
                acc[1][1] = __builtin_amdgcn_mfma_f32_16x16x32_bf16(a1, b1, acc[1][1], 0, 0, 0);
                acc[1][2] = __builtin_amdgcn_mfma_f32_16x16x32_bf16(a1, b2, acc[1][2], 0, 0, 0);
                acc[1][3] = __builtin_amdgcn_mfma_f32_16x16x32_bf16(a1, b3, acc[1][3], 0, 0, 0);
            }
        }
    }
    const int orow = (lane >> 4) * 4, ocol = lane & 15;
    #pragma unroll
    for (int i = 0; i < 2; ++i)
        #pragma unroll
        for (int j = 0; j < 4; ++j) {
            const int co = j * 16 + ocol;
            const float bv = bias[co];
            #pragma unroll
            for (int r = 0; r < 4; ++r) {
                int t = t0 + w * 32 + i * 16 + orow + r;
                if (t < TLEN)
                    out[((size_t)(b * TLEN + t)) * 64 + co] = f2bf(gelu_f(acc[i][j][r] + bv));
            }
        }
}

// ---------- bf16 MFMA GEMM, 128x128 tile ----------
template <int ACT, int RES, int OUTBF>
__global__ __launch_bounds__(256) void bgemm_k(const unsigned short* __restrict__ A,
                                               const unsigned short* __restrict__ W,
                                               const float* __restrict__ bias,
                                               const float* __restrict__ res,
                                               void* __restrict__ Cv,
                                               int M, int N, int K) {
    __shared__ __align__(16) unsigned short As[128][40];
    __shared__ __align__(16) unsigned short Bs[128][40];
    const int tid = threadIdx.x;
    const int gm0 = blockIdx.y * 128, gn0 = blockIdx.x * 128;
    const int w = tid >> 6, lane = tid & 63;
    const int wr0 = (w >> 1) * 64, wc0 = (w & 1) * 64;
    const int srow = tid >> 1, sc = (tid & 1) * 16;
    const unsigned short* ga = A + (size_t)(gm0 + srow) * K + sc;
    const unsigned short* gb = W + (size_t)(gn0 + srow) * K + sc;
    short8b ra0 = *(const short8b*)(ga), ra1 = *(const short8b*)(ga + 8);
    short8b rb0 = *(const short8b*)(gb), rb1 = *(const short8b*)(gb + 8);
    f32x4 acc[4][4];
    #pragma unroll
    for (int i = 0; i < 4; ++i)
        #pragma unroll
        for (int j = 0; j < 4; ++j) acc[i][j] = (f32x4){0.f, 0.f, 0.f, 0.f};
    const int fr = lane & 15, kg = (lane >> 4) * 8;
    const int nstep = K >> 5;
    for (int s = 0; s < nstep; ++s) {
        __syncthreads();
        *(short8b*)&As[srow][sc] = ra0; *(short8b*)&As[srow][sc + 8] = ra1;
        *(short8b*)&Bs[srow][sc] = rb0; *(short8b*)&Bs[srow][sc + 8] = rb1;
        __syncthreads();
        if (s + 1 < nstep) {
            ga += 32; gb += 32;
            ra0 = *(const short8b*)(ga); ra1 = *(const short8b*)(ga + 8);
            rb0 = *(const short8b*)(gb); rb1 = *(const short8b*)(gb + 8);
        }
        short8b af[4], bf[4];
        #pragma unroll
        for (int i = 0; i < 4; ++i) {
            af[i] = *(const short8b*)&As[wr0 + i * 16 + fr][kg];
            bf[i] = *(const short8b*)&Bs[wc0 + i * 16 + fr][kg];
        }
        #pragma unroll
        for (int i = 0; i < 4; ++i)
            #pragma unroll
            for (int j = 0; j < 4; ++j)
                acc[i][j] = __builtin_amdgcn_mfma_f32_16x16x32_bf16(af[i], bf[j], acc[i][j], 0, 0, 0);
    }
    const int orow = (lane >> 4) * 4, ocol = lane & 15;
    #pragma unroll
    for (int i = 0; i < 4; ++i) {
        #pragma unroll
        for (int j = 0; j < 4; ++j) {
            const int colg = gn0 + wc0 + j * 16 + ocol;
            const float bsv = bias[colg];
            #pragma unroll
            for (int r = 0; r < 4; ++r) {
                const int rowg = gm0 + wr0 + i * 16 + orow + r;
                float v = acc[i][j][r] + bsv;
                if (ACT) v = gelu_f(v);
                if (RES) v += res[(size_t)rowg * N + colg];
                if (OUTBF) ((unsigned short*)Cv)[(size_t)rowg * N + colg] = f2bf(v);
                else ((float*)Cv)[(size_t)rowg * N + colg] = v;
            }
        }
    }
}

// ---------- bf16 MFMA GEMM, 64x128 tile (for N=256 parallelism-starved GEMMs) ----------
template <int ACT, int RES, int OUTBF>
__global__ __launch_bounds__(256) void bgemm64_k(const unsigned short* __restrict__ A,
                                                 const unsigned short* __restrict__ W,
                                                 const float* __restrict__ bias,
                                                 const float* __restrict__ res,
                                                 void* __restrict__ Cv,
                                                 int M, int N, int K) {
    __shared__ __align__(16) unsigned short As[64][40];
    __shared__ __align__(16) unsigned short Bs[128][40];
    const int tid = threadIdx.x;
    const int gm0 = blockIdx.y * 64, gn0 = blockIdx.x * 128;
    const int w = tid >> 6, lane = tid & 63;
    const int wc0 = w * 32;
    const int arow = tid >> 2, ac = (tid & 3) * 8;
    const int brow = tid >> 1, bc = (tid & 1) * 16;
    const unsigned short* ga = A + (size_t)(gm0 + arow) * K + ac;
    const unsigned short* gb = W + (size_t)(gn0 + brow) * K + bc;
    short8b ra0 = *(const short8b*)(ga);
    short8b rb0 = *(const short8b*)(gb), rb1 = *(const short8b*)(gb + 8);
    f32x4 acc[4][2];
    #pragma unroll
    for (int i = 0; i < 4; ++i)
        #pragma unroll
        for (int j = 0; j < 2; ++j) acc[i][j] = (f32x4){0.f, 0.f, 0.f, 0.f};
    const int fr = lane & 15, kg = (lane >> 4) * 8;
    const int nstep = K >> 5;
    for (int s = 0; s < nstep; ++s) {
        __syncthreads();
        *(short8b*)&As[arow][ac] = ra0;
        *(short8b*)&Bs[brow][bc] = rb0; *(short8b*)&Bs[brow][bc + 8] = rb1;
        __syncthreads();
        if (s + 1 < nstep) {
            ga += 32; gb += 32;
            ra0 = *(const short8b*)(ga);
            rb0 = *(const short8b*)(gb); rb1 = *(const short8b*)(gb + 8);
        }
        short8b af[4], bf[2];
        #pragma unroll
        for (int i = 0; i < 4; ++i) af[i] = *(const short8b*)&As[i * 16 + fr][kg];
        #pragma unroll
        for (int j = 0; j < 2; ++j) bf[j] = *(const short8b*)&Bs[wc0 + j * 16 + fr][kg];
        #pragma unroll
        for (int i = 0; i < 4; ++i)
            #pragma unroll
            for (int j = 0; j < 2; ++j)
                acc[i][j] = __builtin_amdgcn_mfma_f32_16x16x32_bf16(af[i], bf[j], acc[i][j], 0, 0, 0);
    }
    const int orow = (lane >> 4) * 4, ocol = lane & 15;
    #pragma unroll
    for (int i = 0; i < 4; ++i) {
        #pragma unroll
        for (int j = 0; j < 2; ++j) {
            const int colg = gn0 + wc0 + j * 16 + ocol;
            const float bsv = bias[colg];
            #pragma unroll
            for (int r = 0; r < 4; ++r) {
                const int rowg = gm0 + i * 16 + orow + r;
                float v = acc[i][j][r] + bsv;
                if (ACT) v = gelu_f(v);
                if (RES) v += res[(size_t)rowg * N + colg];
                if (OUTBF) ((unsigned short*)Cv)[(size_t)rowg * N + colg] = f2bf(v);
                else ((float*)Cv)[(size_t)rowg * N + colg] = v;
            }
        }
    }
}

// ---------- LayerNorm over 128 with 6-way split-K partial sum + bias ----------
__global__ __launch_bounds__(128) void ln128s_k(const float* __restrict__ part,
                                                const float* __restrict__ bias,
                                                const float* __restrict__ g,
                                                const float* __restrict__ bb,
                                                float* __restrict__ out,
                                                int M) {
    int row = blockIdx.x, tid = threadIdx.x;
    __shared__ float sm[2];
    size_t stride = (size_t)M * DP;
    size_t base = (size_t)row * DP + tid;
    float v = bias[tid];
    #pragma unroll
    for (int s2 = 0; s2 < 6; ++s2) v += part[base + (size_t)s2 * stride];
    float mean = block_sum_128(v, sm) * (1.0f / DP);
    float d = v - mean;
    float var = block_sum_128(d * d, sm) * (1.0f / DP);
    out[(size_t)row * DP + tid] = d * rsqrtf(var + 1e-5f) * g[tid] + bb[tid];
}

__global__ void vqreduce_k(const float* __restrict__ vqs, float* __restrict__ out) {
    float s = 0;
    for (int i = threadIdx.x; i < BATCH * SS; i += 256) s += vqs[i];
    __shared__ float sm[4];
    s = block_sum_256(s, sm);
    if (threadIdx.x == 0) out[0] = s * (1.25f / (float)(BATCH * SS * DP));
}

// ---------- wave-per-row LayerNorm over 256 (shfl-only) ----------
template <int OUTBF>
__global__ __launch_bounds__(256) void lnw_k(const float* __restrict__ in,
                                             const float* __restrict__ g,
                                             const float* __restrict__ bb,
                                             void* __restrict__ out) {
    const int row = blockIdx.x * 4 + (threadIdx.x >> 6);
    const int lane = threadIdx.x & 63;
    float4 v = *(const float4*)&in[(size_t)row * DM + lane * 4];
    float s = v.x + v.y + v.z + v.w;
    #pragma unroll
    for (int o = 1; o < 64; o <<= 1) s += __shfl_xor(s, o);
    float mean = s * (1.0f / DM);
    float dx = v.x - mean, dy = v.y - mean, dz = v.z - mean, dw = v.w - mean;
    float vv = dx * dx + dy * dy + dz * dz + dw * dw;
    #pragma unroll
    for (int o = 1; o < 64; o <<= 1) vv += __shfl_xor(vv, o);
    float rstd = rsqrtf(vv * (1.0f / DM) + 1e-5f);
    float4 gv = *(const float4*)&g[lane * 4];
    float4 bv = *(const float4*)&bb[lane * 4];
    float o0 = dx * rstd * gv.x + bv.x;
    float o1 = dy * rstd * gv.y + bv.y;
    float o2 = dz * rstd * gv.z + bv.z;
    float o3 = dw * rstd * gv.w + bv.w;
    if (OUTBF) {
        unsigned long long pk = (unsigned long long)f2bf(o0)
                              | ((unsigned long long)f2bf(o1) << 16)
                              | ((unsigned long long)f2bf(o2) << 32)
                              | ((unsigned long long)f2bf(o3) << 48);
        *(unsigned long long*)((unsigned short*)out + (size_t)row * DM + lane * 4) = pk;
    } else {
        float4 o4; o4.x = o0; o4.y = o1; o4.z = o2; o4.w = o3;
        *(float4*)((float*)out + (size_t)row * DM + lane * 4) = o4;
    }
}

// ---------- fused double LayerNorm: hb = LN(tx;g1,b1), xnb = LN(hb;g2,b2) bf16 ----------
__global__ __launch_bounds__(256) void lnw2_k(const float* __restrict__ in,
                                              const float* __restrict__ g1,
                                              const float* __restrict__ b1,
                                              const float* __restrict__ g2,
                                              const float* __restrict__ b2,
                                              float* __restrict__ hbout,
                                              unsigned short* __restrict__ xout) {
    const int row = blockIdx.x * 4 + (threadIdx.x >> 6);
    const int lane = threadIdx.x & 63;
    float4 v = *(const float4*)&in[(size_t)row * DM + lane * 4];
    float s = v.x + v.y + v.z + v.w;
    #pragma unroll
    for (int o = 1; o < 64; o <<= 1) s += __shfl_xor(s, o);
    float mean = s * (1.0f / DM);
    float dx = v.x - mean, dy = v.y - mean, dz = v.z - mean, dw = v.w - mean;
    float vv = dx * dx + dy * dy + dz * dz + dw * dw;
    #pragma unroll
    for (int o = 1; o < 64; o <<= 1) vv += __shfl_xor(vv, o);
    float rstd = rsqrtf(vv * (1.0f / DM) + 1e-5f);
    float4 g1v = *(const float4*)&g1[lane * 4];
    float4 b1v = *(const float4*)&b1[lane * 4];
    float h0 = dx * rstd * g1v.x + b1v.x;
    float h1 = dy * rstd * g1v.y + b1v.y;
    float h2 = dz * rstd * g1v.z + b1v.z;
    float h3 = dw * rstd * g1v.w + b1v.w;
    float4 h4; h4.x = h0; h4.y = h1; h4.z = h2; h4.w = h3;
    *(float4*)&hbout[(size_t)row * DM + lane * 4] = h4;
    // second LN on h
    float s2 = h0 + h1 + h2 + h3;
    #pragma unroll
    for (int o = 1; o < 64; o <<= 1) s2 += __shfl_xor(s2, o);
    float mean2 = s2 * (1.0f / DM);
    float ex = h0 - mean2, ey = h1 - mean2, ez = h2 - mean2, ew = h3 - mean2;
    float vv2 = ex * ex + ey * ey + ez * ez + ew * ew;
    #pragma unroll
    for (int o = 1; o < 64; o <<= 1) vv2 += __shfl_xor(vv2, o);
    float rstd2 = rsqrtf(vv2 * (1.0f / DM) + 1e-5f);
    float4 g2v = *(const float4*)&g2[lane * 4];
    float4 b2v = *(const float4*)&b2[lane * 4];
    unsigned long long pk = (unsigned long long)f2bf(ex * rstd2 * g2v.x + b2v.x)
                          | ((unsigned long long)f2bf(ey * rstd2 * g2v.y + b2v.y) << 16)
                          | ((unsigned long long)f2bf(ez * rstd2 * g2v.z + b2v.z) << 32)
                          | ((unsigned long long)f2bf(ew * rstd2 * g2v.w + b2v.w) << 48);
    *(unsigned long long*)&xout[(size_t)row * DM + lane * 4] = pk;
}

// ---------- fused flash MFMA attention, 64-q blocks (proven variant) ----------
__global__ __launch_bounds__(256) void fattn_k(const unsigned short* __restrict__ qkv,
                                               const float* __restrict__ slopes,
                                               unsigned short* __restrict__ out) {
    __shared__ __align__(16) unsigned short Qs[64][40];
    __shared__ __align__(16) unsigned short Ks[64][40];
    __shared__ __align__(16) unsigned short Vt[32][72];
    __shared__ __align__(16) unsigned short Ps[4][16][72];
    const int qb = blockIdx.x, hh = blockIdx.y, b = blockIdx.z;
    const int tid = threadIdx.x;
    const int w = tid >> 6, lane = tid & 63;
    const int lr = lane & 15, lg = lane >> 4;
    const float slope = fabsf(slopes[hh]);
    const unsigned short* base = qkv + (size_t)b * SS * (3 * DM);
    {
        int row = tid >> 2, c = (tid & 3) * 8;
        int q = qb * 64 + row; q = q < SS ? q : SS - 1;
        *(short8b*)&Qs[row][c] = *(const short8b*)(base + (size_t)q * (3 * DM) + hh * HD + c);
    }
    __syncthreads();
    const short8b qa = *(const short8b*)&Qs[w * 16 + lr][lg * 8];
    float m_run[4] = {-1e30f, -1e30f, -1e30f, -1e30f};
    float l_run[4] = {0.f, 0.f, 0.f, 0.f};
    f32x4 of0 = (f32x4){0.f, 0.f, 0.f, 0.f}, of1 = (f32x4){0.f, 0.f, 0.f, 0.f};
    const int qg0 = qb * 64 + w * 16 + lg * 4;
    for (int kt = 0; kt < SS; kt += 64) {
        const int tl = (SS - kt) < 64 ? (SS - kt) : 64;
        const int nks = tl >> 4;
        __syncthreads();
        {
            int row = tid >> 2, c = (tid & 3) * 8;
            if (row < tl) {
                *(short8b*)&Ks[row][c] =
                    *(const short8b*)(base + (size_t)(kt + row) * (3 * DM) + DM + hh * HD + c);
                short8b v8 = *(const short8b*)(base + (size_t)(kt + row) * (3 * DM) + 2 * DM + hh * HD + c);
                #pragma unroll
                for (int j = 0; j < 8; ++j) Vt[c + j][row] = ((unsigned short*)&v8)[j];
            }
        }
        __syncthreads();
        f32x4 sf[4];
        #pragma unroll
        for (int ks = 0; ks < 4; ++ks) {
            if (ks < nks) {
                short8b kb = *(const short8b*)&Ks[ks * 16 + lr][lg * 8];
                sf[ks] = __builtin_amdgcn_mfma_f32_16x16x32_bf16(qa, kb, (f32x4){0.f, 0.f, 0.f, 0.f}, 0, 0, 0);
            }
        }
        float pv[4][4];
        #pragma unroll
        for (int r = 0; r < 4; ++r) {
            float tmax = -1e30f;
            #pragma unroll
            for (int ks = 0; ks < 4; ++ks) {
                if (ks < nks) {
                    float sv = sf[ks][r] * 0.17677669529663687f
                             - slope * fabsf((float)(qg0 + r - (kt + ks * 16 + lr)));
                    pv[ks][r] = sv;
                    tmax = fmaxf(tmax, sv);
                }
            }
            #pragma unroll
            for (int o = 1; o < 16; o <<= 1) tmax = fmaxf(tmax, __shfl_xor(tmax, o));
            float mnew = fmaxf(m_run[r], tmax);
            float sc = __expf(m_run[r] - mnew);
            m_run[r] = mnew;
            float tsum = 0.f;
            #pragma unroll
            for (int ks = 0; ks < 4; ++ks) {
                if (ks < nks) {
                    float e = __expf(pv[ks][r] - mnew);
                    pv[ks][r] = e;
                    tsum += e;
                }
            }
            #pragma unroll
            for (int o = 1; o < 16; o <<= 1) tsum += __shfl_xor(tsum, o);
            l_run[r] = l_run[r] * sc + tsum;
            of0[r] *= sc; of1[r] *= sc;
        }
        #pragma unroll
        for (int ks = 0; ks < 4; ++ks)
            #pragma unroll
            for (int r = 0; r < 4; ++r)
                Ps[w][lg * 4 + r][ks * 16 + lr] = (ks < nks) ? f2bf(pv[ks][r]) : (unsigned short)0;
        #pragma unroll
        for (int kc = 0; kc < 64; kc += 32) {
            if (kc < nks * 16) {
                short8b pa = *(const short8b*)&Ps[w][lr][kc + lg * 8];
                short8b vb0 = *(const short8b*)&Vt[lr][kc + lg * 8];
                short8b vb1 = *(const short8b*)&Vt[16 + lr][kc + lg * 8];
                of0 = __builtin_amdgcn_mfma_f32_16x16x32_bf16(pa, vb0, of0, 0, 0, 0);
                of1 = __builtin_amdgcn_mfma_f32_16x16x32_bf16(pa, vb1, of1, 0, 0, 0);
            }
        }
    }
    #pragma unroll
    for (int r = 0; r < 4; ++r) {
        int q = qg0 + r;
        if (q < SS) {
            float inv = 1.0f / l_run[r];
            out[((size_t)(b * SS + q)) * DM + hh * HD + lr] = f2bf(of0[r] * inv);
            out[((size_t)(b * SS + q)) * DM + hh * HD + 16 + lr] = f2bf(of1[r] * inv);
        }
    }
}

// ---------- final: d2 conv + r4 1x1 conv + alpha blend; inputs bf16 TM ----------
__global__ __launch_bounds__(256) void final2_k(const unsigned short* __restrict__ ud1,
                                                const unsigned short* __restrict__ r3i,
                                                const float* __restrict__ d2w,
                                                const float* __restrict__ d2b,
                                                const float* __restrict__ r4w,
                                                const float* __restrict__ r4b,
                                                const float* __restrict__ alpha,
                                                float* __restrict__ out) {
    __shared__ float u_s[64][66];
    __shared__ float r_s[64][64];
    __shared__ float wd_s[64][3][12];
    __shared__ float wr_s[64][12];
    __shared__ float o_s[64][12];
    const int b = blockIdx.z, t0 = blockIdx.x * 64, tid = threadIdx.x;
    for (int u2 = tid; u2 < 66 * 8; u2 += 256) {
        int j = u2 >> 3, q = u2 & 7;
        int t = t0 + j - 1;
        short8b v = (short8b){0, 0, 0, 0, 0, 0, 0, 0};
        if (t >= 0 && t < TLEN) v = *(const short8b*)&ud1[((size_t)(b * TLEN + t)) * 64 + q * 8];
        #pragma unroll
        for (int i = 0; i < 8; ++i) u_s[q * 8 + i][j] = bf2f((unsigned short)v[i]);
    }
    for (int u2 = tid; u2 < 64 * 8; u2 += 256) {
        int j = u2 >> 3, q = u2 & 7;
        int t = t0 + j;
        short8b v = (short8b){0, 0, 0, 0, 0, 0, 0, 0};
        if (t < TLEN) v = *(const short8b*)&r3i[((size_t)(b * TLEN + t)) * 64 + q * 8];
        #pragma unroll
        for (int i = 0; i < 8; ++i) r_s[q * 8 + i][j] = bf2f((unsigned short)v[i]);
    }
    for (int idx = tid; idx < 64 * 3 * 12; idx += 256) {
        int l = idx % 12, k = (idx / 12) % 3, ci = idx / 36;
        wd_s[ci][k][l] = d2w[(l * 64 + ci) * 3 + k];
    }
    for (int idx = tid; idx < 64 * 12; idx += 256) {
        int l = idx % 12, ci = idx / 12;
        wr_s[ci][l] = r4w[l * 64 + ci];
    }
    __syncthreads();
    const int tl = tid & 63, lg = tid >> 6;
    float accD[3] = {}, accR[3] = {};
    for (int ci = 0; ci < 64; ++ci) {
        float a0 = u_s[ci][tl], a1 = u_s[ci][tl + 1], a2 = u_s[ci][tl + 2];
        float rv = r_s[ci][tl];
        #pragma unroll
        for (int c = 0; c < 3; ++c) {
            int l = lg * 3 + c;
            accD[c] += a0 * wd_s[ci][0][l] + a1 * wd_s[ci][1][l] + a2 * wd_s[ci][2][l];
            accR[c] = fmaf(rv, wr_s[ci][l], accR[c]);
        }
    }
    float al = alpha[0];
    #pragma unroll
    for (int c = 0; c < 3; ++c) {
        int l = lg * 3 + c;
        o_s[tl][l] = accD[c] + d2b[l] + al * (accR[c] + r4b[l]);
    }
    __syncthreads();
    for (int idx = tid; idx < 64 * 12; idx += 256) {
        int t = t0 + idx / 12;
        if (t < TLEN) out[((size_t)b * TLEN + t) * 12 + idx % 12] = o_s[idx / 12][idx % 12];
    }
}

extern "C" void kernel_launch(void* const* d_in, const int* in_sizes, int n_in,
                              void* d_out, int out_size, void* d_ws, size_t ws_size,
                              hipStream_t stream) {
    const float* x     = (const float*)d_in[0];
    const float* pe_w1 = (const float*)d_in[1];
    const float* pe_b1 = (const float*)d_in[2];
    const float* pe_w2 = (const float*)d_in[3];
    const float* pe_b2 = (const float*)d_in[4];
    const float* pe_pw = (const float*)d_in[5];
    const float* pe_pb = (const float*)d_in[6];
    const float* pe_g  = (const float*)d_in[7];
    const float* pe_bb = (const float*)d_in[8];
    const float* cb    = (const float*)d_in[9];
    const float* tp_w  = (const float*)d_in[10];
    const float* tp_b  = (const float*)d_in[11];
    const float* tp_g  = (const float*)d_in[12];
    const float* tp_bb = (const float*)d_in[13];
    const float* ln1_g = (const float*)d_in[14];
    const float* ln1_b = (const float*)d_in[15];
    const float* inw   = (const float*)d_in[16];
    const float* inb   = (const float*)d_in[17];
    const float* ow    = (const float*)d_in[18];
    const float* ob    = (const float*)d_in[19];
    const float* ln2_g = (const float*)d_in[20];
    const float* ln2_b = (const float*)d_in[21];
    const float* f1w   = (const float*)d_in[22];
    const float* f1b   = (const float*)d_in[23];
    const float* f2w   = (const float*)d_in[24];
    const float* f2b   = (const float*)d_in[25];
    const float* slopes= (const float*)d_in[26];
    const float* fn_g  = (const float*)d_in[27];
    const float* fn_b  = (const float*)d_in[28];
    const float* up_w  = (const float*)d_in[29];
    const float* up_b  = (const float*)d_in[30];
    const float* d1w   = (const float*)d_in[31];
    const float* d1b   = (const float*)d_in[32];
    const float* d2w   = (const float*)d_in[33];
    const float* d2b   = (const float*)d_in[34];
    const float* r1w   = (const float*)d_in[35];
    const float* r1b   = (const float*)d_in[36];
    const float* r2w   = (const float*)d_in[37];
    const float* r2b   = (const float*)d_in[38];
    const float* r3w   = (const float*)d_in[39];
    const float* r3b   = (const float*)d_in[40];
    const float* r4w   = (const float*)d_in[41];
    const float* r4b   = (const float*)d_in[42];
    const float* alpha = (const float*)d_in[43];

    float* W = (float*)d_ws;
    size_t off = 0;
    auto alloc = [&](size_t n) { float* p = W + off; off += (n + 3) & ~(size_t)3; return p; };
    const size_t M = (size_t)BATCH * SS;  // 6400
    float* A    = alloc((size_t)BATCH * DP * TLEN);
    float* Bb   = alloc((size_t)BATCH * 64 * TLEN);
    float* ze   = alloc(M * DP);
    float* tx   = alloc(M * DM);
    float* hb   = alloc(M * DM);
    float* qf   = alloc(M * 3 * DM);
    float* cbn  = alloc(VV);
    float* vqs  = alloc(M);
    float* upb2 = alloc(1152);
    float* pval = alloc(4 * M);
    int*   pidx = (int*)alloc(4 * M);
    unsigned short* zqb  = (unsigned short*)alloc(M * DP / 2);
    unsigned short* xnb  = (unsigned short*)alloc(M * DM / 2);
    unsigned short* aob  = (unsigned short*)alloc(M * DM / 2);
    float* pgpart        = qf;
    unsigned short* qkvb = (unsigned short*)qf;
    unsigned short* ffb  = (unsigned short*)qf;
    unsigned short* utm  = (unsigned short*)qf;
    unsigned short* inwb = (unsigned short*)alloc((size_t)NLAY * 3 * DM * DM / 2);
    unsigned short* owb  = (unsigned short*)alloc((size_t)NLAY * DM * DM / 2);
    unsigned short* f1wb = (unsigned short*)alloc((size_t)NLAY * 4 * DM * DM / 2);
    unsigned short* f2wb = (unsigned short*)alloc((size_t)NLAY * 4 * DM * DM / 2);
    unsigned short* tpwb = (unsigned short*)alloc((size_t)DM * DP / 2);
    unsigned short* upwb = (unsigned short*)alloc((size_t)1152 * DM / 2);
    unsigned short* pwh  = (unsigned short*)alloc((size_t)128 * 1152 / 2);
    unsigned short* pwl  = (unsigned short*)alloc((size_t)128 * 1152 / 2);
    unsigned short* w2h  = (unsigned short*)alloc((size_t)3 * 128 * 64 / 2);
    unsigned short* w2l  = (unsigned short*)alloc((size_t)3 * 128 * 64 / 2);
    unsigned short* cbh  = (unsigned short*)alloc((size_t)VV * DP / 2);
    unsigned short* cbl  = (unsigned short*)alloc((size_t)VV * DP / 2);
    unsigned short* r2pk = (unsigned short*)alloc((size_t)64 * 64 * 5 / 2);
    unsigned short* r3pk = (unsigned short*)alloc((size_t)64 * 64 * 3 / 2 + 2);
    unsigned short* d1pk = (unsigned short*)alloc((size_t)64 * 128 * 5 / 2);
    unsigned short* r1tm = (unsigned short*)alloc((size_t)BATCH * TLEN * 64 / 2);
    unsigned short* r2tm = (unsigned short*)alloc((size_t)BATCH * TLEN * 64 / 2);
    unsigned short* r3tm = (unsigned short*)alloc((size_t)BATCH * TLEN * 64 / 2);
    unsigned short* d1tm = (unsigned short*)alloc((size_t)BATCH * TLEN * 64 / 2);
    if (off * sizeof(float) > ws_size) return;

    float* outp = (float*)d_out;
    const dim3 cgrid(57, 1, BATCH);
    const dim3 mgrid(29, 1, BATCH);

    // --- ALL weight conversions / packs in ONE launch ---
    packall_k<<<(5358080 + 255) / 256, 256, 0, stream>>>(
        inw, inwb, ow, owb, f1w, f1wb, f2w, f2wb, tp_w, tpwb,
        up_w, up_b, upwb, upb2, pe_pw, pwh, pwl, pe_w2, w2h, w2l,
        cb, cbh, cbl, cbn, r2w, r2pk, r3w, r3pk, d1w, d1pk);

    // --- fused pe1 + r1 ---
    enc1_k<<<dim3(57, BATCH), 256, 0, stream>>>(x, pe_w1, pe_b1, r1w, r1b, Bb, r1tm);

    // --- encoder tail ---
    pe2m_k<<<dim3(29, BATCH), 256, 0, stream>>>(Bb, w2h, w2l, pe_b2, A);
    pproj3_k<<<dim3(1, M / 128, 6), 256, 0, stream>>>(A, pwh, pwl, pgpart, M);
    ln128s_k<<<M, 128, 0, stream>>>(pgpart, pe_pb, pe_g, pe_bb, ze, M);
    vq3_k<<<dim3(4, M / 128), 256, 0, stream>>>(ze, cbh, cbl, cbn, pval, pidx, M);
    vqfin_k<<<M, 128, 0, stream>>>(ze, cb, pval, pidx, zqb, vqs, M);
    vqreduce_k<<<1, 256, 0, stream>>>(vqs, outp + (size_t)BATCH * TLEN * LEADS);

    // --- residual CNN ---
    mfconv_k<64, 5, 2><<<mgrid, 256, 0, stream>>>(r1tm, r2pk, r2b, r2tm);
    mfconv_k<64, 3, 1><<<mgrid, 256, 0, stream>>>(r2tm, r3pk, r3b, r3tm);

    // --- token projection + fused double-LN (tp-LN then ln1 of layer 0) ---
    bgemm64_k<0, 0, 0><<<dim3(DM / 128, M / 64), 256, 0, stream>>>(zqb, tpwb, tp_b, nullptr, tx, M, DM, DP);
    lnw2_k<<<M / 4, 256, 0, stream>>>(tx, tp_g, tp_bb, ln1_g, ln1_b, hb, xnb);

    // --- transformer ---
    for (int l = 0; l < NLAY; ++l) {
        if (l) lnw_k<1><<<M / 4, 256, 0, stream>>>(hb, ln1_g + l * DM, ln1_b + l * DM, xnb);
        bgemm_k<0, 0, 1><<<dim3(3 * DM / 128, M / 128), 256, 0, stream>>>(
            xnb, inwb + (size_t)l * 3 * DM * DM, inb + l * 3 * DM, nullptr, qkvb, M, 3 * DM, DM);
        fattn_k<<<dim3((SS + 63) / 64, NH, BATCH), 256, 0, stream>>>(qkvb, slopes + l * NH, aob);
        bgemm64_k<0, 1, 0><<<dim3(DM / 128, M / 64), 256, 0, stream>>>(
            aob, owb + (size_t)l * DM * DM, ob + l * DM, hb, hb, M, DM, DM);
        lnw_k<1><<<M / 4, 256, 0, stream>>>(hb, ln2_g + l * DM, ln2_b + l * DM, xnb);
        bgemm_k<1, 0, 1><<<dim3(4 * DM / 128, M / 128), 256, 0, stream>>>(
            xnb, f1wb + (size_t)l * 4 * DM * DM, f1b + l * 4 * DM, nullptr, ffb, M, 4 * DM, DM);
        bgemm64_k<0, 1, 0><<<dim3(DM / 128, M / 64), 256, 0, stream>>>(
            ffb, f2wb + (size_t)l * 4 * DM * DM, f2b + l * DM, hb, hb, M, DM, 4 * DM);
    }
    lnw_k<1><<<M / 4, 256, 0, stream>>>(hb, fn_g, fn_b, xnb);

    // --- decoder ---
    bgemm_k<1, 0, 1><<<dim3(1152 / 128, M / 128), 256, 0, stream>>>(xnb, upwb, upb2, nullptr, utm, M, 1152, DM);
    mfconv_k<128, 5, 2><<<mgrid, 256, 0, stream>>>(utm, d1pk, d1b, d1tm);

    // --- fused d2 conv + r4 conv + alpha blend ---
    final2_k<<<cgrid, 256, 0, stream>>>(d1tm, r3tm, d2w, d2b, r4w, r4b, alpha, outp);
}

// Round 14
// 709.560 us; speedup vs baseline: 1.1533x; 1.0138x over previous
//
#include <hip/hip_runtime.h>
#include <hip/hip_bf16.h>
#include <math.h>

#define BATCH 16
#define TLEN 3600
#define LEADS 12
#define PP 9
#define SS 400
#define DP 128
#define DM 256
#define NH 8
#define HD 32
#define NLAY 6
#define VV 512
#define RH 64

typedef __attribute__((ext_vector_type(8))) short short8b;
typedef __attribute__((ext_vector_type(4))) float f32x4;

__device__ __forceinline__ float gelu_f(float x) {
    return 0.5f * x * (1.0f + erff(x * 0.70710678118654752f));
}

__device__ __forceinline__ unsigned short f2bf(float f) {
    union { float f; unsigned u; } v; v.f = f;
    return (unsigned short)((v.u + 0x7FFFu + ((v.u >> 16) & 1u)) >> 16);
}

__device__ __forceinline__ float bf2f(unsigned short h) {
    union { unsigned u; float f; } v; v.u = ((unsigned)h) << 16; return v.f;
}

// ---------- block reduction helpers ----------
__device__ __forceinline__ float block_sum_256(float v, float* sm) {
    #pragma unroll
    for (int o = 32; o > 0; o >>= 1) v += __shfl_down(v, o);
    __syncthreads();
    if ((threadIdx.x & 63) == 0) sm[threadIdx.x >> 6] = v;
    __syncthreads();
    return sm[0] + sm[1] + sm[2] + sm[3];
}

__device__ __forceinline__ float block_sum_128(float v, float* sm) {
    #pragma unroll
    for (int o = 32; o > 0; o >>= 1) v += __shfl_down(v, o);
    __syncthreads();
    if ((threadIdx.x & 63) == 0) sm[threadIdx.x >> 6] = v;
    __syncthreads();
    return sm[0] + sm[1];
}

// ---------- ALL weight packs + codebook prep in ONE kernel ----------
__global__ void packall_k(const float* __restrict__ inw, unsigned short* __restrict__ inwb,
                          const float* __restrict__ ow,  unsigned short* __restrict__ owb,
                          const float* __restrict__ f1w, unsigned short* __restrict__ f1wb,
                          const float* __restrict__ f2w, unsigned short* __restrict__ f2wb,
                          const float* __restrict__ tpw, unsigned short* __restrict__ tpwb,
                          const float* __restrict__ upw, const float* __restrict__ upb,
                          unsigned short* __restrict__ upwb, float* __restrict__ upb2,
                          const float* __restrict__ ppw, unsigned short* __restrict__ pwh,
                          unsigned short* __restrict__ pwl,
                          const float* __restrict__ w2, unsigned short* __restrict__ w2h,
                          unsigned short* __restrict__ w2l,
                          const float* __restrict__ cb, unsigned short* __restrict__ cbh,
                          unsigned short* __restrict__ cbl, float* __restrict__ cbn,
                          const float* __restrict__ r2w, unsigned short* __restrict__ r2pk,
                          const float* __restrict__ r3w, unsigned short* __restrict__ r3pk,
                          const float* __restrict__ d1w, unsigned short* __restrict__ d1pk) {
    long idx = (long)blockIdx.x * 256 + threadIdx.x;
    const long S0 = 1179648, S1 = 393216, S2 = 1572864, S3 = 1572864, S4 = 32768,
               S5 = 294912, S6 = 147456, S7 = 24576, S8 = 65536, S8b = 512,
               S9 = 20480, S10 = 12288, S11 = 40960;
    if (idx < S0) { inwb[idx] = f2bf(inw[idx]); return; } idx -= S0;
    if (idx < S1) { owb[idx] = f2bf(ow[idx]); return; } idx -= S1;
    if (idx < S2) { f1wb[idx] = f2bf(f1w[idx]); return; } idx -= S2;
    if (idx < S3) { f2wb[idx] = f2bf(f2w[idx]); return; } idx -= S3;
    if (idx < S4) { tpwb[idx] = f2bf(tpw[idx]); return; } idx -= S4;
    if (idx < S5) {                               // upwt2: W'[n][d], n=k*128+o
        int d = (int)(idx & 255), n = (int)(idx >> 8);
        int o = n & 127, k = n >> 7;
        upwb[(size_t)n * 256 + d] = f2bf(upw[(size_t)d * 1152 + o * 9 + k]);
        if (idx < 1152) upb2[idx] = upb[idx & 127];
        return;
    } idx -= S5;
    if (idx < S6) {                               // pwpack3: hi/lo, kidx=kk*128+co
        int n = (int)(idx % 1152), d = (int)(idx / 1152);
        int co = n & 127, kk = n >> 7;
        float v = ppw[(size_t)d * 1152 + co * 9 + kk];
        unsigned short h = f2bf(v);
        pwh[idx] = h; pwl[idx] = f2bf(v - bf2f(h));
        return;
    } idx -= S6;
    if (idx < S7) {                               // pwpack2
        int ci = (int)(idx & 63); long rest = idx >> 6; int co = (int)(rest & 127); int k = (int)(rest >> 7);
        float v = w2[((size_t)co * 64 + ci) * 3 + k];
        unsigned short h = f2bf(v);
        w2h[idx] = h; w2l[idx] = f2bf(v - bf2f(h));
        return;
    } idx -= S7;
    if (idx < S8) {                               // cbpack
        float v = cb[idx];
        unsigned short h = f2bf(v);
        cbh[idx] = h; cbl[idx] = f2bf(v - bf2f(h));
        return;
    } idx -= S8;
    if (idx < S8b) {                              // cbnorm
        const float* cr = cb + (size_t)idx * DP;
        float s = 0;
        for (int i = 0; i < DP; ++i) s += cr[i] * cr[i];
        cbn[idx] = s;
        return;
    } idx -= S8b;
    if (idx < S9) {                               // r2 cpack (Co=64,CI=64,K=5)
        int ci = (int)(idx % 64); long rest = idx / 64; int co = (int)(rest % 64); int k = (int)(rest / 64);
        r2pk[idx] = f2bf(r2w[((size_t)co * 64 + ci) * 5 + k]);
        return;
    } idx -= S9;
    if (idx < S10) {                              // r3 cpack (Co=64,CI=64,K=3)
        int ci = (int)(idx % 64); long rest = idx / 64; int co = (int)(rest % 64); int k = (int)(rest / 64);
        r3pk[idx] = f2bf(r3w[((size_t)co * 64 + ci) * 3 + k]);
        return;
    } idx -= S10;
    if (idx < S11) {                              // d1 cpack (Co=64,CI=128,K=5)
        int ci = (int)(idx % 128); long rest = idx / 128; int co = (int)(rest % 64); int k = (int)(rest / 64);
        d1pk[idx] = f2bf(d1w[((size_t)co * 128 + ci) * 5 + k]);
        return;
    }
}

// ---------- fused pe1 + r1: both read x (B,T,12) ----------
__global__ __launch_bounds__(256, 4) void enc1_k(const float* __restrict__ x,
                                                 const float* __restrict__ w1,
                                                 const float* __restrict__ b1,
                                                 const float* __restrict__ w7,
                                                 const float* __restrict__ b7,
                                                 float* __restrict__ out1,
                                                 unsigned short* __restrict__ out7) {
    __shared__ __align__(16) float xs[12][80];
    __shared__ float w1s[12][3][64];
    __shared__ float w7s[12][7][64];
    const int b = blockIdx.y, t0 = blockIdx.x * 64, tid = threadIdx.x;
    const int tx = tid & 15, ty = tid >> 4;
    for (int idx = tid; idx < 70 * 12; idx += 256) {
        int j = idx / 12, ci = idx - j * 12;
        int t = t0 + j - 3;
        xs[ci][j] = (t >= 0 && t < TLEN) ? x[((size_t)b * TLEN + t) * 12 + ci] : 0.f;
    }
    for (int idx = tid; idx < 12 * 3 * 64; idx += 256) {
        int co = idx & 63; int rest = idx >> 6; int k = rest % 3; int ci = rest / 3;
        w1s[ci][k][co] = w1[(co * 12 + ci) * 3 + k];
    }
    for (int idx = tid; idx < 12 * 7 * 64; idx += 256) {
        int co = idx & 63; int rest = idx >> 6; int k = rest % 7; int ci = rest / 7;
        w7s[ci][k][co] = w7[(co * 12 + ci) * 7 + k];
    }
    __syncthreads();
    float a1[4][4] = {}, a7[4][4] = {};
    #pragma unroll 2
    for (int ci = 0; ci < 12; ++ci) {
        float tv[12];
        *(float4*)&tv[0] = *(const float4*)&xs[ci][tx * 4];
        *(float4*)&tv[4] = *(const float4*)&xs[ci][tx * 4 + 4];
        *(float4*)&tv[8] = *(const float4*)&xs[ci][tx * 4 + 8];
        #pragma unroll
        for (int k = 0; k < 7; ++k) {
            float4 wv = *(const float4*)&w7s[ci][k][ty * 4];
            #pragma unroll
            for (int j = 0; j < 4; ++j) {
                float iv = tv[j + k];
                a7[0][j] = fmaf(wv.x, iv, a7[0][j]);
                a7[1][j] = fmaf(wv.y, iv, a7[1][j]);
                a7[2][j] = fmaf(wv.z, iv, a7[2][j]);
                a7[3][j] = fmaf(wv.w, iv, a7[3][j]);
            }
        }
        #pragma unroll
        for (int k = 0; k < 3; ++k) {
            float4 wv = *(const float4*)&w1s[ci][k][ty * 4];
            #pragma unroll
            for (int j = 0; j < 4; ++j) {
                float iv = tv[j + k + 2];
                a1[0][j] = fmaf(wv.x, iv, a1[0][j]);
                a1[1][j] = fmaf(wv.y, iv, a1[1][j]);
                a1[2][j] = fmaf(wv.z, iv, a1[2][j]);
                a1[3][j] = fmaf(wv.w, iv, a1[3][j]);
            }
        }
    }
    float4 b1v4 = *(const float4*)&b1[ty * 4];
    #pragma unroll
    for (int j = 0; j < 4; ++j) {
        int t = t0 + tx * 4 + j;
        if (t < TLEN) {
            float4 o4;
            o4.x = gelu_f(a1[0][j] + b1v4.x);
            o4.y = gelu_f(a1[1][j] + b1v4.y);
            o4.z = gelu_f(a1[2][j] + b1v4.z);
            o4.w = gelu_f(a1[3][j] + b1v4.w);
            *(float4*)&out1[((size_t)(b * TLEN + t)) * 64 + ty * 4] = o4;
        }
    }
    float bv0 = b7[ty * 4], bv1 = b7[ty * 4 + 1], bv2 = b7[ty * 4 + 2], bv3 = b7[ty * 4 + 3];
    #pragma unroll
    for (int j = 0; j < 4; ++j) {
        int t = t0 + tx * 4 + j;
        if (t < TLEN) {
            unsigned long long pk =
                  (unsigned long long)f2bf(gelu_f(a7[0][j] + bv0))
                | ((unsigned long long)f2bf(gelu_f(a7[1][j] + bv1)) << 16)
                | ((unsigned long long)f2bf(gelu_f(a7[2][j] + bv2)) << 32)
                | ((unsigned long long)f2bf(gelu_f(a7[3][j] + bv3)) << 48);
            *(unsigned long long*)&out7[((size_t)(b * TLEN + t)) * 64 + ty * 4] = pk;
        }
    }
}

// ---------- pe2 hi/lo MFMA conv ----------
__global__ __launch_bounds__(256) void pe2m_k(const float* __restrict__ in,
                                              const unsigned short* __restrict__ wh,
                                              const unsigned short* __restrict__ wl,
                                              const float* __restrict__ bias,
                                              float* __restrict__ out) {
    __shared__ __align__(16) unsigned short Ah[130][72];
    __shared__ __align__(16) unsigned short Al[130][72];
    __shared__ __align__(16) unsigned short Wh_s[128][72];
    __shared__ __align__(16) unsigned short Wl_s[128][72];
    const int b = blockIdx.y, t0 = blockIdx.x * 128, tid = threadIdx.x;
    const int w = tid >> 6, lane = tid & 63;
    const int fr = lane & 15, kg = (lane >> 4) * 8;
    for (int u = tid; u < 130 * 8; u += 256) {
        int row = u >> 3, q = u & 7;
        int t = t0 + row - 1;
        short8b h8 = (short8b){0, 0, 0, 0, 0, 0, 0, 0};
        short8b l8 = (short8b){0, 0, 0, 0, 0, 0, 0, 0};
        if (t >= 0 && t < TLEN) {
            const float* src = in + ((size_t)(b * TLEN + t)) * 64 + q * 8;
            float4 v0 = *(const float4*)src;
            float4 v1 = *(const float4*)(src + 4);
            float vv[8] = {v0.x, v0.y, v0.z, v0.w, v1.x, v1.y, v1.z, v1.w};
            #pragma unroll
            for (int e = 0; e < 8; ++e) {
                unsigned short h = f2bf(vv[e]);
                h8[e] = (short)h;
                l8[e] = (short)f2bf(vv[e] - bf2f(h));
            }
        }
        *(short8b*)&Ah[row][q * 8] = h8;
        *(short8b*)&Al[row][q * 8] = l8;
    }
    f32x4 acc[2][8];
    #pragma unroll
    for (int i = 0; i < 2; ++i)
        #pragma unroll
        for (int j = 0; j < 8; ++j) acc[i][j] = (f32x4){0.f, 0.f, 0.f, 0.f};
    for (int k = 0; k < 3; ++k) {
        __syncthreads();
        for (int u = tid; u < 128 * 8; u += 256) {
            int co = u >> 3, q = u & 7;
            *(short8b*)&Wh_s[co][q * 8] = *(const short8b*)&wh[((size_t)(k * 128 + co)) * 64 + q * 8];
            *(short8b*)&Wl_s[co][q * 8] = *(const short8b*)&wl[((size_t)(k * 128 + co)) * 64 + q * 8];
        }
        __syncthreads();
        #pragma unroll
        for (int c32 = 0; c32 < 2; ++c32) {
            short8b ah0 = *(const short8b*)&Ah[w * 32 + fr + k][c32 * 32 + kg];
            short8b ah1 = *(const short8b*)&Ah[w * 32 + 16 + fr + k][c32 * 32 + kg];
            short8b al0 = *(const short8b*)&Al[w * 32 + fr + k][c32 * 32 + kg];
            short8b al1 = *(const short8b*)&Al[w * 32 + 16 + fr + k][c32 * 32 + kg];
            #pragma unroll
            for (int j = 0; j < 8; ++j) {
                short8b bh = *(const short8b*)&Wh_s[j * 16 + fr][c32 * 32 + kg];
                short8b bl = *(const short8b*)&Wl_s[j * 16 + fr][c32 * 32 + kg];
                acc[0][j] = __builtin_amdgcn_mfma_f32_16x16x32_bf16(ah0, bh, acc[0][j], 0, 0, 0);
                acc[0][j] = __builtin_amdgcn_mfma_f32_16x16x32_bf16(ah0, bl, acc[0][j], 0, 0, 0);
                acc[0][j] = __builtin_amdgcn_mfma_f32_16x16x32_bf16(al0, bh, acc[0][j], 0, 0, 0);
                acc[1][j] = __builtin_amdgcn_mfma_f32_16x16x32_bf16(ah1, bh, acc[1][j], 0, 0, 0);
                acc[1][j] = __builtin_amdgcn_mfma_f32_16x16x32_bf16(ah1, bl, acc[1][j], 0, 0, 0);
                acc[1][j] = __builtin_amdgcn_mfma_f32_16x16x32_bf16(al1, bh, acc[1][j], 0, 0, 0);
            }
        }
    }
    const int orow = (lane >> 4) * 4, ocol = lane & 15;
    #pragma unroll
    for (int i = 0; i < 2; ++i)
        #pragma unroll
        for (int j = 0; j < 8; ++j) {
            const int co = j * 16 + ocol;
            const float bv = bias[co];
            #pragma unroll
            for (int r = 0; r < 4; ++r) {
                int t = t0 + w * 32 + i * 16 + orow + r;
                if (t < TLEN) {
                    int s = t / PP, kk = t - s * PP;
                    out[((size_t)(b * SS + s)) * 1152 + kk * 128 + co] = gelu_f(acc[i][j][r] + bv);
                }
            }
        }
}

// ---------- patch projection: hi/lo 3-MFMA, 6-way split-K ----------
__global__ __launch_bounds__(256) void pproj3_k(const float* __restrict__ A,
                                                const unsigned short* __restrict__ Wh,
                                                const unsigned short* __restrict__ Wl,
                                                float* __restrict__ Cp,
                                                int M) {
    __shared__ __align__(16) unsigned short Ah[128][40];
    __shared__ __align__(16) unsigned short Al[128][40];
    __shared__ __align__(16) unsigned short Bh[128][40];
    __shared__ __align__(16) unsigned short Bl[128][40];
    const int tid = threadIdx.x;
    const int gm0 = blockIdx.y * 128;
    const int z = blockIdx.z;
    const int w = tid >> 6, lane = tid & 63;
    const int wr0 = (w >> 1) * 64, wc0 = (w & 1) * 64;
    const int srow = tid >> 1, sc = (tid & 1) * 16;
    const int K = 1152;
    const int kb = z * 192;
    f32x4 acc[4][4];
    #pragma unroll
    for (int i = 0; i < 4; ++i)
        #pragma unroll
        for (int j = 0; j < 4; ++j) acc[i][j] = (f32x4){0.f, 0.f, 0.f, 0.f};
    const int fr = lane & 15, kg = (lane >> 4) * 8;
    for (int s = 0; s < 6; ++s) {
        const int k0 = kb + s * 32;
        __syncthreads();
        {
            const float* ga = A + (size_t)(gm0 + srow) * K + k0 + sc;
            #pragma unroll
            for (int g = 0; g < 2; ++g) {
                float4 v0 = *(const float4*)(ga + g * 8);
                float4 v1 = *(const float4*)(ga + g * 8 + 4);
                short8b h8, l8;
                float vv[8] = {v0.x, v0.y, v0.z, v0.w, v1.x, v1.y, v1.z, v1.w};
                #pragma unroll
                for (int e = 0; e < 8; ++e) {
                    unsigned short h = f2bf(vv[e]);
                    h8[e] = (short)h;
                    l8[e] = (short)f2bf(vv[e] - bf2f(h));
                }
                *(short8b*)&Ah[srow][sc + g * 8] = h8;
                *(short8b*)&Al[srow][sc + g * 8] = l8;
            }
            const unsigned short* gh = Wh + (size_t)srow * K + k0 + sc;
            const unsigned short* gl = Wl + (size_t)srow * K + k0 + sc;
            *(short8b*)&Bh[srow][sc] = *(const short8b*)gh;
            *(short8b*)&Bh[srow][sc + 8] = *(const short8b*)(gh + 8);
            *(short8b*)&Bl[srow][sc] = *(const short8b*)gl;
            *(short8b*)&Bl[srow][sc + 8] = *(const short8b*)(gl + 8);
        }
        __syncthreads();
        short8b afh[4], afl[4], bfh[4], bfl[4];
        #pragma unroll
        for (int i = 0; i < 4; ++i) {
            afh[i] = *(const short8b*)&Ah[wr0 + i * 16 + fr][kg];
            afl[i] = *(const short8b*)&Al[wr0 + i * 16 + fr][kg];
            bfh[i] = *(const short8b*)&Bh[wc0 + i * 16 + fr][kg];
            bfl[i] = *(const short8b*)&Bl[wc0 + i * 16 + fr][kg];
        }
        #pragma unroll
        for (int i = 0; i < 4; ++i)
            #pragma unroll
            for (int j = 0; j < 4; ++j) {
                acc[i][j] = __builtin_amdgcn_mfma_f32_16x16x32_bf16(afh[i], bfh[j], acc[i][j], 0, 0, 0);
                acc[i][j] = __builtin_amdgcn_mfma_f32_16x16x32_bf16(afh[i], bfl[j], acc[i][j], 0, 0, 0);
                acc[i][j] = __builtin_amdgcn_mfma_f32_16x16x32_bf16(afl[i], bfh[j], acc[i][j], 0, 0, 0);
            }
    }
    const int orow = (lane >> 4) * 4, ocol = lane & 15;
    float* Cz = Cp + (size_t)z * M * 128;
    #pragma unroll
    for (int i = 0; i < 4; ++i)
        #pragma unroll
        for (int j = 0; j < 4; ++j) {
            const int colg = wc0 + j * 16 + ocol;
            #pragma unroll
            for (int r = 0; r < 4; ++r) {
                const int rowg = gm0 + wr0 + i * 16 + orow + r;
                Cz[(size_t)rowg * 128 + colg] = acc[i][j][r];
            }
        }
}

// ---------- VQ distances via hi/lo 3-MFMA + in-wave argmin ----------
__global__ __launch_bounds__(256) void vq3_k(const float* __restrict__ ze,
                                             const unsigned short* __restrict__ ch,
                                             const unsigned short* __restrict__ cl,
                                             const float* __restrict__ cbn,
                                             float* __restrict__ pval,
                                             int* __restrict__ pidx,
                                             int M) {
    __shared__ __align__(16) unsigned short Ah[128][40];
    __shared__ __align__(16) unsigned short Al[128][40];
    __shared__ __align__(16) unsigned short Bh[128][40];
    __shared__ __align__(16) unsigned short Bl[128][40];
    __shared__ float bwv[128][2];
    __shared__ int bwi[128][2];
    const int tid = threadIdx.x;
    const int c0 = blockIdx.x * 128;
    const int gm0 = blockIdx.y * 128;
    const int w = tid >> 6, lane = tid & 63;
    const int wr0 = (w >> 1) * 64, wc0 = (w & 1) * 64;
    const int srow = tid >> 1, sc = (tid & 1) * 16;
    const int fr = lane & 15, kg = (lane >> 4) * 8;
    f32x4 acc[4][4];
    #pragma unroll
    for (int i = 0; i < 4; ++i)
        #pragma unroll
        for (int j = 0; j < 4; ++j) acc[i][j] = (f32x4){0.f, 0.f, 0.f, 0.f};
    for (int s = 0; s < 4; ++s) {
        const int k0 = s * 32;
        __syncthreads();
        {
            const float* ga = ze + (size_t)(gm0 + srow) * DP + k0 + sc;
            #pragma unroll
            for (int g = 0; g < 2; ++g) {
                float4 v0 = *(const float4*)(ga + g * 8);
                float4 v1 = *(const float4*)(ga + g * 8 + 4);
                short8b h8, l8;
                float vv[8] = {v0.x, v0.y, v0.z, v0.w, v1.x, v1.y, v1.z, v1.w};
                #pragma unroll
                for (int e = 0; e < 8; ++e) {
                    unsigned short h = f2bf(vv[e]);
                    h8[e] = (short)h;
                    l8[e] = (short)f2bf(vv[e] - bf2f(h));
                }
                *(short8b*)&Ah[srow][sc + g * 8] = h8;
                *(short8b*)&Al[srow][sc + g * 8] = l8;
            }
            const unsigned short* gh = ch + (size_t)(c0 + srow) * DP + k0 + sc;
            const unsigned short* gl = cl + (size_t)(c0 + srow) * DP + k0 + sc;
            *(short8b*)&Bh[srow][sc] = *(const short8b*)gh;
            *(short8b*)&Bh[srow][sc + 8] = *(const short8b*)(gh + 8);
            *(short8b*)&Bl[srow][sc] = *(const short8b*)gl;
            *(short8b*)&Bl[srow][sc + 8] = *(const short8b*)(gl + 8);
        }
        __syncthreads();
        short8b afh[4], afl[4], bfh[4], bfl[4];
        #pragma unroll
        for (int i = 0; i < 4; ++i) {
            afh[i] = *(const short8b*)&Ah[wr0 + i * 16 + fr][kg];
            afl[i] = *(const short8b*)&Al[wr0 + i * 16 + fr][kg];
            bfh[i] = *(const short8b*)&Bh[wc0 + i * 16 + fr][kg];
            bfl[i] = *(const short8b*)&Bl[wc0 + i * 16 + fr][kg];
        }
        #pragma unroll
        for (int i = 0; i < 4; ++i)
            #pragma unroll
            for (int j = 0; j < 4; ++j) {
                acc[i][j] = __builtin_amdgcn_mfma_f32_16x16x32_bf16(afh[i], bfh[j], acc[i][j], 0, 0, 0);
                acc[i][j] = __builtin_amdgcn_mfma_f32_16x16x32_bf16(afh[i], bfl[j], acc[i][j], 0, 0, 0);
                acc[i][j] = __builtin_amdgcn_mfma_f32_16x16x32_bf16(afl[i], bfh[j], acc[i][j], 0, 0, 0);
            }
    }
    const int orow = (lane >> 4) * 4, ocol = lane & 15;
    #pragma unroll
    for (int i = 0; i < 4; ++i)
        #pragma unroll
        for (int r = 0; r < 4; ++r) {
            int row = wr0 + i * 16 + orow + r;
            float bv = 1e30f; int bi = 0;
            #pragma unroll
            for (int j = 0; j < 4; ++j) {
                int col = c0 + wc0 + j * 16 + ocol;
                float d = cbn[col] - 2.0f * acc[i][j][r];
                if (d < bv || (d == bv && col < bi)) { bv = d; bi = col; }
            }
            #pragma unroll
            for (int o = 1; o < 16; o <<= 1) {
                float ov = __shfl_xor(bv, o);
                int oi = __shfl_xor(bi, o);
                if (ov < bv || (ov == bv && oi < bi)) { bv = ov; bi = oi; }
            }
            if (ocol == 0) { bwv[row][w & 1] = bv; bwi[row][w & 1] = bi; }
        }
    __syncthreads();
    if (tid < 128) {
        float v0 = bwv[tid][0], v1 = bwv[tid][1];
        int i0 = bwi[tid][0], i1 = bwi[tid][1];
        bool sel = (v1 < v0) || (v1 == v0 && i1 < i0);
        pval[(size_t)blockIdx.x * M + gm0 + tid] = sel ? v1 : v0;
        pidx[(size_t)blockIdx.x * M + gm0 + tid] = sel ? i1 : i0;
    }
}

// ---------- VQ finish ----------
__global__ __launch_bounds__(128) void vqfin_k(const float* __restrict__ ze,
                                               const float* __restrict__ cb,
                                               const float* __restrict__ pval,
                                               const int* __restrict__ pidx,
                                               unsigned short* __restrict__ zqb,
                                               float* __restrict__ vqs,
                                               int M) {
    const int row = blockIdx.x, tid = threadIdx.x;
    __shared__ float sm[2];
    __shared__ int tok_s;
    if (tid == 0) {
        float bv = pval[row]; int bi = pidx[row];
        #pragma unroll
        for (int z = 1; z < 4; ++z) {
            float v = pval[(size_t)z * M + row]; int ix = pidx[(size_t)z * M + row];
            if (v < bv || (v == bv && ix < bi)) { bv = v; bi = ix; }
        }
        tok_s = bi;
    }
    __syncthreads();
    int tok = tok_s;
    float qv = cb[(size_t)tok * DP + tid];
    float zv = ze[(size_t)row * DP + tid];
    zqb[(size_t)row * DP + tid] = f2bf(qv);
    float d = qv - zv;
    float tot = block_sum_128(d * d, sm);
    if (tid == 0) vqs[row] = tot;
}

// ---------- bf16 MFMA implicit-GEMM conv ----------
template <int CI, int K, int PAD>
__global__ __launch_bounds__(256) void mfconv_k(const unsigned short* __restrict__ in,
                                                const unsigned short* __restrict__ wpk,
                                                const float* __restrict__ bias,
                                                unsigned short* __restrict__ out) {
    constexpr int CIC = (CI > 64) ? 64 : CI;
    constexpr int NCH = CI / CIC;
    constexpr int TROWS = 128 + K - 1;
    constexpr int CQ = CIC / 8;
    __shared__ __align__(16) unsigned short in_s[TROWS][CIC + 8];
    __shared__ __align__(16) unsigned short w_s[K][64][CIC + 8];
    const int b = blockIdx.z;
    const int t0 = blockIdx.x * 128;
    const int tid = threadIdx.x;
    const int w = tid >> 6, lane = tid & 63;
    const int fr = lane & 15, kg = (lane >> 4) * 8;
    f32x4 acc[2][4];
    #pragma unroll
    for (int i = 0; i < 2; ++i)
        #pragma unroll
        for (int j = 0; j < 4; ++j) acc[i][j] = (f32x4){0.f, 0.f, 0.f, 0.f};
    for (int ch = 0; ch < NCH; ++ch) {
        const int c0 = ch * CIC;
        if (ch) __syncthreads();
        for (int u = tid; u < TROWS * CQ; u += 256) {
            int row = u / CQ, q = u - row * CQ;
            int t = t0 + row - PAD;
            short8b v = (short8b){0, 0, 0, 0, 0, 0, 0, 0};
            if (t >= 0 && t < TLEN)
                v = *(const short8b*)&in[((size_t)(b * TLEN + t)) * CI + c0 + q * 8];
            *(short8b*)&in_s[row][q * 8] = v;
        }
        for (int u = tid; u < K * 64 * CQ; u += 256) {
            int q = u % CQ; int rest = u / CQ; int co = rest & 63; int k = rest >> 6;
            *(short8b*)&w_s[k][co][q * 8] =
                *(const short8b*)&wpk[((size_t)(k * 64 + co)) * CI + c0 + q * 8];
        }
        __syncthreads();
        #pragma unroll
        for (int k = 0; k < K; ++k) {
            #pragma unroll
            for (int c32 = 0; c32 < CIC / 32; ++c32) {
                short8b a0 = *(const short8b*)&in_s[w * 32 + fr + k][c32 * 32 + kg];
                short8b a1 = *(const short8b*)&in_s[w * 32 + 16 + fr + k][c32 * 32 + kg];
                short8b b0 = *(const short8b*)&w_s[k][fr][c32 * 32 + kg];
                short8b b1 = *(const short8b*)&w_s[k][16 + fr][c32 * 32 + kg];
                short8b b2 = *(const short8b*)&w_s[k][32 + fr][c32 * 32 + kg];
                short8b b3 = *(const short8b*)&w_s[k][48 + fr][c32 * 32 + kg];
                acc[0][0] = __builtin_amdgcn_mfma_f32_16x16x32_bf16(a0, b0, acc[0][0], 0, 0, 0);
                acc[0][1] = __builtin_amdgcn_mfma_f32_16x16x32_bf16(a0, b1, acc[0][1], 0, 0, 0);
                acc[0][2] = __builtin_amdgcn_mfma_f32_16x16x32_bf16(a0, b2, acc[0][2], 0, 0, 0);
                acc[0][3] = __builtin_amdgcn_mfma_f32_16x16x32_bf16(a0, b3, acc[0][3], 0, 0, 0);
                acc[1][0] = __builtin_amdgcn_mfma_f32_16x16x32_bf16(a1, b0, acc[1][0], 0, 0, 0);
                acc[1][1] = __builtin_amdgcn_mfma_f32_16x16x32_bf16(a1, b1, acc[1][1], 0, 0, 0);
                acc[1][2] = __builtin_amdgcn_mfma_f32_16x16x32_bf16(a1, b2, acc[1][2], 0, 0, 0);
                acc[1][3] = __builtin_amdgcn_mfma_f32_16x16x32_bf16(a1, b3, acc[1][3], 0, 0, 0);
            }
        }
    }
    const int orow = (lane >> 4) * 4, ocol = lane & 15;
    #pragma unroll
    for (int i = 0; i < 2; ++i)
        #pragma unroll
        for (int j = 0; j < 4; ++j) {
            const int co = j * 16 + ocol;
            const float bv = bias[co];
            #pragma unroll
            for (int r = 0; r < 4; ++r) {
                int t = t0 + w * 32 + i * 16 + orow + r;
                if (t < TLEN)
                    out[((size_t)(b * TLEN + t)) * 64 + co] = f2bf(gelu_f(acc[i][j][r] + bv));
            }
        }
}

// ---------- bf16 MFMA GEMM, 128x128 tile ----------
template <int ACT, int RES, int OUTBF>
__global__ __launch_bounds__(256) void bgemm_k(const unsigned short* __restrict__ A,
                                               const unsigned short* __restrict__ W,
                                               const float* __restrict__ bias,
                                               const float* __restrict__ res,
                                               void* __restrict__ Cv,
                                               int M, int N, int K) {
    __shared__ __align__(16) unsigned short As[128][40];
    __shared__ __align__(16) unsigned short Bs[128][40];
    const int tid = threadIdx.x;
    const int gm0 = blockIdx.y * 128, gn0 = blockIdx.x * 128;
    const int w = tid >> 6, lane = tid & 63;
    const int wr0 = (w >> 1) * 64, wc0 = (w & 1) * 64;
    const int srow = tid >> 1, sc = (tid & 1) * 16;
    const unsigned short* ga = A + (size_t)(gm0 + srow) * K + sc;
    const unsigned short* gb = W + (size_t)(gn0 + srow) * K + sc;
    short8b ra0 = *(const short8b*)(ga), ra1 = *(const short8b*)(ga + 8);
    short8b rb0 = *(const short8b*)(gb), rb1 = *(const short8b*)(gb + 8);
    f32x4 acc[4][4];
    #pragma unroll
    for (int i = 0; i < 4; ++i)
        #pragma unroll
        for (int j = 0; j < 4; ++j) acc[i][j] = (f32x4){0.f, 0.f, 0.f, 0.f};
    const int fr = lane & 15, kg = (lane >> 4) * 8;
    const int nstep = K >> 5;
    for (int s = 0; s < nstep; ++s) {
        __syncthreads();
        *(short8b*)&As[srow][sc] = ra0; *(short8b*)&As[srow][sc + 8] = ra1;
        *(short8b*)&Bs[srow][sc] = rb0; *(short8b*)&Bs[srow][sc + 8] = rb1;
        __syncthreads();
        if (s + 1 < nstep) {
            ga += 32; gb += 32;
            ra0 = *(const short8b*)(ga); ra1 = *(const short8b*)(ga + 8);
            rb0 = *(const short8b*)(gb); rb1 = *(const short8b*)(gb + 8);
        }
        short8b af[4], bf[4];
        #pragma unroll
        for (int i = 0; i < 4; ++i) {
            af[i] = *(const short8b*)&As[wr0 + i * 16 + fr][kg];
            bf[i] = *(const short8b*)&Bs[wc0 + i * 16 + fr][kg];
        }
        #pragma unroll
        for (int i = 0; i < 4; ++i)
            #pragma unroll
            for (int j = 0; j < 4; ++j)
                acc[i][j] = __builtin_amdgcn_mfma_f32_16x16x32_bf16(af[i], bf[j], acc[i][j], 0, 0, 0);
    }
    const int orow = (lane >> 4) * 4, ocol = lane & 15;
    #pragma unroll
    for (int i = 0; i < 4; ++i) {
        #pragma unroll
        for (int j = 0; j < 4; ++j) {
            const int colg = gn0 + wc0 + j * 16 + ocol;
            const float bsv = bias[colg];
            #pragma unroll
            for (int r = 0; r < 4; ++r) {
                const int rowg = gm0 + wr0 + i * 16 + orow + r;
                float v = acc[i][j][r] + bsv;
                if (ACT) v = gelu_f(v);
                if (RES) v += res[(size_t)rowg * N + colg];
                if (OUTBF) ((unsigned short*)Cv)[(size_t)rowg * N + colg] = f2bf(v);
                else ((float*)Cv)[(size_t)rowg * N + colg] = v;
            }
        }
    }
}

// ---------- bf16 MFMA GEMM, 64x128 tile (grid-rich variant for small GEMMs) ----------
template <int ACT, int RES, int OUTBF>
__global__ __launch_bounds__(256) void bgemm64_k(const unsigned short* __restrict__ A,
                                                 const unsigned short* __restrict__ W,
                                                 const float* __restrict__ bias,
                                                 const float* __restrict__ res,
                                                 void* __restrict__ Cv,
                                                 int M, int N, int K) {
    __shared__ __align__(16) unsigned short As[64][40];
    __shared__ __align__(16) unsigned short Bs[128][40];
    const int tid = threadIdx.x;
    const int gm0 = blockIdx.y * 64, gn0 = blockIdx.x * 128;
    const int w = tid >> 6, lane = tid & 63;
    const int wc0 = w * 32;
    const int arow = tid >> 2, ac = (tid & 3) * 8;
    const int brow = tid >> 1, bc = (tid & 1) * 16;
    const unsigned short* ga = A + (size_t)(gm0 + arow) * K + ac;
    const unsigned short* gb = W + (size_t)(gn0 + brow) * K + bc;
    short8b ra0 = *(const short8b*)(ga);
    short8b rb0 = *(const short8b*)(gb), rb1 = *(const short8b*)(gb + 8);
    f32x4 acc[4][2];
    #pragma unroll
    for (int i = 0; i < 4; ++i)
        #pragma unroll
        for (int j = 0; j < 2; ++j) acc[i][j] = (f32x4){0.f, 0.f, 0.f, 0.f};
    const int fr = lane & 15, kg = (lane >> 4) * 8;
    const int nstep = K >> 5;
    for (int s = 0; s < nstep; ++s) {
        __syncthreads();
        *(short8b*)&As[arow][ac] = ra0;
        *(short8b*)&Bs[brow][bc] = rb0; *(short8b*)&Bs[brow][bc + 8] = rb1;
        __syncthreads();
        if (s + 1 < nstep) {
            ga += 32; gb += 32;
            ra0 = *(const short8b*)(ga);
            rb0 = *(const short8b*)(gb); rb1 = *(const short8b*)(gb + 8);
        }
        short8b af[4], bf[2];
        #pragma unroll
        for (int i = 0; i < 4; ++i) af[i] = *(const short8b*)&As[i * 16 + fr][kg];
        #pragma unroll
        for (int j = 0; j < 2; ++j) bf[j] = *(const short8b*)&Bs[wc0 + j * 16 + fr][kg];
        #pragma unroll
        for (int i = 0; i < 4; ++i)
            #pragma unroll
            for (int j = 0; j < 2; ++j)
                acc[i][j] = __builtin_amdgcn_mfma_f32_16x16x32_bf16(af[i], bf[j], acc[i][j], 0, 0, 0);
    }
    const int orow = (lane >> 4) * 4, ocol = lane & 15;
    #pragma unroll
    for (int i = 0; i < 4; ++i) {
        #pragma unroll
        for (int j = 0; j < 2; ++j) {
            const int colg = gn0 + wc0 + j * 16 + ocol;
            const float bsv = bias[colg];
            #pragma unroll
            for (int r = 0; r < 4; ++r) {
                const int rowg = gm0 + i * 16 + orow + r;
                float v = acc[i][j][r] + bsv;
                if (ACT) v = gelu_f(v);
                if (RES) v += res[(size_t)rowg * N + colg];
                if (OUTBF) ((unsigned short*)Cv)[(size_t)rowg * N + colg] = f2bf(v);
                else ((float*)Cv)[(size_t)rowg * N + colg] = v;
            }
        }
    }
}

// ---------- LayerNorm over 128 with 6-way split-K partial sum + bias ----------
__global__ __launch_bounds__(128) void ln128s_k(const float* __restrict__ part,
                                                const float* __restrict__ bias,
                                                const float* __restrict__ g,
                                                const float* __restrict__ bb,
                                                float* __restrict__ out,
                                                int M) {
    int row = blockIdx.x, tid = threadIdx.x;
    __shared__ float sm[2];
    size_t stride = (size_t)M * DP;
    size_t base = (size_t)row * DP + tid;
    float v = bias[tid];
    #pragma unroll
    for (int s2 = 0; s2 < 6; ++s2) v += part[base + (size_t)s2 * stride];
    float mean = block_sum_128(v, sm) * (1.0f / DP);
    float d = v - mean;
    float var = block_sum_128(d * d, sm) * (1.0f / DP);
    out[(size_t)row * DP + tid] = d * rsqrtf(var + 1e-5f) * g[tid] + bb[tid];
}

__global__ void vqreduce_k(const float* __restrict__ vqs, float* __restrict__ out) {
    float s = 0;
    for (int i = threadIdx.x; i < BATCH * SS; i += 256) s += vqs[i];
    __shared__ float sm[4];
    s = block_sum_256(s, sm);
    if (threadIdx.x == 0) out[0] = s * (1.25f / (float)(BATCH * SS * DP));
}

// ---------- wave-per-row LayerNorm over 256 (shfl-only) ----------
template <int OUTBF>
__global__ __launch_bounds__(256) void lnw_k(const float* __restrict__ in,
                                             const float* __restrict__ g,
                                             const float* __restrict__ bb,
                                             void* __restrict__ out) {
    const int row = blockIdx.x * 4 + (threadIdx.x >> 6);
    const int lane = threadIdx.x & 63;
    float4 v = *(const float4*)&in[(size_t)row * DM + lane * 4];
    float s = v.x + v.y + v.z + v.w;
    #pragma unroll
    for (int o = 1; o < 64; o <<= 1) s += __shfl_xor(s, o);
    float mean = s * (1.0f / DM);
    float dx = v.x - mean, dy = v.y - mean, dz = v.z - mean, dw = v.w - mean;
    float vv = dx * dx + dy * dy + dz * dz + dw * dw;
    #pragma unroll
    for (int o = 1; o < 64; o <<= 1) vv += __shfl_xor(vv, o);
    float rstd = rsqrtf(vv * (1.0f / DM) + 1e-5f);
    float4 gv = *(const float4*)&g[lane * 4];
    float4 bv = *(const float4*)&bb[lane * 4];
    float o0 = dx * rstd * gv.x + bv.x;
    float o1 = dy * rstd * gv.y + bv.y;
    float o2 = dz * rstd * gv.z + bv.z;
    float o3 = dw * rstd * gv.w + bv.w;
    if (OUTBF) {
        unsigned long long pk = (unsigned long long)f2bf(o0)
                              | ((unsigned long long)f2bf(o1) << 16)
                              | ((unsigned long long)f2bf(o2) << 32)
                              | ((unsigned long long)f2bf(o3) << 48);
        *(unsigned long long*)((unsigned short*)out + (size_t)row * DM + lane * 4) = pk;
    } else {
        float4 o4; o4.x = o0; o4.y = o1; o4.z = o2; o4.w = o3;
        *(float4*)((float*)out + (size_t)row * DM + lane * 4) = o4;
    }
}

// ---------- fused double LayerNorm: hb = LN(tx;g1,b1), xnb = LN(hb;g2,b2) bf16 ----------
__global__ __launch_bounds__(256) void lnw2_k(const float* __restrict__ in,
                                              const float* __restrict__ g1,
                                              const float* __restrict__ b1,
                                              const float* __restrict__ g2,
                                              const float* __restrict__ b2,
                                              float* __restrict__ hbout,
                                              unsigned short* __restrict__ xout) {
    const int row = blockIdx.x * 4 + (threadIdx.x >> 6);
    const int lane = threadIdx.x & 63;
    float4 v = *(const float4*)&in[(size_t)row * DM + lane * 4];
    float s = v.x + v.y + v.z + v.w;
    #pragma unroll
    for (int o = 1; o < 64; o <<= 1) s += __shfl_xor(s, o);
    float mean = s * (1.0f / DM);
    float dx = v.x - mean, dy = v.y - mean, dz = v.z - mean, dw = v.w - mean;
    float vv = dx * dx + dy * dy + dz * dz + dw * dw;
    #pragma unroll
    for (int o = 1; o < 64; o <<= 1) vv += __shfl_xor(vv, o);
    float rstd = rsqrtf(vv * (1.0f / DM) + 1e-5f);
    float4 g1v = *(const float4*)&g1[lane * 4];
    float4 b1v = *(const float4*)&b1[lane * 4];
    float h0 = dx * rstd * g1v.x + b1v.x;
    float h1 = dy * rstd * g1v.y + b1v.y;
    float h2 = dz * rstd * g1v.z + b1v.z;
    float h3 = dw * rstd * g1v.w + b1v.w;
    float4 h4; h4.x = h0; h4.y = h1; h4.z = h2; h4.w = h3;
    *(float4*)&hbout[(size_t)row * DM + lane * 4] = h4;
    float s2 = h0 + h1 + h2 + h3;
    #pragma unroll
    for (int o = 1; o < 64; o <<= 1) s2 += __shfl_xor(s2, o);
    float mean2 = s2 * (1.0f / DM);
    float ex = h0 - mean2, ey = h1 - mean2, ez = h2 - mean2, ew = h3 - mean2;
    float vv2 = ex * ex + ey * ey + ez * ez + ew * ew;
    #pragma unroll
    for (int o = 1; o < 64; o <<= 1) vv2 += __shfl_xor(vv2, o);
    float rstd2 = rsqrtf(vv2 * (1.0f / DM) + 1e-5f);
    float4 g2v = *(const float4*)&g2[lane * 4];
    float4 b2v = *(const float4*)&b2[lane * 4];
    unsigned long long pk = (unsigned long long)f2bf(ex * rstd2 * g2v.x + b2v.x)
                          | ((unsigned long long)f2bf(ey * rstd2 * g2v.y + b2v.y) << 16)
                          | ((unsigned long long)f2bf(ez * rstd2 * g2v.z + b2v.z) << 32)
                          | ((unsigned long long)f2bf(ew * rstd2 * g2v.w + b2v.w) << 48);
    *(unsigned long long*)&xout[(size_t)row * DM + lane * 4] = pk;
}

// ---------- fused flash MFMA attention, 64-q blocks (proven variant) ----------
__global__ __launch_bounds__(256) void fattn_k(const unsigned short* __restrict__ qkv,
                                               const float* __restrict__ slopes,
                                               unsigned short* __restrict__ out) {
    __shared__ __align__(16) unsigned short Qs[64][40];
    __shared__ __align__(16) unsigned short Ks[64][40];
    __shared__ __align__(16) unsigned short Vt[32][72];
    __shared__ __align__(16) unsigned short Ps[4][16][72];
    const int qb = blockIdx.x, hh = blockIdx.y, b = blockIdx.z;
    const int tid = threadIdx.x;
    const int w = tid >> 6, lane = tid & 63;
    const int lr = lane & 15, lg = lane >> 4;
    const float slope = fabsf(slopes[hh]);
    const unsigned short* base = qkv + (size_t)b * SS * (3 * DM);
    {
        int row = tid >> 2, c = (tid & 3) * 8;
        int q = qb * 64 + row; q = q < SS ? q : SS - 1;
        *(short8b*)&Qs[row][c] = *(const short8b*)(base + (size_t)q * (3 * DM) + hh * HD + c);
    }
    __syncthreads();
    const short8b qa = *(const short8b*)&Qs[w * 16 + lr][lg * 8];
    float m_run[4] = {-1e30f, -1e30f, -1e30f, -1e30f};
    float l_run[4] = {0.f, 0.f, 0.f, 0.f};
    f32x4 of0 = (f32x4){0.f, 0.f, 0.f, 0.f}, of1 = (f32x4){0.f, 0.f, 0.f, 0.f};
    const int qg0 = qb * 64 + w * 16 + lg * 4;
    for (int kt = 0; kt < SS; kt += 64) {
        const int tl = (SS - kt) < 64 ? (SS - kt) : 64;
        const int nks = tl >> 4;
        __syncthreads();
        {
            int row = tid >> 2, c = (tid & 3) * 8;
            if (row < tl) {
                *(short8b*)&Ks[row][c] =
                    *(const short8b*)(base + (size_t)(kt + row) * (3 * DM) + DM + hh * HD + c);
                short8b v8 = *(const short8b*)(base + (size_t)(kt + row) * (3 * DM) + 2 * DM + hh * HD + c);
                #pragma unroll
                for (int j = 0; j < 8; ++j) Vt[c + j][row] = ((unsigned short*)&v8)[j];
            }
        }
        __syncthreads();
        f32x4 sf[4];
        #pragma unroll
        for (int ks = 0; ks < 4; ++ks) {
            if (ks < nks) {
                short8b kb = *(const short8b*)&Ks[ks * 16 + lr][lg * 8];
                sf[ks] = __builtin_amdgcn_mfma_f32_16x16x32_bf16(qa, kb, (f32x4){0.f, 0.f, 0.f, 0.f}, 0, 0, 0);
            }
        }
        float pv[4][4];
        #pragma unroll
        for (int r = 0; r < 4; ++r) {
            float tmax = -1e30f;
            #pragma unroll
            for (int ks = 0; ks < 4; ++ks) {
                if (ks < nks) {
                    float sv = sf[ks][r] * 0.17677669529663687f
                             - slope * fabsf((float)(qg0 + r - (kt + ks * 16 + lr)));
                    pv[ks][r] = sv;
                    tmax = fmaxf(tmax, sv);
                }
            }
            #pragma unroll
            for (int o = 1; o < 16; o <<= 1) tmax = fmaxf(tmax, __shfl_xor(tmax, o));
            float mnew = fmaxf(m_run[r], tmax);
            float sc = __expf(m_run[r] - mnew);
            m_run[r] = mnew;
            float tsum = 0.f;
            #pragma unroll
            for (int ks = 0; ks < 4; ++ks) {
                if (ks < nks) {
                    float e = __expf(pv[ks][r] - mnew);
                    pv[ks][r] = e;
                    tsum += e;
                }
            }
            #pragma unroll
            for (int o = 1; o < 16; o <<= 1) tsum += __shfl_xor(tsum, o);
            l_run[r] = l_run[r] * sc + tsum;
            of0[r] *= sc; of1[r] *= sc;
        }
        #pragma unroll
        for (int ks = 0; ks < 4; ++ks)
            #pragma unroll
            for (int r = 0; r < 4; ++r)
                Ps[w][lg * 4 + r][ks * 16 + lr] = (ks < nks) ? f2bf(pv[ks][r]) : (unsigned short)0;
        #pragma unroll
        for (int kc = 0; kc < 64; kc += 32) {
            if (kc < nks * 16) {
                short8b pa = *(const short8b*)&Ps[w][lr][kc + lg * 8];
                short8b vb0 = *(const short8b*)&Vt[lr][kc + lg * 8];
                short8b vb1 = *(const short8b*)&Vt[16 + lr][kc + lg * 8];
                of0 = __builtin_amdgcn_mfma_f32_16x16x32_bf16(pa, vb0, of0, 0, 0, 0);
                of1 = __builtin_amdgcn_mfma_f32_16x16x32_bf16(pa, vb1, of1, 0, 0, 0);
            }
        }
    }
    #pragma unroll
    for (int r = 0; r < 4; ++r) {
        int q = qg0 + r;
        if (q < SS) {
            float inv = 1.0f / l_run[r];
            out[((size_t)(b * SS + q)) * DM + hh * HD + lr] = f2bf(of0[r] * inv);
            out[((size_t)(b * SS + q)) * DM + hh * HD + 16 + lr] = f2bf(of1[r] * inv);
        }
    }
}

// ---------- final: d2 conv + r4 1x1 conv + alpha blend; inputs bf16 TM ----------
__global__ __launch_bounds__(256) void final2_k(const unsigned short* __restrict__ ud1,
                                                const unsigned short* __restrict__ r3i,
                                                const float* __restrict__ d2w,
                                                const float* __restrict__ d2b,
                                                const float* __restrict__ r4w,
                                                const float* __restrict__ r4b,
                                                const float* __restrict__ alpha,
                                                float* __restrict__ out) {
    __shared__ float u_s[64][66];
    __shared__ float r_s[64][64];
    __shared__ float wd_s[64][3][12];
    __shared__ float wr_s[64][12];
    __shared__ float o_s[64][12];
    const int b = blockIdx.z, t0 = blockIdx.x * 64, tid = threadIdx.x;
    for (int u2 = tid; u2 < 66 * 8; u2 += 256) {
        int j = u2 >> 3, q = u2 & 7;
        int t = t0 + j - 1;
        short8b v = (short8b){0, 0, 0, 0, 0, 0, 0, 0};
        if (t >= 0 && t < TLEN) v = *(const short8b*)&ud1[((size_t)(b * TLEN + t)) * 64 + q * 8];
        #pragma unroll
        for (int i = 0; i < 8; ++i) u_s[q * 8 + i][j] = bf2f((unsigned short)v[i]);
    }
    for (int u2 = tid; u2 < 64 * 8; u2 += 256) {
        int j = u2 >> 3, q = u2 & 7;
        int t = t0 + j;
        short8b v = (short8b){0, 0, 0, 0, 0, 0, 0, 0};
        if (t < TLEN) v = *(const short8b*)&r3i[((size_t)(b * TLEN + t)) * 64 + q * 8];
        #pragma unroll
        for (int i = 0; i < 8; ++i) r_s[q * 8 + i][j] = bf2f((unsigned short)v[i]);
    }
    for (int idx = tid; idx < 64 * 3 * 12; idx += 256) {
        int l = idx % 12, k = (idx / 12) % 3, ci = idx / 36;
        wd_s[ci][k][l] = d2w[(l * 64 + ci) * 3 + k];
    }
    for (int idx = tid; idx < 64 * 12; idx += 256) {
        int l = idx % 12, ci = idx / 12;
        wr_s[ci][l] = r4w[l * 64 + ci];
    }
    __syncthreads();
    const int tl = tid & 63, lg = tid >> 6;
    float accD[3] = {}, accR[3] = {};
    for (int ci = 0; ci < 64; ++ci) {
        float a0 = u_s[ci][tl], a1 = u_s[ci][tl + 1], a2 = u_s[ci][tl + 2];
        float rv = r_s[ci][tl];
        #pragma unroll
        for (int c = 0; c < 3; ++c) {
            int l = lg * 3 + c;
            accD[c] += a0 * wd_s[ci][0][l] + a1 * wd_s[ci][1][l] + a2 * wd_s[ci][2][l];
            accR[c] = fmaf(rv, wr_s[ci][l], accR[c]);
        }
    }
    float al = alpha[0];
    #pragma unroll
    for (int c = 0; c < 3; ++c) {
        int l = lg * 3 + c;
        o_s[tl][l] = accD[c] + d2b[l] + al * (accR[c] + r4b[l]);
    }
    __syncthreads();
    for (int idx = tid; idx < 64 * 12; idx += 256) {
        int t = t0 + idx / 12;
        if (t < TLEN) out[((size_t)b * TLEN + t) * 12 + idx % 12] = o_s[idx / 12][idx % 12];
    }
}

extern "C" void kernel_launch(void* const* d_in, const int* in_sizes, int n_in,
                              void* d_out, int out_size, void* d_ws, size_t ws_size,
                              hipStream_t stream) {
    const float* x     = (const float*)d_in[0];
    const float* pe_w1 = (const float*)d_in[1];
    const float* pe_b1 = (const float*)d_in[2];
    const float* pe_w2 = (const float*)d_in[3];
    const float* pe_b2 = (const float*)d_in[4];
    const float* pe_pw = (const float*)d_in[5];
    const float* pe_pb = (const float*)d_in[6];
    const float* pe_g  = (const float*)d_in[7];
    const float* pe_bb = (const float*)d_in[8];
    const float* cb    = (const float*)d_in[9];
    const float* tp_w  = (const float*)d_in[10];
    const float* tp_b  = (const float*)d_in[11];
    const float* tp_g  = (const float*)d_in[12];
    const float* tp_bb = (const float*)d_in[13];
    const float* ln1_g = (const float*)d_in[14];
    const float* ln1_b = (const float*)d_in[15];
    const float* inw   = (const float*)d_in[16];
    const float* inb   = (const float*)d_in[17];
    const float* ow    = (const float*)d_in[18];
    const float* ob    = (const float*)d_in[19];
    const float* ln2_g = (const float*)d_in[20];
    const float* ln2_b = (const float*)d_in[21];
    const float* f1w   = (const float*)d_in[22];
    const float* f1b   = (const float*)d_in[23];
    const float* f2w   = (const float*)d_in[24];
    const float* f2b   = (const float*)d_in[25];
    const float* slopes= (const float*)d_in[26];
    const float* fn_g  = (const float*)d_in[27];
    const float* fn_b  = (const float*)d_in[28];
    const float* up_w  = (const float*)d_in[29];
    const float* up_b  = (const float*)d_in[30];
    const float* d1w   = (const float*)d_in[31];
    const float* d1b   = (const float*)d_in[32];
    const float* d2w   = (const float*)d_in[33];
    const float* d2b   = (const float*)d_in[34];
    const float* r1w   = (const float*)d_in[35];
    const float* r1b   = (const float*)d_in[36];
    const float* r2w   = (const float*)d_in[37];
    const float* r2b   = (const float*)d_in[38];
    const float* r3w   = (const float*)d_in[39];
    const float* r3b   = (const float*)d_in[40];
    const float* r4w   = (const float*)d_in[41];
    const float* r4b   = (const float*)d_in[42];
    const float* alpha = (const float*)d_in[43];

    float* W = (float*)d_ws;
    size_t off = 0;
    auto alloc = [&](size_t n) { float* p = W + off; off += (n + 3) & ~(size_t)3; return p; };
    const size_t M = (size_t)BATCH * SS;  // 6400
    float* A    = alloc((size_t)BATCH * DP * TLEN);
    float* Bb   = alloc((size_t)BATCH * 64 * TLEN);
    float* ze   = alloc(M * DP);
    float* tx   = alloc(M * DM);
    float* hb   = alloc(M * DM);
    float* qf   = alloc(M * 3 * DM);
    float* cbn  = alloc(VV);
    float* vqs  = alloc(M);
    float* upb2 = alloc(1152);
    float* pval = alloc(4 * M);
    int*   pidx = (int*)alloc(4 * M);
    unsigned short* zqb  = (unsigned short*)alloc(M * DP / 2);
    unsigned short* xnb  = (unsigned short*)alloc(M * DM / 2);
    unsigned short* aob  = (unsigned short*)alloc(M * DM / 2);
    float* pgpart        = qf;
    unsigned short* qkvb = (unsigned short*)qf;
    unsigned short* ffb  = (unsigned short*)qf;
    unsigned short* utm  = (unsigned short*)qf;
    unsigned short* inwb = (unsigned short*)alloc((size_t)NLAY * 3 * DM * DM / 2);
    unsigned short* owb  = (unsigned short*)alloc((size_t)NLAY * DM * DM / 2);
    unsigned short* f1wb = (unsigned short*)alloc((size_t)NLAY * 4 * DM * DM / 2);
    unsigned short* f2wb = (unsigned short*)alloc((size_t)NLAY * 4 * DM * DM / 2);
    unsigned short* tpwb = (unsigned short*)alloc((size_t)DM * DP / 2);
    unsigned short* upwb = (unsigned short*)alloc((size_t)1152 * DM / 2);
    unsigned short* pwh  = (unsigned short*)alloc((size_t)128 * 1152 / 2);
    unsigned short* pwl  = (unsigned short*)alloc((size_t)128 * 1152 / 2);
    unsigned short* w2h  = (unsigned short*)alloc((size_t)3 * 128 * 64 / 2);
    unsigned short* w2l  = (unsigned short*)alloc((size_t)3 * 128 * 64 / 2);
    unsigned short* cbh  = (unsigned short*)alloc((size_t)VV * DP / 2);
    unsigned short* cbl  = (unsigned short*)alloc((size_t)VV * DP / 2);
    unsigned short* r2pk = (unsigned short*)alloc((size_t)64 * 64 * 5 / 2);
    unsigned short* r3pk = (unsigned short*)alloc((size_t)64 * 64 * 3 / 2 + 2);
    unsigned short* d1pk = (unsigned short*)alloc((size_t)64 * 128 * 5 / 2);
    unsigned short* r1tm = (unsigned short*)alloc((size_t)BATCH * TLEN * 64 / 2);
    unsigned short* r2tm = (unsigned short*)alloc((size_t)BATCH * TLEN * 64 / 2);
    unsigned short* r3tm = (unsigned short*)alloc((size_t)BATCH * TLEN * 64 / 2);
    unsigned short* d1tm = (unsigned short*)alloc((size_t)BATCH * TLEN * 64 / 2);
    if (off * sizeof(float) > ws_size) return;

    float* outp = (float*)d_out;
    const dim3 cgrid(57, 1, BATCH);
    const dim3 mgrid(29, 1, BATCH);

    // --- ALL weight conversions / packs in ONE launch ---
    packall_k<<<(5358080 + 255) / 256, 256, 0, stream>>>(
        inw, inwb, ow, owb, f1w, f1wb, f2w, f2wb, tp_w, tpwb,
        up_w, up_b, upwb, upb2, pe_pw, pwh, pwl, pe_w2, w2h, w2l,
        cb, cbh, cbl, cbn, r2w, r2pk, r3w, r3pk, d1w, d1pk);

    // --- fused pe1 + r1 ---
    enc1_k<<<dim3(57, BATCH), 256, 0, stream>>>(x, pe_w1, pe_b1, r1w, r1b, Bb, r1tm);

    // --- encoder tail ---
    pe2m_k<<<dim3(29, BATCH), 256, 0, stream>>>(Bb, w2h, w2l, pe_b2, A);
    pproj3_k<<<dim3(1, M / 128, 6), 256, 0, stream>>>(A, pwh, pwl, pgpart, M);
    ln128s_k<<<M, 128, 0, stream>>>(pgpart, pe_pb, pe_g, pe_bb, ze, M);
    vq3_k<<<dim3(4, M / 128), 256, 0, stream>>>(ze, cbh, cbl, cbn, pval, pidx, M);
    vqfin_k<<<M, 128, 0, stream>>>(ze, cb, pval, pidx, zqb, vqs, M);
    vqreduce_k<<<1, 256, 0, stream>>>(vqs, outp + (size_t)BATCH * TLEN * LEADS);

    // --- residual CNN ---
    mfconv_k<64, 5, 2><<<mgrid, 256, 0, stream>>>(r1tm, r2pk, r2b, r2tm);
    mfconv_k<64, 3, 1><<<mgrid, 256, 0, stream>>>(r2tm, r3pk, r3b, r3tm);

    // --- token projection + fused double-LN ---
    bgemm64_k<0, 0, 0><<<dim3(DM / 128, M / 64), 256, 0, stream>>>(zqb, tpwb, tp_b, nullptr, tx, M, DM, DP);
    lnw2_k<<<M / 4, 256, 0, stream>>>(tx, tp_g, tp_bb, ln1_g, ln1_b, hb, xnb);

    // --- transformer (all GEMMs on 64-row tiles for grid richness) ---
    for (int l = 0; l < NLAY; ++l) {
        if (l) lnw_k<1><<<M / 4, 256, 0, stream>>>(hb, ln1_g + l * DM, ln1_b + l * DM, xnb);
        bgemm64_k<0, 0, 1><<<dim3(3 * DM / 128, M / 64), 256, 0, stream>>>(
            xnb, inwb + (size_t)l * 3 * DM * DM, inb + l * 3 * DM, nullptr, qkvb, M, 3 * DM, DM);
        fattn_k<<<dim3((SS + 63) / 64, NH, BATCH), 256, 0, stream>>>(qkvb, slopes + l * NH, aob);
        bgemm64_k<0, 1, 0><<<dim3(DM / 128, M / 64), 256, 0, stream>>>(
            aob, owb + (size_t)l * DM * DM, ob + l * DM, hb, hb, M, DM, DM);
        lnw_k<1><<<M / 4, 256, 0, stream>>>(hb, ln2_g + l * DM, ln2_b + l * DM, xnb);
        bgemm64_k<1, 0, 1><<<dim3(4 * DM / 128, M / 64), 256, 0, stream>>>(
            xnb, f1wb + (size_t)l * 4 * DM * DM, f1b + l * 4 * DM, nullptr, ffb, M, 4 * DM, DM);
        bgemm64_k<0, 1, 0><<<dim3(DM / 128, M / 64), 256, 0, stream>>>(
            ffb, f2wb + (size_t)l * 4 * DM * DM, f2b + l * DM, hb, hb, M, DM, 4 * DM);
    }
    lnw_k<1><<<M / 4, 256, 0, stream>>>(hb, fn_g, fn_b, xnb);

    // --- decoder ---
    bgemm64_k<1, 0, 1><<<dim3(1152 / 128, M / 64), 256, 0, stream>>>(xnb, upwb, upb2, nullptr, utm, M, 1152, DM);
    mfconv_k<128, 5, 2><<<mgrid, 256, 0, stream>>>(utm, d1pk, d1b, d1tm);

    // --- fused d2 conv + r4 conv + alpha blend ---
    final2_k<<<cgrid, 256, 0, stream>>>(d1tm, r3tm, d2w, d2b, r4w, r4b, alpha, outp);
}